// Round 1
// baseline (2368.935 us; speedup 1.0000x reference)
//
#include <hip/hip_runtime.h>

#define N_NODESX 30000
#define N_EDGES0 300000
#define N_E      330000
#define N_GRAPHSX 64
#define N_CLASSESX 100
#define F_XDX 78
#define HEADSX 10
#define HIDX 780
#define IN_CHX 300

// ---------- helpers ----------
__device__ inline unsigned fenc(float f) {
  unsigned b = __float_as_uint(f);
  return (b & 0x80000000u) ? ~b : (b | 0x80000000u);
}
__device__ inline float fdec(unsigned k) {
  unsigned b = (k & 0x80000000u) ? (k ^ 0x80000000u) : ~k;
  return __uint_as_float(b);
}

// ---------- generic fp32 NN GEMM: C[M,N] = A[M,K] @ B[K,N] (+bias, act) ----------
// ACT: 0 none, 1 relu, 2 leaky_relu(0.2)
template<int ACT, bool HAS_BIAS>
__global__ __launch_bounds__(256)
void gemm_nn(const float* __restrict__ A, const float* __restrict__ B,
             const float* __restrict__ bias, float* __restrict__ C,
             int M, int N, int K) {
  __shared__ float As[16][64];
  __shared__ float Bs[16][64];
  int tid = threadIdx.x;
  int bm = blockIdx.y * 64;
  int bn = blockIdx.x * 64;
  int tr = tid >> 4;   // 0..15
  int tc = tid & 15;   // 0..15
  float acc[4][4] = {{0.f}};
  int la_m = tid >> 2;         // 0..63
  int la_k = (tid & 3) << 2;   // 0,4,8,12
  int lb_k4 = (tid >> 6) << 2; // 0,4,8,12
  int lb_n = tid & 63;

  for (int k0 = 0; k0 < K; k0 += 16) {
    {
      int gm = bm + la_m;
      bool mok = gm < M;
      const float* ap = A + (long)gm * K + k0 + la_k;
      #pragma unroll
      for (int q = 0; q < 4; q++) {
        int kk = la_k + q;
        As[kk][la_m] = (mok && (k0 + kk) < K) ? ap[q] : 0.f;
      }
    }
    {
      int gn = bn + lb_n;
      #pragma unroll
      for (int q = 0; q < 4; q++) {
        int kk = lb_k4 + q;
        int gk = k0 + kk;
        Bs[kk][lb_n] = (gk < K && gn < N) ? B[(long)gk * N + gn] : 0.f;
      }
    }
    __syncthreads();
    #pragma unroll
    for (int kk = 0; kk < 16; kk++) {
      float a0 = As[kk][tr*4+0], a1 = As[kk][tr*4+1],
            a2 = As[kk][tr*4+2], a3 = As[kk][tr*4+3];
      float b0 = Bs[kk][tc*4+0], b1 = Bs[kk][tc*4+1],
            b2 = Bs[kk][tc*4+2], b3 = Bs[kk][tc*4+3];
      acc[0][0] += a0*b0; acc[0][1] += a0*b1; acc[0][2] += a0*b2; acc[0][3] += a0*b3;
      acc[1][0] += a1*b0; acc[1][1] += a1*b1; acc[1][2] += a1*b2; acc[1][3] += a1*b3;
      acc[2][0] += a2*b0; acc[2][1] += a2*b1; acc[2][2] += a2*b2; acc[2][3] += a2*b3;
      acc[3][0] += a3*b0; acc[3][1] += a3*b1; acc[3][2] += a3*b2; acc[3][3] += a3*b3;
    }
    __syncthreads();
  }
  #pragma unroll
  for (int i = 0; i < 4; i++) {
    int gm = bm + tr*4 + i;
    if (gm >= M) continue;
    #pragma unroll
    for (int j = 0; j < 4; j++) {
      int gn = bn + tc*4 + j;
      if (gn >= N) continue;
      float v = acc[i][j];
      if (HAS_BIAS) v += bias[gn];
      if (ACT == 1) v = fmaxf(v, 0.f);
      else if (ACT == 2) v = v > 0.f ? v : 0.2f * v;
      C[(long)gm * N + gn] = v;
    }
  }
}

// ---------- attention logits per (node, head) ----------
__global__ void k_al(const float* __restrict__ h, const float* __restrict__ a_src,
                     const float* __restrict__ a_dst,
                     float* __restrict__ al_s, float* __restrict__ al_d) {
  int idx = blockIdx.x * 256 + threadIdx.x;
  if (idx >= N_NODESX * HEADSX) return;
  int n = idx / HEADSX, hd = idx % HEADSX;
  const float* hp = h + (long)n * HIDX + hd * F_XDX;
  const float* as = a_src + hd * F_XDX;
  const float* ad = a_dst + hd * F_XDX;
  float s1 = 0.f, s2 = 0.f;
  #pragma unroll 6
  for (int c = 0; c < F_XDX; c++) { float v = hp[c]; s1 += v * as[c]; s2 += v * ad[c]; }
  al_s[idx] = s1; al_d[idx] = s2;
}

// ---------- CSR build ----------
__global__ void k_count(const int* __restrict__ ei, int* __restrict__ counts) {
  int e = blockIdx.x * 256 + threadIdx.x;
  if (e >= N_E) return;
  int dst = (e < N_EDGES0) ? ei[N_EDGES0 + e] : (e - N_EDGES0);
  atomicAdd(&counts[dst], 1);
}

__global__ void k_scan(const int* __restrict__ cnt, int* __restrict__ row_ptr) {
  __shared__ int sm[1024];
  __shared__ int s_carry;
  int tid = threadIdx.x;
  if (tid == 0) s_carry = 0;
  __syncthreads();
  for (int base = 0; base < N_NODESX; base += 1024) {
    int i = base + tid;
    int v = (i < N_NODESX) ? cnt[i] : 0;
    sm[tid] = v;
    __syncthreads();
    for (int off = 1; off < 1024; off <<= 1) {
      int t = (tid >= off) ? sm[tid - off] : 0;
      __syncthreads();
      sm[tid] += t;
      __syncthreads();
    }
    int carry = s_carry;
    if (i < N_NODESX) row_ptr[i] = carry + sm[tid] - v;
    __syncthreads();
    if (tid == 0) s_carry = carry + sm[1023];
    __syncthreads();
  }
  if (tid == 0) row_ptr[N_NODESX] = s_carry;
}

__global__ void k_fill(const int* __restrict__ ei, const int* __restrict__ row_ptr,
                       int* __restrict__ cursor, int* __restrict__ csr_src,
                       int* __restrict__ csr_eid) {
  int e = blockIdx.x * 256 + threadIdx.x;
  if (e >= N_E) return;
  int src, dst;
  if (e < N_EDGES0) { src = ei[e]; dst = ei[N_EDGES0 + e]; }
  else { src = dst = e - N_EDGES0; }
  int pos = row_ptr[dst] + atomicAdd(&cursor[dst], 1);
  csr_src[pos] = src;
  csr_eid[pos] = e;
}

// ---------- edge softmax ----------
__global__ void k_edge_logits(const int* __restrict__ ei, const float* __restrict__ al_s,
                              const float* __restrict__ al_d, float* __restrict__ e_edge,
                              unsigned* __restrict__ m_enc) {
  int idx = blockIdx.x * 256 + threadIdx.x;
  if (idx >= N_E * HEADSX) return;
  int e = idx / HEADSX, hd = idx % HEADSX;
  int src, dst;
  if (e < N_EDGES0) { src = ei[e]; dst = ei[N_EDGES0 + e]; }
  else { src = dst = e - N_EDGES0; }
  float v = al_s[src * HEADSX + hd] + al_d[dst * HEADSX + hd];
  v = v > 0.f ? v : 0.2f * v;
  e_edge[idx] = v;
  atomicMax(&m_enc[dst * HEADSX + hd], fenc(v));
}

__global__ void k_decode_max(const unsigned* __restrict__ m_enc, float* __restrict__ m) {
  int i = blockIdx.x * 256 + threadIdx.x;
  if (i < N_NODESX * HEADSX) m[i] = fdec(m_enc[i]);
}

__global__ void k_edge_exp(const int* __restrict__ ei, const float* __restrict__ m,
                           float* __restrict__ e_edge, float* __restrict__ den) {
  int idx = blockIdx.x * 256 + threadIdx.x;
  if (idx >= N_E * HEADSX) return;
  int e = idx / HEADSX, hd = idx % HEADSX;
  int dst = (e < N_EDGES0) ? ei[N_EDGES0 + e] : (e - N_EDGES0);
  float ex = expf(e_edge[idx] - m[dst * HEADSX + hd]);
  e_edge[idx] = ex;
  atomicAdd(&den[dst * HEADSX + hd], ex);
}

// ---------- GAT aggregation (gather per dst) ----------
__global__ __launch_bounds__(256)
void k_gat_agg(const float* __restrict__ h, const float* __restrict__ exe,
               const float* __restrict__ den, const int* __restrict__ row_ptr,
               const int* __restrict__ csr_src, const int* __restrict__ csr_eid,
               const float* __restrict__ b_gat, float* __restrict__ xg) {
  int d = blockIdx.x, t = threadIdx.x;
  int c0 = t, c1 = t + 256, c2 = t + 512, c3 = 768 + t;
  bool has3 = t < (HIDX - 768);
  int h0 = c0 / F_XDX, h1 = c1 / F_XDX, h2 = c2 / F_XDX;
  const float* dn = den + (long)d * HEADSX;
  float id0 = 1.f / (dn[h0] + 1e-16f);
  float id1 = 1.f / (dn[h1] + 1e-16f);
  float id2 = 1.f / (dn[h2] + 1e-16f);
  float id3 = 1.f / (dn[9] + 1e-16f);
  float a0 = 0.f, a1 = 0.f, a2 = 0.f, a3 = 0.f;
  int beg = row_ptr[d], end = row_ptr[d + 1];
  for (int j = beg; j < end; j++) {
    int s = csr_src[j];
    int eid = csr_eid[j];
    const float* hr = h + (long)s * HIDX;
    const float* er = exe + (long)eid * HEADSX;
    a0 += er[h0] * id0 * hr[c0];
    a1 += er[h1] * id1 * hr[c1];
    a2 += er[h2] * id2 * hr[c2];
    if (has3) a3 += er[9] * id3 * hr[c3];
  }
  float* xr = xg + (long)d * HIDX;
  xr[c0] = fmaxf(a0 + b_gat[c0], 0.f);
  xr[c1] = fmaxf(a1 + b_gat[c1], 0.f);
  xr[c2] = fmaxf(a2 + b_gat[c2], 0.f);
  if (has3) xr[c3] = fmaxf(a3 + b_gat[c3], 0.f);
}

// ---------- degree inv sqrt ----------
__global__ void k_dinv(const int* __restrict__ counts, float* __restrict__ dinv) {
  int n = blockIdx.x * 256 + threadIdx.x;
  if (n < N_NODESX) dinv[n] = rsqrtf(fmaxf((float)counts[n], 1.f));
}

// ---------- GCN aggregation (gather per dst) ----------
__global__ __launch_bounds__(256)
void k_gcn_agg(const float* __restrict__ s, const float* __restrict__ dinv,
               const int* __restrict__ row_ptr, const int* __restrict__ csr_src,
               const float* __restrict__ b_gcn, float* __restrict__ out) {
  int d = blockIdx.x, t = threadIdx.x;
  bool has3 = t < (HIDX - 768);
  float dd = dinv[d];
  float a0 = 0.f, a1 = 0.f, a2 = 0.f, a3 = 0.f;
  int beg = row_ptr[d], end = row_ptr[d + 1];
  for (int j = beg; j < end; j++) {
    int sidx = csr_src[j];
    float w = dinv[sidx] * dd;
    const float* sr = s + (long)sidx * HIDX;
    a0 += w * sr[t];
    a1 += w * sr[t + 256];
    a2 += w * sr[t + 512];
    if (has3) a3 += w * sr[768 + t];
  }
  float* xr = out + (long)d * HIDX;
  xr[t]       = fmaxf(a0 + b_gcn[t], 0.f);
  xr[t + 256] = fmaxf(a1 + b_gcn[t + 256], 0.f);
  xr[t + 512] = fmaxf(a2 + b_gcn[t + 512], 0.f);
  if (has3) xr[768 + t] = fmaxf(a3 + b_gcn[768 + t], 0.f);
}

// ---------- per-graph ranges (batch is sorted) ----------
__global__ void k_range_init(int* __restrict__ gstart, int* __restrict__ gend) {
  int g = threadIdx.x;
  if (g < N_GRAPHSX) { gstart[g] = 0x7FFFFFFF; gend[g] = 0; }
}
__global__ void k_ranges(const int* __restrict__ batch, int* __restrict__ gstart,
                         int* __restrict__ gend) {
  int n = blockIdx.x * 256 + threadIdx.x;
  if (n >= N_NODESX) return;
  int b = batch[n];
  atomicMin(&gstart[b], n);
  atomicMax(&gend[b], n + 1);
}

// ---------- pooling: max + mean per graph ----------
__global__ __launch_bounds__(256)
void k_pool(const float* __restrict__ xg2, const int* __restrict__ gstart,
            const int* __restrict__ gend, float* __restrict__ xf) {
  int g = blockIdx.x, t = threadIdx.x;
  int st = gstart[g], en = gend[g];
  bool has3 = t < (HIDX - 768);
  float mx0 = 0.f, mx1 = 0.f, mx2 = 0.f, mx3 = 0.f;
  float s0 = 0.f, s1 = 0.f, s2 = 0.f, s3 = 0.f;
  for (int n = st; n < en; n++) {
    const float* r = xg2 + (long)n * HIDX;
    float v0 = r[t], v1 = r[t + 256], v2 = r[t + 512];
    mx0 = fmaxf(mx0, v0); s0 += v0;
    mx1 = fmaxf(mx1, v1); s1 += v1;
    mx2 = fmaxf(mx2, v2); s2 += v2;
    if (has3) { float v3 = r[768 + t]; mx3 = fmaxf(mx3, v3); s3 += v3; }
  }
  float inv = (en > st) ? 1.f / (float)(en - st) : 0.f;
  float* xr = xf + (long)g * (2 * HIDX);
  xr[t]       = mx0; xr[HIDX + t]       = s0 * inv;
  xr[t + 256] = mx1; xr[HIDX + t + 256] = s1 * inv;
  xr[t + 512] = mx2; xr[HIDX + t + 512] = s2 * inv;
  if (has3) { xr[768 + t] = mx3; xr[HIDX + 768 + t] = s3 * inv; }
}

// ---------- label branch ----------
__global__ void k_dvec(const float* __restrict__ A, float* __restrict__ dvec) {
  int i = blockIdx.x * 64 + threadIdx.x;
  if (i >= N_CLASSESX) return;
  float s = 0.f;
  for (int j = 0; j < N_CLASSESX; j++) s += A[i * N_CLASSESX + j];
  dvec[i] = rsqrtf(s);
}
__global__ void k_adj(const float* __restrict__ A, const float* __restrict__ dvec,
                      float* __restrict__ adj) {
  int idx = blockIdx.x * 256 + threadIdx.x;
  if (idx >= N_CLASSESX * N_CLASSESX) return;
  int i = idx / N_CLASSESX, j = idx % N_CLASSESX;
  adj[idx] = dvec[i] * A[j * N_CLASSESX + i] * dvec[j];
}

// ---------- final out = xf2 @ y^T ----------
__global__ void k_out(const float* __restrict__ xf2, const float* __restrict__ y,
                      float* __restrict__ out) {
  int idx = blockIdx.x * 256 + threadIdx.x;
  if (idx >= N_GRAPHSX * N_CLASSESX) return;
  int b = idx / N_CLASSESX, c = idx % N_CLASSESX;
  const float* xr = xf2 + (long)b * 1024;
  const float* yr = y + (long)c * 1024;
  float s = 0.f;
  #pragma unroll 8
  for (int k = 0; k < 1024; k++) s += xr[k] * yr[k];
  out[idx] = s;
}

// =======================================================================
extern "C" void kernel_launch(void* const* d_in, const int* in_sizes, int n_in,
                              void* d_out, int out_size, void* d_ws, size_t ws_size,
                              hipStream_t stream) {
  const float* x     = (const float*)d_in[0];
  const int*   ei    = (const int*)d_in[1];
  const int*   batch = (const int*)d_in[2];
  const float* inp   = (const float*)d_in[3];
  const float* W_gat = (const float*)d_in[4];
  const float* a_src = (const float*)d_in[5];
  const float* a_dst = (const float*)d_in[6];
  const float* b_gat = (const float*)d_in[7];
  const float* W_gcn = (const float*)d_in[8];
  const float* b_gcn = (const float*)d_in[9];
  const float* W_fc1 = (const float*)d_in[10];
  const float* b_fc1 = (const float*)d_in[11];
  const float* W_fc2 = (const float*)d_in[12];
  const float* b_fc2 = (const float*)d_in[13];
  const float* W_gc1 = (const float*)d_in[14];
  const float* W_gc2 = (const float*)d_in[15];
  const float* A     = (const float*)d_in[16];
  float* out = (float*)d_out;

  char* ws = (char*)d_ws;
  size_t off = 0;
  auto alloc = [&](size_t bytes) -> void* {
    void* p = ws + off;
    off = (off + bytes + 255) & ~(size_t)255;
    return p;
  };

  float* bufA   = (float*)alloc(sizeof(float) * (size_t)N_NODESX * HIDX); // h, then s
  float* bufB   = (float*)alloc(sizeof(float) * (size_t)N_NODESX * HIDX); // xg, then xg2
  float* e_edge = (float*)alloc(sizeof(float) * (size_t)N_E * HEADSX);
  float* al_s   = (float*)alloc(sizeof(float) * N_NODESX * HEADSX);
  float* al_d   = (float*)alloc(sizeof(float) * N_NODESX * HEADSX);
  unsigned* m_enc = (unsigned*)alloc(sizeof(unsigned) * N_NODESX * HEADSX);
  float* m_dec  = (float*)alloc(sizeof(float) * N_NODESX * HEADSX);
  float* den    = (float*)alloc(sizeof(float) * N_NODESX * HEADSX);
  int* counts   = (int*)alloc(sizeof(int) * N_NODESX);
  int* row_ptr  = (int*)alloc(sizeof(int) * (N_NODESX + 1));
  int* cursor   = (int*)alloc(sizeof(int) * N_NODESX);
  int* csr_src  = (int*)alloc(sizeof(int) * N_E);
  int* csr_eid  = (int*)alloc(sizeof(int) * N_E);
  float* dinv   = (float*)alloc(sizeof(float) * N_NODESX);
  int* gstart   = (int*)alloc(sizeof(int) * N_GRAPHSX);
  int* gend     = (int*)alloc(sizeof(int) * N_GRAPHSX);
  float* xf     = (float*)alloc(sizeof(float) * N_GRAPHSX * 2 * HIDX);
  float* fc1o   = (float*)alloc(sizeof(float) * N_GRAPHSX * 1500);
  float* fc2o   = (float*)alloc(sizeof(float) * N_GRAPHSX * 1024);
  float* t1     = (float*)alloc(sizeof(float) * N_CLASSESX * 1024);
  float* adj    = (float*)alloc(sizeof(float) * N_CLASSESX * N_CLASSESX);
  float* dvec   = (float*)alloc(sizeof(float) * N_CLASSESX);
  float* y1     = (float*)alloc(sizeof(float) * N_CLASSESX * 1024);
  float* t2     = (float*)alloc(sizeof(float) * N_CLASSESX * 1024);
  float* ybuf   = (float*)alloc(sizeof(float) * N_CLASSESX * 1024);
  (void)ws_size; (void)in_sizes; (void)n_in; (void)out_size;

  hipMemsetAsync(m_enc, 0, sizeof(unsigned) * N_NODESX * HEADSX, stream);
  hipMemsetAsync(den, 0, sizeof(float) * N_NODESX * HEADSX, stream);
  hipMemsetAsync(counts, 0, sizeof(int) * N_NODESX, stream);
  hipMemsetAsync(cursor, 0, sizeof(int) * N_NODESX, stream);

  // h = x @ W_gat
  gemm_nn<0, false><<<dim3((HIDX + 63) / 64, (N_NODESX + 63) / 64), 256, 0, stream>>>(
      x, W_gat, nullptr, bufA, N_NODESX, HIDX, F_XDX);
  // attention logits
  k_al<<<(N_NODESX * HEADSX + 255) / 256, 256, 0, stream>>>(bufA, a_src, a_dst, al_s, al_d);
  // CSR
  k_count<<<(N_E + 255) / 256, 256, 0, stream>>>(ei, counts);
  k_scan<<<1, 1024, 0, stream>>>(counts, row_ptr);
  k_fill<<<(N_E + 255) / 256, 256, 0, stream>>>(ei, row_ptr, cursor, csr_src, csr_eid);
  // edge softmax
  k_edge_logits<<<(N_E * HEADSX + 255) / 256, 256, 0, stream>>>(ei, al_s, al_d, e_edge, m_enc);
  k_decode_max<<<(N_NODESX * HEADSX + 255) / 256, 256, 0, stream>>>(m_enc, m_dec);
  k_edge_exp<<<(N_E * HEADSX + 255) / 256, 256, 0, stream>>>(ei, m_dec, e_edge, den);
  // GAT aggregate -> xg (bufB)
  k_gat_agg<<<N_NODESX, 256, 0, stream>>>(bufA, e_edge, den, row_ptr, csr_src, csr_eid,
                                          b_gat, bufB);
  // GCN
  k_dinv<<<(N_NODESX + 255) / 256, 256, 0, stream>>>(counts, dinv);
  gemm_nn<0, false><<<dim3((HIDX + 63) / 64, (N_NODESX + 63) / 64), 256, 0, stream>>>(
      bufB, W_gcn, nullptr, bufA, N_NODESX, HIDX, HIDX);           // s -> bufA
  k_gcn_agg<<<N_NODESX, 256, 0, stream>>>(bufA, dinv, row_ptr, csr_src, b_gcn, bufB); // xg2 -> bufB
  // pooling
  k_range_init<<<1, 64, 0, stream>>>(gstart, gend);
  k_ranges<<<(N_NODESX + 255) / 256, 256, 0, stream>>>(batch, gstart, gend);
  k_pool<<<N_GRAPHSX, 256, 0, stream>>>(bufB, gstart, gend, xf);
  // dense head
  gemm_nn<1, true><<<dim3((1500 + 63) / 64, (N_GRAPHSX + 63) / 64), 256, 0, stream>>>(
      xf, W_fc1, b_fc1, fc1o, N_GRAPHSX, 1500, 2 * HIDX);
  gemm_nn<0, true><<<dim3((1024 + 63) / 64, (N_GRAPHSX + 63) / 64), 256, 0, stream>>>(
      fc1o, W_fc2, b_fc2, fc2o, N_GRAPHSX, 1024, 1500);
  // label branch
  k_dvec<<<(N_CLASSESX + 63) / 64, 64, 0, stream>>>(A, dvec);
  k_adj<<<(N_CLASSESX * N_CLASSESX + 255) / 256, 256, 0, stream>>>(A, dvec, adj);
  gemm_nn<0, false><<<dim3((1024 + 63) / 64, (N_CLASSESX + 63) / 64), 256, 0, stream>>>(
      inp, W_gc1, nullptr, t1, N_CLASSESX, 1024, IN_CHX);
  gemm_nn<2, false><<<dim3((1024 + 63) / 64, (N_CLASSESX + 63) / 64), 256, 0, stream>>>(
      adj, t1, nullptr, y1, N_CLASSESX, 1024, N_CLASSESX);
  gemm_nn<0, false><<<dim3((1024 + 63) / 64, (N_CLASSESX + 63) / 64), 256, 0, stream>>>(
      y1, W_gc2, nullptr, t2, N_CLASSESX, 1024, 1024);
  gemm_nn<0, false><<<dim3((1024 + 63) / 64, (N_CLASSESX + 63) / 64), 256, 0, stream>>>(
      adj, t2, nullptr, ybuf, N_CLASSESX, 1024, N_CLASSESX);
  // out = fc2o @ ybuf^T
  k_out<<<(N_GRAPHSX * N_CLASSESX + 255) / 256, 256, 0, stream>>>(fc2o, ybuf, out);
}

// Round 2
// 2308.334 us; speedup vs baseline: 1.0263x; 1.0263x over previous
//
#include <hip/hip_runtime.h>

#define N_NODESX 30000
#define N_EDGES0 300000
#define N_E      330000
#define N_GRAPHSX 64
#define N_CLASSESX 100
#define F_XDX 78
#define HEADSX 10
#define HIDX 780
#define IN_CHX 300

// ---------- generic fp32 NN GEMM (small sizes): C[M,N]=A@B (+bias, act) ----------
// ACT: 0 none, 1 relu, 2 leaky_relu(0.2)
template<int ACT, bool HAS_BIAS>
__global__ __launch_bounds__(256)
void gemm_nn(const float* __restrict__ A, const float* __restrict__ B,
             const float* __restrict__ bias, float* __restrict__ C,
             int M, int N, int K) {
  __shared__ float As[16][64];
  __shared__ float Bs[16][64];
  int tid = threadIdx.x;
  int bm = blockIdx.y * 64;
  int bn = blockIdx.x * 64;
  int tr = tid >> 4;
  int tc = tid & 15;
  float acc[4][4] = {{0.f}};
  int la_m = tid >> 2;
  int la_k = (tid & 3) << 2;
  int lb_k4 = (tid >> 6) << 2;
  int lb_n = tid & 63;

  for (int k0 = 0; k0 < K; k0 += 16) {
    {
      int gm = bm + la_m;
      bool mok = gm < M;
      const float* ap = A + (long)gm * K + k0 + la_k;
      #pragma unroll
      for (int q = 0; q < 4; q++) {
        int kk = la_k + q;
        As[kk][la_m] = (mok && (k0 + kk) < K) ? ap[q] : 0.f;
      }
    }
    {
      int gn = bn + lb_n;
      #pragma unroll
      for (int q = 0; q < 4; q++) {
        int kk = lb_k4 + q;
        int gk = k0 + kk;
        Bs[kk][lb_n] = (gk < K && gn < N) ? B[(long)gk * N + gn] : 0.f;
      }
    }
    __syncthreads();
    #pragma unroll
    for (int kk = 0; kk < 16; kk++) {
      float a0 = As[kk][tr*4+0], a1 = As[kk][tr*4+1],
            a2 = As[kk][tr*4+2], a3 = As[kk][tr*4+3];
      float b0 = Bs[kk][tc*4+0], b1 = Bs[kk][tc*4+1],
            b2 = Bs[kk][tc*4+2], b3 = Bs[kk][tc*4+3];
      acc[0][0] += a0*b0; acc[0][1] += a0*b1; acc[0][2] += a0*b2; acc[0][3] += a0*b3;
      acc[1][0] += a1*b0; acc[1][1] += a1*b1; acc[1][2] += a1*b2; acc[1][3] += a1*b3;
      acc[2][0] += a2*b0; acc[2][1] += a2*b1; acc[2][2] += a2*b2; acc[2][3] += a2*b3;
      acc[3][0] += a3*b0; acc[3][1] += a3*b1; acc[3][2] += a3*b2; acc[3][3] += a3*b3;
    }
    __syncthreads();
  }
  #pragma unroll
  for (int i = 0; i < 4; i++) {
    int gm = bm + tr*4 + i;
    if (gm >= M) continue;
    #pragma unroll
    for (int j = 0; j < 4; j++) {
      int gn = bn + tc*4 + j;
      if (gn >= N) continue;
      float v = acc[i][j];
      if (HAS_BIAS) v += bias[gn];
      if (ACT == 1) v = fmaxf(v, 0.f);
      else if (ACT == 2) v = v > 0.f ? v : 0.2f * v;
      C[(long)gm * N + gn] = v;
    }
  }
}

// ---------- big fp32 GEMM: BM=256, BN=64, BK=16, 256 thr, 16x4 micro ----------
// Requires K%4==0 and 16B-aligned rows for the fast A path (guarded generically).
template<int ACT, bool HAS_BIAS>
__global__ __launch_bounds__(256)
void gemm_big(const float* __restrict__ A, const float* __restrict__ B,
              const float* __restrict__ bias, float* __restrict__ C,
              int M, int N, int K) {
  __shared__ float As[16][264];
  __shared__ float Bs[16][68];
  const int tid = threadIdx.x;
  const int bm = blockIdx.y * 256;
  const int bn = blockIdx.x * 64;
  const int rg = tid >> 4;        // 0..15 -> rows rg*16..rg*16+15
  const int cg = tid & 15;        // cols cg*4
  const int gmA = bm + tid;       // the one row this thread stages
  const int bkB = tid >> 4;
  const int nbB = (tid & 15) * 4;
  const bool edgeN = (bn + 64 > N);

  float acc[16][4];
  #pragma unroll
  for (int i = 0; i < 16; i++)
    #pragma unroll
    for (int j = 0; j < 4; j++) acc[i][j] = 0.f;

  for (int k0 = 0; k0 < K; k0 += 16) {
    // stage A: one row of 16 floats per thread -> As[k][row] (transposed)
    if (gmA < M) {
      if (k0 + 16 <= K) {
        const float* ap = A + (size_t)gmA * K + k0;
        float4 v0 = *(const float4*)(ap);
        float4 v1 = *(const float4*)(ap + 4);
        float4 v2 = *(const float4*)(ap + 8);
        float4 v3 = *(const float4*)(ap + 12);
        As[ 0][tid]=v0.x; As[ 1][tid]=v0.y; As[ 2][tid]=v0.z; As[ 3][tid]=v0.w;
        As[ 4][tid]=v1.x; As[ 5][tid]=v1.y; As[ 6][tid]=v1.z; As[ 7][tid]=v1.w;
        As[ 8][tid]=v2.x; As[ 9][tid]=v2.y; As[10][tid]=v2.z; As[11][tid]=v2.w;
        As[12][tid]=v3.x; As[13][tid]=v3.y; As[14][tid]=v3.z; As[15][tid]=v3.w;
      } else {
        #pragma unroll
        for (int q = 0; q < 16; q++) {
          int gk = k0 + q;
          As[q][tid] = (gk < K) ? A[(size_t)gmA * K + gk] : 0.f;
        }
      }
    } else {
      #pragma unroll
      for (int q = 0; q < 16; q++) As[q][tid] = 0.f;
    }
    // stage B: 16x64 tile, one float4 per thread
    {
      int gk = k0 + bkB;
      if (gk < K && !edgeN) {
        float4 v = *(const float4*)(B + (size_t)gk * N + bn + nbB);
        *(float4*)&Bs[bkB][nbB] = v;
      } else {
        #pragma unroll
        for (int q = 0; q < 4; q++) {
          int gn = bn + nbB + q;
          Bs[bkB][nbB + q] = (gk < K && gn < N) ? B[(size_t)gk * N + gn] : 0.f;
        }
      }
    }
    __syncthreads();
    #pragma unroll
    for (int kk = 0; kk < 16; kk++) {
      float4 b4 = *(const float4*)&Bs[kk][cg * 4];
      const float* arow = &As[kk][rg * 16];
      float4 a0 = *(const float4*)(arow);
      float4 a1 = *(const float4*)(arow + 4);
      float4 a2 = *(const float4*)(arow + 8);
      float4 a3 = *(const float4*)(arow + 12);
      float a[16];
      a[0]=a0.x; a[1]=a0.y; a[2]=a0.z; a[3]=a0.w;
      a[4]=a1.x; a[5]=a1.y; a[6]=a1.z; a[7]=a1.w;
      a[8]=a2.x; a[9]=a2.y; a[10]=a2.z; a[11]=a2.w;
      a[12]=a3.x; a[13]=a3.y; a[14]=a3.z; a[15]=a3.w;
      #pragma unroll
      for (int i = 0; i < 16; i++) {
        acc[i][0] += a[i] * b4.x;
        acc[i][1] += a[i] * b4.y;
        acc[i][2] += a[i] * b4.z;
        acc[i][3] += a[i] * b4.w;
      }
    }
    __syncthreads();
  }
  // epilogue
  const int gn = bn + cg * 4;
  #pragma unroll
  for (int i = 0; i < 16; i++) {
    int gm = bm + rg * 16 + i;
    if (gm >= M) continue;
    if (gn + 3 < N) {
      float4 r;
      r.x = acc[i][0]; r.y = acc[i][1]; r.z = acc[i][2]; r.w = acc[i][3];
      if (HAS_BIAS) { r.x += bias[gn]; r.y += bias[gn+1]; r.z += bias[gn+2]; r.w += bias[gn+3]; }
      if (ACT == 1) { r.x=fmaxf(r.x,0.f); r.y=fmaxf(r.y,0.f); r.z=fmaxf(r.z,0.f); r.w=fmaxf(r.w,0.f); }
      else if (ACT == 2) {
        r.x = r.x>0.f?r.x:0.2f*r.x; r.y = r.y>0.f?r.y:0.2f*r.y;
        r.z = r.z>0.f?r.z:0.2f*r.z; r.w = r.w>0.f?r.w:0.2f*r.w;
      }
      *(float4*)&C[(size_t)gm * N + gn] = r;
    } else {
      #pragma unroll
      for (int q = 0; q < 4; q++) {
        int g2 = gn + q;
        if (g2 >= N) continue;
        float v = acc[i][q];
        if (HAS_BIAS) v += bias[g2];
        if (ACT == 1) v = fmaxf(v, 0.f);
        else if (ACT == 2) v = v > 0.f ? v : 0.2f * v;
        C[(size_t)gm * N + g2] = v;
      }
    }
  }
}

// ---------- attention logits per (node, head), float2 ----------
__global__ void k_al(const float* __restrict__ h, const float* __restrict__ a_src,
                     const float* __restrict__ a_dst,
                     float* __restrict__ al_s, float* __restrict__ al_d) {
  int idx = blockIdx.x * 256 + threadIdx.x;
  if (idx >= N_NODESX * HEADSX) return;
  int n = idx / HEADSX, hd = idx % HEADSX;
  const float2* hp  = (const float2*)(h + (size_t)n * HIDX + hd * F_XDX);
  const float2* as2 = (const float2*)(a_src + hd * F_XDX);
  const float2* ad2 = (const float2*)(a_dst + hd * F_XDX);
  float s1 = 0.f, s2 = 0.f;
  #pragma unroll 13
  for (int i = 0; i < F_XDX / 2; i++) {
    float2 v = hp[i], a = as2[i], d = ad2[i];
    s1 += v.x * a.x + v.y * a.y;
    s2 += v.x * d.x + v.y * d.y;
  }
  al_s[idx] = s1; al_d[idx] = s2;
}

// ---------- CSR build ----------
__global__ void k_count(const int* __restrict__ ei, int* __restrict__ counts) {
  int e = blockIdx.x * 256 + threadIdx.x;
  if (e >= N_E) return;
  int dst = (e < N_EDGES0) ? ei[N_EDGES0 + e] : (e - N_EDGES0);
  atomicAdd(&counts[dst], 1);
}

__global__ void k_scan(const int* __restrict__ cnt, int* __restrict__ row_ptr) {
  __shared__ int part[1024];
  int tid = threadIdx.x;
  const int CH = 30;   // 1024*30 >= 30000
  int b0 = tid * CH;
  int s = 0;
  for (int i = 0; i < CH; i++) { int g = b0 + i; if (g < N_NODESX) s += cnt[g]; }
  part[tid] = s;
  __syncthreads();
  for (int off = 1; off < 1024; off <<= 1) {
    int v = (tid >= off) ? part[tid - off] : 0;
    __syncthreads();
    part[tid] += v;
    __syncthreads();
  }
  int pre = (tid > 0) ? part[tid - 1] : 0;
  for (int i = 0; i < CH; i++) {
    int g = b0 + i;
    if (g < N_NODESX) { row_ptr[g] = pre; pre += cnt[g]; }
  }
  if (tid == 1023) row_ptr[N_NODESX] = part[1023];
}

__global__ void k_fill(const int* __restrict__ ei, const int* __restrict__ row_ptr,
                       int* __restrict__ cursor, int* __restrict__ csr_src,
                       int* __restrict__ csr_eid) {
  int e = blockIdx.x * 256 + threadIdx.x;
  if (e >= N_E) return;
  int src, dst;
  if (e < N_EDGES0) { src = ei[e]; dst = ei[N_EDGES0 + e]; }
  else { src = dst = e - N_EDGES0; }
  int pos = row_ptr[dst] + atomicAdd(&cursor[dst], 1);
  csr_src[pos] = src;
  csr_eid[pos] = e;
}

// ---------- edge softmax (no max shift: logits bounded ~|1.5|) ----------
__global__ void k_edge_exp(const int* __restrict__ ei, const float* __restrict__ al_s,
                           const float* __restrict__ al_d,
                           float* __restrict__ e_edge, float* __restrict__ den) {
  int e = blockIdx.x * 256 + threadIdx.x;
  if (e >= N_E) return;
  int src, dst;
  if (e < N_EDGES0) { src = ei[e]; dst = ei[N_EDGES0 + e]; }
  else { src = dst = e - N_EDGES0; }
  const float* ps = al_s + (size_t)src * HEADSX;
  const float* pd = al_d + (size_t)dst * HEADSX;
  float* pe = e_edge + (size_t)e * HEADSX;
  #pragma unroll
  for (int hd = 0; hd < HEADSX; hd++) {
    float v = ps[hd] + pd[hd];
    v = v > 0.f ? v : 0.2f * v;
    float ex = expf(v);
    pe[hd] = ex;
    atomicAdd(&den[dst * HEADSX + hd], ex);
  }
}

// ---------- GAT aggregation (gather per dst, float4) ----------
__global__ __launch_bounds__(256)
void k_gat_agg(const float* __restrict__ h, const float* __restrict__ exe,
               const float* __restrict__ den, const int* __restrict__ row_ptr,
               const int* __restrict__ csr_src, const int* __restrict__ csr_eid,
               const float* __restrict__ b_gat, float* __restrict__ xg) {
  __shared__ float id[HEADSX];
  int d = blockIdx.x, t = threadIdx.x;
  if (t < HEADSX) id[t] = 1.f / (den[d * HEADSX + t] + 1e-16f);
  __syncthreads();
  if (t >= HIDX / 4) return;         // 195 active
  int c = t * 4;
  int ha = c / F_XDX;
  int hb = (c + 3) / F_XDX;
  int split = (ha + 1) * F_XDX - c;  // elements [0,split) belong to head ha
  float idA = id[ha], idB = id[hb];
  float4 acc = {0.f, 0.f, 0.f, 0.f};
  int beg = row_ptr[d], end = row_ptr[d + 1];
  for (int j = beg; j < end; j++) {
    int s = csr_src[j];
    int eid = csr_eid[j];
    const float* er = exe + (size_t)eid * HEADSX;
    float aA = er[ha] * idA;
    float aB = (hb != ha) ? er[hb] * idB : aA;
    float w0 = (split > 0) ? aA : aB;
    float w1 = (split > 1) ? aA : aB;
    float w2 = (split > 2) ? aA : aB;
    float w3 = (split > 3) ? aA : aB;
    float4 hv = *(const float4*)(h + (size_t)s * HIDX + c);
    acc.x += w0 * hv.x; acc.y += w1 * hv.y; acc.z += w2 * hv.z; acc.w += w3 * hv.w;
  }
  float4 bb = *(const float4*)(b_gat + c);
  float4 r;
  r.x = fmaxf(acc.x + bb.x, 0.f);
  r.y = fmaxf(acc.y + bb.y, 0.f);
  r.z = fmaxf(acc.z + bb.z, 0.f);
  r.w = fmaxf(acc.w + bb.w, 0.f);
  *(float4*)(xg + (size_t)d * HIDX + c) = r;
}

// ---------- degree inv sqrt ----------
__global__ void k_dinv(const int* __restrict__ counts, float* __restrict__ dinv) {
  int n = blockIdx.x * 256 + threadIdx.x;
  if (n < N_NODESX) dinv[n] = rsqrtf(fmaxf((float)counts[n], 1.f));
}

// ---------- GCN aggregation (gather per dst, float4) ----------
__global__ __launch_bounds__(256)
void k_gcn_agg(const float* __restrict__ s, const float* __restrict__ dinv,
               const int* __restrict__ row_ptr, const int* __restrict__ csr_src,
               const float* __restrict__ b_gcn, float* __restrict__ out) {
  int d = blockIdx.x, t = threadIdx.x;
  if (t >= HIDX / 4) return;
  int c = t * 4;
  float4 acc = {0.f, 0.f, 0.f, 0.f};
  int beg = row_ptr[d], end = row_ptr[d + 1];
  for (int j = beg; j < end; j++) {
    int si = csr_src[j];
    float w = dinv[si];
    float4 sv = *(const float4*)(s + (size_t)si * HIDX + c);
    acc.x += w * sv.x; acc.y += w * sv.y; acc.z += w * sv.z; acc.w += w * sv.w;
  }
  float dd = dinv[d];
  float4 bb = *(const float4*)(b_gcn + c);
  float4 r;
  r.x = fmaxf(acc.x * dd + bb.x, 0.f);
  r.y = fmaxf(acc.y * dd + bb.y, 0.f);
  r.z = fmaxf(acc.z * dd + bb.z, 0.f);
  r.w = fmaxf(acc.w * dd + bb.w, 0.f);
  *(float4*)(out + (size_t)d * HIDX + c) = r;
}

// ---------- per-graph ranges (batch is sorted) ----------
__global__ void k_range_init(int* __restrict__ gstart, int* __restrict__ gend) {
  int g = threadIdx.x;
  if (g < N_GRAPHSX) { gstart[g] = 0x7FFFFFFF; gend[g] = 0; }
}
__global__ void k_ranges(const int* __restrict__ batch, int* __restrict__ gstart,
                         int* __restrict__ gend) {
  int n = blockIdx.x * 256 + threadIdx.x;
  if (n >= N_NODESX) return;
  int b = batch[n];
  atomicMin(&gstart[b], n);
  atomicMax(&gend[b], n + 1);
}

// ---------- pooling: max + mean per graph, float4 ----------
__global__ __launch_bounds__(256)
void k_pool(const float* __restrict__ xg2, const int* __restrict__ gstart,
            const int* __restrict__ gend, float* __restrict__ xf) {
  int g = blockIdx.x, t = threadIdx.x;
  if (t >= HIDX / 4) return;
  int c = t * 4;
  int st = gstart[g], en = gend[g];
  float4 mx = {0.f, 0.f, 0.f, 0.f};
  float4 sm = {0.f, 0.f, 0.f, 0.f};
  for (int n = st; n < en; n++) {
    float4 v = *(const float4*)(xg2 + (size_t)n * HIDX + c);
    mx.x = fmaxf(mx.x, v.x); sm.x += v.x;
    mx.y = fmaxf(mx.y, v.y); sm.y += v.y;
    mx.z = fmaxf(mx.z, v.z); sm.z += v.z;
    mx.w = fmaxf(mx.w, v.w); sm.w += v.w;
  }
  float inv = (en > st) ? 1.f / (float)(en - st) : 0.f;
  float* xr = xf + (size_t)g * (2 * HIDX);
  float4 mean; mean.x = sm.x*inv; mean.y = sm.y*inv; mean.z = sm.z*inv; mean.w = sm.w*inv;
  *(float4*)(xr + c) = mx;
  *(float4*)(xr + HIDX + c) = mean;
}

// ---------- label branch ----------
__global__ void k_dvec(const float* __restrict__ A, float* __restrict__ dvec) {
  int i = blockIdx.x * 64 + threadIdx.x;
  if (i >= N_CLASSESX) return;
  float s = 0.f;
  for (int j = 0; j < N_CLASSESX; j++) s += A[i * N_CLASSESX + j];
  dvec[i] = rsqrtf(s);
}
__global__ void k_adj(const float* __restrict__ A, const float* __restrict__ dvec,
                      float* __restrict__ adj) {
  int idx = blockIdx.x * 256 + threadIdx.x;
  if (idx >= N_CLASSESX * N_CLASSESX) return;
  int i = idx / N_CLASSESX, j = idx % N_CLASSESX;
  adj[idx] = dvec[i] * A[j * N_CLASSESX + i] * dvec[j];
}

// ---------- final out = xf2 @ y^T, float4 ----------
__global__ void k_out(const float* __restrict__ xf2, const float* __restrict__ y,
                      float* __restrict__ out) {
  int idx = blockIdx.x * 256 + threadIdx.x;
  if (idx >= N_GRAPHSX * N_CLASSESX) return;
  int b = idx / N_CLASSESX, c = idx % N_CLASSESX;
  const float4* xr = (const float4*)(xf2 + (size_t)b * 1024);
  const float4* yr = (const float4*)(y + (size_t)c * 1024);
  float s = 0.f;
  #pragma unroll 8
  for (int k = 0; k < 256; k++) {
    float4 xv = xr[k], yv = yr[k];
    s += xv.x*yv.x + xv.y*yv.y + xv.z*yv.z + xv.w*yv.w;
  }
  out[idx] = s;
}

// =======================================================================
extern "C" void kernel_launch(void* const* d_in, const int* in_sizes, int n_in,
                              void* d_out, int out_size, void* d_ws, size_t ws_size,
                              hipStream_t stream) {
  const float* x     = (const float*)d_in[0];
  const int*   ei    = (const int*)d_in[1];
  const int*   batch = (const int*)d_in[2];
  const float* inp   = (const float*)d_in[3];
  const float* W_gat = (const float*)d_in[4];
  const float* a_src = (const float*)d_in[5];
  const float* a_dst = (const float*)d_in[6];
  const float* b_gat = (const float*)d_in[7];
  const float* W_gcn = (const float*)d_in[8];
  const float* b_gcn = (const float*)d_in[9];
  const float* W_fc1 = (const float*)d_in[10];
  const float* b_fc1 = (const float*)d_in[11];
  const float* W_fc2 = (const float*)d_in[12];
  const float* b_fc2 = (const float*)d_in[13];
  const float* W_gc1 = (const float*)d_in[14];
  const float* W_gc2 = (const float*)d_in[15];
  const float* A     = (const float*)d_in[16];
  float* out = (float*)d_out;

  char* ws = (char*)d_ws;
  size_t off = 0;
  auto alloc = [&](size_t bytes) -> void* {
    void* p = ws + off;
    off = (off + bytes + 255) & ~(size_t)255;
    return p;
  };

  float* bufA   = (float*)alloc(sizeof(float) * (size_t)N_NODESX * HIDX); // h, then s
  float* bufB   = (float*)alloc(sizeof(float) * (size_t)N_NODESX * HIDX); // xg, then xg2
  float* e_edge = (float*)alloc(sizeof(float) * (size_t)N_E * HEADSX);
  float* al_s   = (float*)alloc(sizeof(float) * N_NODESX * HEADSX);
  float* al_d   = (float*)alloc(sizeof(float) * N_NODESX * HEADSX);
  float* den    = (float*)alloc(sizeof(float) * N_NODESX * HEADSX);
  int* counts   = (int*)alloc(sizeof(int) * N_NODESX);
  int* row_ptr  = (int*)alloc(sizeof(int) * (N_NODESX + 1));
  int* cursor   = (int*)alloc(sizeof(int) * N_NODESX);
  int* csr_src  = (int*)alloc(sizeof(int) * N_E);
  int* csr_eid  = (int*)alloc(sizeof(int) * N_E);
  float* dinv   = (float*)alloc(sizeof(float) * N_NODESX);
  int* gstart   = (int*)alloc(sizeof(int) * N_GRAPHSX);
  int* gend     = (int*)alloc(sizeof(int) * N_GRAPHSX);
  float* xf     = (float*)alloc(sizeof(float) * N_GRAPHSX * 2 * HIDX);
  float* fc1o   = (float*)alloc(sizeof(float) * N_GRAPHSX * 1500);
  float* fc2o   = (float*)alloc(sizeof(float) * N_GRAPHSX * 1024);
  float* t1     = (float*)alloc(sizeof(float) * N_CLASSESX * 1024);
  float* adj    = (float*)alloc(sizeof(float) * N_CLASSESX * N_CLASSESX);
  float* dvec   = (float*)alloc(sizeof(float) * N_CLASSESX);
  float* y1     = (float*)alloc(sizeof(float) * N_CLASSESX * 1024);
  float* t2     = (float*)alloc(sizeof(float) * N_CLASSESX * 1024);
  float* ybuf   = (float*)alloc(sizeof(float) * N_CLASSESX * 1024);
  (void)ws_size; (void)in_sizes; (void)n_in; (void)out_size;

  hipMemsetAsync(den, 0, sizeof(float) * N_NODESX * HEADSX, stream);
  hipMemsetAsync(counts, 0, sizeof(int) * N_NODESX, stream);
  hipMemsetAsync(cursor, 0, sizeof(int) * N_NODESX, stream);

  // h = x @ W_gat  (K=78: rows not 16B-aligned -> keep small-GEMM kernel)
  gemm_nn<0, false><<<dim3((HIDX + 63) / 64, (N_NODESX + 63) / 64), 256, 0, stream>>>(
      x, W_gat, nullptr, bufA, N_NODESX, HIDX, F_XDX);
  // attention logits
  k_al<<<(N_NODESX * HEADSX + 255) / 256, 256, 0, stream>>>(bufA, a_src, a_dst, al_s, al_d);
  // CSR
  k_count<<<(N_E + 255) / 256, 256, 0, stream>>>(ei, counts);
  k_scan<<<1, 1024, 0, stream>>>(counts, row_ptr);
  k_fill<<<(N_E + 255) / 256, 256, 0, stream>>>(ei, row_ptr, cursor, csr_src, csr_eid);
  // edge softmax (exp + denominator; no max shift, logits are bounded)
  k_edge_exp<<<(N_E + 255) / 256, 256, 0, stream>>>(ei, al_s, al_d, e_edge, den);
  // GAT aggregate -> xg (bufB)
  k_gat_agg<<<N_NODESX, 256, 0, stream>>>(bufA, e_edge, den, row_ptr, csr_src, csr_eid,
                                          b_gat, bufB);
  // GCN
  k_dinv<<<(N_NODESX + 255) / 256, 256, 0, stream>>>(counts, dinv);
  gemm_big<0, false><<<dim3((HIDX + 63) / 64, (N_NODESX + 255) / 256), 256, 0, stream>>>(
      bufB, W_gcn, nullptr, bufA, N_NODESX, HIDX, HIDX);            // s -> bufA
  k_gcn_agg<<<N_NODESX, 256, 0, stream>>>(bufA, dinv, row_ptr, csr_src, b_gcn, bufB);
  // pooling
  k_range_init<<<1, 64, 0, stream>>>(gstart, gend);
  k_ranges<<<(N_NODESX + 255) / 256, 256, 0, stream>>>(batch, gstart, gend);
  k_pool<<<N_GRAPHSX, 256, 0, stream>>>(bufB, gstart, gend, xf);
  // dense head
  gemm_nn<1, true><<<dim3((1500 + 63) / 64, (N_GRAPHSX + 63) / 64), 256, 0, stream>>>(
      xf, W_fc1, b_fc1, fc1o, N_GRAPHSX, 1500, 2 * HIDX);
  gemm_nn<0, true><<<dim3((1024 + 63) / 64, (N_GRAPHSX + 63) / 64), 256, 0, stream>>>(
      fc1o, W_fc2, b_fc2, fc2o, N_GRAPHSX, 1024, 1500);
  // label branch
  k_dvec<<<(N_CLASSESX + 63) / 64, 64, 0, stream>>>(A, dvec);
  k_adj<<<(N_CLASSESX * N_CLASSESX + 255) / 256, 256, 0, stream>>>(A, dvec, adj);
  gemm_nn<0, false><<<dim3((1024 + 63) / 64, (N_CLASSESX + 63) / 64), 256, 0, stream>>>(
      inp, W_gc1, nullptr, t1, N_CLASSESX, 1024, IN_CHX);
  gemm_nn<2, false><<<dim3((1024 + 63) / 64, (N_CLASSESX + 63) / 64), 256, 0, stream>>>(
      adj, t1, nullptr, y1, N_CLASSESX, 1024, N_CLASSESX);
  gemm_nn<0, false><<<dim3((1024 + 63) / 64, (N_CLASSESX + 63) / 64), 256, 0, stream>>>(
      y1, W_gc2, nullptr, t2, N_CLASSESX, 1024, 1024);
  gemm_nn<0, false><<<dim3((1024 + 63) / 64, (N_CLASSESX + 63) / 64), 256, 0, stream>>>(
      adj, t2, nullptr, ybuf, N_CLASSESX, 1024, N_CLASSESX);
  // out = fc2o @ ybuf^T
  k_out<<<(N_GRAPHSX * N_CLASSESX + 255) / 256, 256, 0, stream>>>(fc2o, ybuf, out);
}

// Round 3
// 2142.767 us; speedup vs baseline: 1.1055x; 1.0773x over previous
//
#include <hip/hip_runtime.h>

#define N_NODESX 30000
#define N_EDGES0 300000
#define N_E      330000
#define N_GRAPHSX 64
#define N_CLASSESX 100
#define F_XDX 78
#define HEADSX 10
#define HIDX 780
#define IN_CHX 300
#define KP_GAT 96    // ceil(78/32)*32
#define KP_GCN 800   // ceil(780/32)*32

typedef __attribute__((ext_vector_type(8))) short short8v;
typedef __attribute__((ext_vector_type(8))) unsigned short ushort8v;
typedef __attribute__((ext_vector_type(4))) float f32x4;

// ---------- bf16 split helpers ----------
__device__ inline unsigned short f2bf_rne(float f) {
  unsigned u = __float_as_uint(f);
  unsigned r = (u + 0x7FFFu + ((u >> 16) & 1u)) >> 16;
  return (unsigned short)r;
}
__device__ inline float bf2f(unsigned short h) {
  return __uint_as_float(((unsigned)h) << 16);
}
__device__ inline void splitbf(float v, unsigned short& h, unsigned short& l) {
  unsigned short hh = f2bf_rne(v);
  h = hh;
  l = f2bf_rne(v - bf2f(hh));
}

// ---------- split fp32 matrix (M x K, row-major) into hi/lo bf16 planes (M x Kp, zero pad) ----------
__global__ void k_split_pad(const float* __restrict__ X, int M, int K, int Kp,
                            unsigned short* __restrict__ Ph, unsigned short* __restrict__ Pl) {
  int idx = blockIdx.x * 256 + threadIdx.x;
  int packs = Kp >> 3;
  if (idx >= M * packs) return;
  int row = idx / packs, p = idx - row * packs;
  ushort8v h, l;
  #pragma unroll
  for (int j = 0; j < 8; j++) {
    int k = p * 8 + j;
    float v = (k < K) ? X[(size_t)row * K + k] : 0.f;
    unsigned short hh, ll;
    splitbf(v, hh, ll);
    h[j] = hh; l[j] = ll;
  }
  *(ushort8v*)&Ph[(size_t)row * Kp + p * 8] = h;
  *(ushort8v*)&Pl[(size_t)row * Kp + p * 8] = l;
}

// ---------- split + transpose: W (K x N) -> planes (N x Kp) ----------
__global__ void k_splitT(const float* __restrict__ W, int K, int N, int Kp,
                         unsigned short* __restrict__ Th, unsigned short* __restrict__ Tl) {
  int idx = blockIdx.x * 256 + threadIdx.x;
  int packs = Kp >> 3;
  if (idx >= N * packs) return;
  int n = idx / packs, p = idx - n * packs;
  ushort8v h, l;
  #pragma unroll
  for (int j = 0; j < 8; j++) {
    int k = p * 8 + j;
    float v = (k < K) ? W[(size_t)k * N + n] : 0.f;
    unsigned short hh, ll;
    splitbf(v, hh, ll);
    h[j] = hh; l[j] = ll;
  }
  *(ushort8v*)&Th[(size_t)n * Kp + p * 8] = h;
  *(ushort8v*)&Tl[(size_t)n * Kp + p * 8] = l;
}

// ---------- MFMA split-bf16 GEMM: C[M,N] = A[M,K] @ B[K,N] ----------
// A given as hi/lo planes (M x Kp), B as TRANSPOSED hi/lo planes (N x Kp).
// 3-product: AhBh + AhBl + AlBh. Tile 128x128xBK32, 256 threads (4 waves, 2x2).
__global__ __launch_bounds__(256)
void gemm_mfma3(const unsigned short* __restrict__ Ah, const unsigned short* __restrict__ Al,
                const unsigned short* __restrict__ Bh, const unsigned short* __restrict__ Bl,
                float* __restrict__ C, int M, int N, int Kp) {
  __shared__ unsigned short lds[4 * 4096];  // planes: Ah, Al, Bh, Bl; fragment-order
  const int tid  = threadIdx.x;
  const int lane = tid & 63;
  const int w    = tid >> 6;
  const int wr   = w >> 1, wc = w & 1;
  const int bm = blockIdx.y * 128;
  const int bn = blockIdx.x * 128;

  f32x4 acc[4][4];
  #pragma unroll
  for (int m = 0; m < 4; m++)
    #pragma unroll
    for (int n = 0; n < 4; n++) acc[m][n] = (f32x4){0.f, 0.f, 0.f, 0.f};

  const unsigned short* srcs[4] = {Ah, Al, Bh, Bl};

  for (int k0 = 0; k0 < Kp; k0 += 32) {
    __syncthreads();
    // stage 2048 16B packets (4 planes x 512), 8 per thread, plane compile-time per i
    #pragma unroll
    for (int i = 0; i < 8; i++) {
      const int plane = i >> 1;                 // compile-time after unroll
      const int q  = ((i & 1) << 8) + tid;      // 0..511
      const int fm = q >> 6;
      const int rr = q & 63;                    // ks*16 + r16
      const int ks = rr >> 4, r16 = rr & 15;
      const int rowbase = (plane < 2) ? bm : bn;
      const int lim     = (plane < 2) ? M : N;
      const int row = rowbase + fm * 16 + r16;
      ushort8v v = (ushort8v){0,0,0,0,0,0,0,0};
      if (row < lim)
        v = *(const ushort8v*)(srcs[plane] + (size_t)row * Kp + k0 + ks * 8);
      *(ushort8v*)&lds[(size_t)plane * 4096 + (size_t)q * 8] = v;
    }
    __syncthreads();

    short8v afh[4], afl[4], bfh[4], bfl[4];
    #pragma unroll
    for (int m = 0; m < 4; m++) {
      int fmA = wr * 4 + m;
      afh[m] = *(const short8v*)&lds[0 * 4096 + fmA * 512 + lane * 8];
      afl[m] = *(const short8v*)&lds[1 * 4096 + fmA * 512 + lane * 8];
    }
    #pragma unroll
    for (int n = 0; n < 4; n++) {
      int fnB = wc * 4 + n;
      bfh[n] = *(const short8v*)&lds[2 * 4096 + fnB * 512 + lane * 8];
      bfl[n] = *(const short8v*)&lds[3 * 4096 + fnB * 512 + lane * 8];
    }
    #pragma unroll
    for (int m = 0; m < 4; m++) {
      #pragma unroll
      for (int n = 0; n < 4; n++) {
        acc[m][n] = __builtin_amdgcn_mfma_f32_16x16x32_bf16(afh[m], bfh[n], acc[m][n], 0, 0, 0);
        acc[m][n] = __builtin_amdgcn_mfma_f32_16x16x32_bf16(afh[m], bfl[n], acc[m][n], 0, 0, 0);
        acc[m][n] = __builtin_amdgcn_mfma_f32_16x16x32_bf16(afl[m], bfh[n], acc[m][n], 0, 0, 0);
      }
    }
  }

  // epilogue: C/D layout col = lane&15, row = (lane>>4)*4 + r  [m89-verified]
  const int r0 = (lane >> 4) * 4;
  const int cc = lane & 15;
  #pragma unroll
  for (int m = 0; m < 4; m++) {
    #pragma unroll
    for (int n = 0; n < 4; n++) {
      int gcol = bn + (wc * 4 + n) * 16 + cc;
      if (gcol >= N) continue;
      #pragma unroll
      for (int r = 0; r < 4; r++) {
        int grow = bm + (wr * 4 + m) * 16 + r0 + r;
        if (grow < M) C[(size_t)grow * N + gcol] = acc[m][n][r];
      }
    }
  }
}

// ---------- generic fp32 NN GEMM (small sizes): C[M,N]=A@B (+bias, act) ----------
template<int ACT, bool HAS_BIAS>
__global__ __launch_bounds__(256)
void gemm_nn(const float* __restrict__ A, const float* __restrict__ B,
             const float* __restrict__ bias, float* __restrict__ C,
             int M, int N, int K) {
  __shared__ float As[16][64];
  __shared__ float Bs[16][64];
  int tid = threadIdx.x;
  int bm = blockIdx.y * 64;
  int bn = blockIdx.x * 64;
  int tr = tid >> 4;
  int tc = tid & 15;
  float acc[4][4] = {{0.f}};
  int la_m = tid >> 2;
  int la_k = (tid & 3) << 2;
  int lb_k4 = (tid >> 6) << 2;
  int lb_n = tid & 63;

  for (int k0 = 0; k0 < K; k0 += 16) {
    {
      int gm = bm + la_m;
      bool mok = gm < M;
      const float* ap = A + (long)gm * K + k0 + la_k;
      #pragma unroll
      for (int q = 0; q < 4; q++) {
        int kk = la_k + q;
        As[kk][la_m] = (mok && (k0 + kk) < K) ? ap[q] : 0.f;
      }
    }
    {
      int gn = bn + lb_n;
      #pragma unroll
      for (int q = 0; q < 4; q++) {
        int kk = lb_k4 + q;
        int gk = k0 + kk;
        Bs[kk][lb_n] = (gk < K && gn < N) ? B[(long)gk * N + gn] : 0.f;
      }
    }
    __syncthreads();
    #pragma unroll
    for (int kk = 0; kk < 16; kk++) {
      float a0 = As[kk][tr*4+0], a1 = As[kk][tr*4+1],
            a2 = As[kk][tr*4+2], a3 = As[kk][tr*4+3];
      float b0 = Bs[kk][tc*4+0], b1 = Bs[kk][tc*4+1],
            b2 = Bs[kk][tc*4+2], b3 = Bs[kk][tc*4+3];
      acc[0][0] += a0*b0; acc[0][1] += a0*b1; acc[0][2] += a0*b2; acc[0][3] += a0*b3;
      acc[1][0] += a1*b0; acc[1][1] += a1*b1; acc[1][2] += a1*b2; acc[1][3] += a1*b3;
      acc[2][0] += a2*b0; acc[2][1] += a2*b1; acc[2][2] += a2*b2; acc[2][3] += a2*b3;
      acc[3][0] += a3*b0; acc[3][1] += a3*b1; acc[3][2] += a3*b2; acc[3][3] += a3*b3;
    }
    __syncthreads();
  }
  #pragma unroll
  for (int i = 0; i < 4; i++) {
    int gm = bm + tr*4 + i;
    if (gm >= M) continue;
    #pragma unroll
    for (int j = 0; j < 4; j++) {
      int gn = bn + tc*4 + j;
      if (gn >= N) continue;
      float v = acc[i][j];
      if (HAS_BIAS) v += bias[gn];
      if (ACT == 1) v = fmaxf(v, 0.f);
      else if (ACT == 2) v = v > 0.f ? v : 0.2f * v;
      C[(long)gm * N + gn] = v;
    }
  }
}

// ---------- attention logits per (node, head), float2 ----------
__global__ void k_al(const float* __restrict__ h, const float* __restrict__ a_src,
                     const float* __restrict__ a_dst,
                     float* __restrict__ al_s, float* __restrict__ al_d) {
  int idx = blockIdx.x * 256 + threadIdx.x;
  if (idx >= N_NODESX * HEADSX) return;
  int n = idx / HEADSX, hd = idx % HEADSX;
  const float2* hp  = (const float2*)(h + (size_t)n * HIDX + hd * F_XDX);
  const float2* as2 = (const float2*)(a_src + hd * F_XDX);
  const float2* ad2 = (const float2*)(a_dst + hd * F_XDX);
  float s1 = 0.f, s2 = 0.f;
  #pragma unroll 13
  for (int i = 0; i < F_XDX / 2; i++) {
    float2 v = hp[i], a = as2[i], d = ad2[i];
    s1 += v.x * a.x + v.y * a.y;
    s2 += v.x * d.x + v.y * d.y;
  }
  al_s[idx] = s1; al_d[idx] = s2;
}

// ---------- CSR build ----------
__global__ void k_count(const int* __restrict__ ei, int* __restrict__ counts) {
  int e = blockIdx.x * 256 + threadIdx.x;
  if (e >= N_E) return;
  int dst = (e < N_EDGES0) ? ei[N_EDGES0 + e] : (e - N_EDGES0);
  atomicAdd(&counts[dst], 1);
}

__global__ void k_scan(const int* __restrict__ cnt, int* __restrict__ row_ptr) {
  __shared__ int part[1024];
  int tid = threadIdx.x;
  const int CH = 30;
  int b0 = tid * CH;
  int s = 0;
  for (int i = 0; i < CH; i++) { int g = b0 + i; if (g < N_NODESX) s += cnt[g]; }
  part[tid] = s;
  __syncthreads();
  for (int off = 1; off < 1024; off <<= 1) {
    int v = (tid >= off) ? part[tid - off] : 0;
    __syncthreads();
    part[tid] += v;
    __syncthreads();
  }
  int pre = (tid > 0) ? part[tid - 1] : 0;
  for (int i = 0; i < CH; i++) {
    int g = b0 + i;
    if (g < N_NODESX) { row_ptr[g] = pre; pre += cnt[g]; }
  }
  if (tid == 1023) row_ptr[N_NODESX] = part[1023];
}

__global__ void k_fill(const int* __restrict__ ei, const int* __restrict__ row_ptr,
                       int* __restrict__ cursor, int* __restrict__ csr_src,
                       int* __restrict__ csr_eid) {
  int e = blockIdx.x * 256 + threadIdx.x;
  if (e >= N_E) return;
  int src, dst;
  if (e < N_EDGES0) { src = ei[e]; dst = ei[N_EDGES0 + e]; }
  else { src = dst = e - N_EDGES0; }
  int pos = row_ptr[dst] + atomicAdd(&cursor[dst], 1);
  csr_src[pos] = src;
  csr_eid[pos] = e;
}

// ---------- edge softmax (no max shift: logits bounded) ----------
__global__ void k_edge_exp(const int* __restrict__ ei, const float* __restrict__ al_s,
                           const float* __restrict__ al_d,
                           float* __restrict__ e_edge, float* __restrict__ den) {
  int e = blockIdx.x * 256 + threadIdx.x;
  if (e >= N_E) return;
  int src, dst;
  if (e < N_EDGES0) { src = ei[e]; dst = ei[N_EDGES0 + e]; }
  else { src = dst = e - N_EDGES0; }
  const float* ps = al_s + (size_t)src * HEADSX;
  const float* pd = al_d + (size_t)dst * HEADSX;
  float* pe = e_edge + (size_t)e * HEADSX;
  #pragma unroll
  for (int hd = 0; hd < HEADSX; hd++) {
    float v = ps[hd] + pd[hd];
    v = v > 0.f ? v : 0.2f * v;
    float ex = expf(v);
    pe[hd] = ex;
    atomicAdd(&den[dst * HEADSX + hd], ex);
  }
}

// ---------- GAT aggregation (gather per dst); writes bf16 hi/lo planes (M x KP_GCN) ----------
__global__ __launch_bounds__(256)
void k_gat_agg(const float* __restrict__ h, const float* __restrict__ exe,
               const float* __restrict__ den, const int* __restrict__ row_ptr,
               const int* __restrict__ csr_src, const int* __restrict__ csr_eid,
               const float* __restrict__ b_gat,
               unsigned short* __restrict__ xgh, unsigned short* __restrict__ xgl) {
  __shared__ float id[HEADSX];
  int d = blockIdx.x, t = threadIdx.x;
  if (t < HEADSX) id[t] = 1.f / (den[d * HEADSX + t] + 1e-16f);
  __syncthreads();
  if (t >= 200) return;
  if (t >= 195) {  // zero the K padding 780..799
    int c = 780 + (t - 195) * 4;
    ushort4 z = make_ushort4(0, 0, 0, 0);
    *(ushort4*)(xgh + (size_t)d * KP_GCN + c) = z;
    *(ushort4*)(xgl + (size_t)d * KP_GCN + c) = z;
    return;
  }
  int c = t * 4;
  int ha = c / F_XDX;
  int hb = (c + 3) / F_XDX;
  int split = (ha + 1) * F_XDX - c;
  float idA = id[ha], idB = id[hb];
  float4 acc = {0.f, 0.f, 0.f, 0.f};
  int beg = row_ptr[d], end = row_ptr[d + 1];
  for (int j = beg; j < end; j++) {
    int s = csr_src[j];
    int eid = csr_eid[j];
    const float* er = exe + (size_t)eid * HEADSX;
    float aA = er[ha] * idA;
    float aB = (hb != ha) ? er[hb] * idB : aA;
    float w0 = (split > 0) ? aA : aB;
    float w1 = (split > 1) ? aA : aB;
    float w2 = (split > 2) ? aA : aB;
    float w3 = (split > 3) ? aA : aB;
    float4 hv = *(const float4*)(h + (size_t)s * HIDX + c);
    acc.x += w0 * hv.x; acc.y += w1 * hv.y; acc.z += w2 * hv.z; acc.w += w3 * hv.w;
  }
  float4 bb = *(const float4*)(b_gat + c);
  float v0 = fmaxf(acc.x + bb.x, 0.f);
  float v1 = fmaxf(acc.y + bb.y, 0.f);
  float v2 = fmaxf(acc.z + bb.z, 0.f);
  float v3 = fmaxf(acc.w + bb.w, 0.f);
  ushort4 h4, l4;
  splitbf(v0, h4.x, l4.x); splitbf(v1, h4.y, l4.y);
  splitbf(v2, h4.z, l4.z); splitbf(v3, h4.w, l4.w);
  *(ushort4*)(xgh + (size_t)d * KP_GCN + c) = h4;
  *(ushort4*)(xgl + (size_t)d * KP_GCN + c) = l4;
}

// ---------- degree inv sqrt ----------
__global__ void k_dinv(const int* __restrict__ counts, float* __restrict__ dinv) {
  int n = blockIdx.x * 256 + threadIdx.x;
  if (n < N_NODESX) dinv[n] = rsqrtf(fmaxf((float)counts[n], 1.f));
}

// ---------- GCN aggregation (gather per dst, float4) ----------
__global__ __launch_bounds__(256)
void k_gcn_agg(const float* __restrict__ s, const float* __restrict__ dinv,
               const int* __restrict__ row_ptr, const int* __restrict__ csr_src,
               const float* __restrict__ b_gcn, float* __restrict__ out) {
  int d = blockIdx.x, t = threadIdx.x;
  if (t >= HIDX / 4) return;
  int c = t * 4;
  float4 acc = {0.f, 0.f, 0.f, 0.f};
  int beg = row_ptr[d], end = row_ptr[d + 1];
  for (int j = beg; j < end; j++) {
    int si = csr_src[j];
    float w = dinv[si];
    float4 sv = *(const float4*)(s + (size_t)si * HIDX + c);
    acc.x += w * sv.x; acc.y += w * sv.y; acc.z += w * sv.z; acc.w += w * sv.w;
  }
  float dd = dinv[d];
  float4 bb = *(const float4*)(b_gcn + c);
  float4 r;
  r.x = fmaxf(acc.x * dd + bb.x, 0.f);
  r.y = fmaxf(acc.y * dd + bb.y, 0.f);
  r.z = fmaxf(acc.z * dd + bb.z, 0.f);
  r.w = fmaxf(acc.w * dd + bb.w, 0.f);
  *(float4*)(out + (size_t)d * HIDX + c) = r;
}

// ---------- per-graph ranges ----------
__global__ void k_range_init(int* __restrict__ gstart, int* __restrict__ gend) {
  int g = threadIdx.x;
  if (g < N_GRAPHSX) { gstart[g] = 0x7FFFFFFF; gend[g] = 0; }
}
__global__ void k_ranges(const int* __restrict__ batch, int* __restrict__ gstart,
                         int* __restrict__ gend) {
  int n = blockIdx.x * 256 + threadIdx.x;
  if (n >= N_NODESX) return;
  int b = batch[n];
  atomicMin(&gstart[b], n);
  atomicMax(&gend[b], n + 1);
}

// ---------- pooling: max + mean per graph, float4 ----------
__global__ __launch_bounds__(256)
void k_pool(const float* __restrict__ xg2, const int* __restrict__ gstart,
            const int* __restrict__ gend, float* __restrict__ xf) {
  int g = blockIdx.x, t = threadIdx.x;
  if (t >= HIDX / 4) return;
  int c = t * 4;
  int st = gstart[g], en = gend[g];
  float4 mx = {0.f, 0.f, 0.f, 0.f};
  float4 sm = {0.f, 0.f, 0.f, 0.f};
  for (int n = st; n < en; n++) {
    float4 v = *(const float4*)(xg2 + (size_t)n * HIDX + c);
    mx.x = fmaxf(mx.x, v.x); sm.x += v.x;
    mx.y = fmaxf(mx.y, v.y); sm.y += v.y;
    mx.z = fmaxf(mx.z, v.z); sm.z += v.z;
    mx.w = fmaxf(mx.w, v.w); sm.w += v.w;
  }
  float inv = (en > st) ? 1.f / (float)(en - st) : 0.f;
  float* xr = xf + (size_t)g * (2 * HIDX);
  float4 mean; mean.x = sm.x*inv; mean.y = sm.y*inv; mean.z = sm.z*inv; mean.w = sm.w*inv;
  *(float4*)(xr + c) = mx;
  *(float4*)(xr + HIDX + c) = mean;
}

// ---------- label branch ----------
__global__ void k_dvec(const float* __restrict__ A, float* __restrict__ dvec) {
  int i = blockIdx.x * 64 + threadIdx.x;
  if (i >= N_CLASSESX) return;
  float s = 0.f;
  for (int j = 0; j < N_CLASSESX; j++) s += A[i * N_CLASSESX + j];
  dvec[i] = rsqrtf(s);
}
__global__ void k_adj(const float* __restrict__ A, const float* __restrict__ dvec,
                      float* __restrict__ adj) {
  int idx = blockIdx.x * 256 + threadIdx.x;
  if (idx >= N_CLASSESX * N_CLASSESX) return;
  int i = idx / N_CLASSESX, j = idx % N_CLASSESX;
  adj[idx] = dvec[i] * A[j * N_CLASSESX + i] * dvec[j];
}

// ---------- final out = xf2 @ y^T, float4 ----------
__global__ void k_out(const float* __restrict__ xf2, const float* __restrict__ y,
                      float* __restrict__ out) {
  int idx = blockIdx.x * 256 + threadIdx.x;
  if (idx >= N_GRAPHSX * N_CLASSESX) return;
  int b = idx / N_CLASSESX, c = idx % N_CLASSESX;
  const float4* xr = (const float4*)(xf2 + (size_t)b * 1024);
  const float4* yr = (const float4*)(y + (size_t)c * 1024);
  float s = 0.f;
  #pragma unroll 8
  for (int k = 0; k < 256; k++) {
    float4 xv = xr[k], yv = yr[k];
    s += xv.x*yv.x + xv.y*yv.y + xv.z*yv.z + xv.w*yv.w;
  }
  out[idx] = s;
}

// =======================================================================
extern "C" void kernel_launch(void* const* d_in, const int* in_sizes, int n_in,
                              void* d_out, int out_size, void* d_ws, size_t ws_size,
                              hipStream_t stream) {
  const float* x     = (const float*)d_in[0];
  const int*   ei    = (const int*)d_in[1];
  const int*   batch = (const int*)d_in[2];
  const float* inp   = (const float*)d_in[3];
  const float* W_gat = (const float*)d_in[4];
  const float* a_src = (const float*)d_in[5];
  const float* a_dst = (const float*)d_in[6];
  const float* b_gat = (const float*)d_in[7];
  const float* W_gcn = (const float*)d_in[8];
  const float* b_gcn = (const float*)d_in[9];
  const float* W_fc1 = (const float*)d_in[10];
  const float* b_fc1 = (const float*)d_in[11];
  const float* W_fc2 = (const float*)d_in[12];
  const float* b_fc2 = (const float*)d_in[13];
  const float* W_gc1 = (const float*)d_in[14];
  const float* W_gc2 = (const float*)d_in[15];
  const float* A     = (const float*)d_in[16];
  float* out = (float*)d_out;

  char* ws = (char*)d_ws;
  size_t off = 0;
  auto alloc = [&](size_t bytes) -> void* {
    void* p = ws + off;
    off = (off + bytes + 255) & ~(size_t)255;
    return p;
  };

  float* bufA   = (float*)alloc(sizeof(float) * (size_t)N_NODESX * HIDX); // h, then s
  float* bufB   = (float*)alloc(sizeof(float) * (size_t)N_NODESX * HIDX); // xgh alias, then xg2
  float* e_edge = (float*)alloc(sizeof(float) * (size_t)N_E * HEADSX);    // also aliases xh/xl
  float* al_s   = (float*)alloc(sizeof(float) * N_NODESX * HEADSX);
  float* al_d   = (float*)alloc(sizeof(float) * N_NODESX * HEADSX);
  float* den    = (float*)alloc(sizeof(float) * N_NODESX * HEADSX);
  int* counts   = (int*)alloc(sizeof(int) * N_NODESX);
  int* row_ptr  = (int*)alloc(sizeof(int) * (N_NODESX + 1));
  int* cursor   = (int*)alloc(sizeof(int) * N_NODESX);
  int* csr_src  = (int*)alloc(sizeof(int) * N_E);
  int* csr_eid  = (int*)alloc(sizeof(int) * N_E);
  float* dinv   = (float*)alloc(sizeof(float) * N_NODESX);
  int* gstart   = (int*)alloc(sizeof(int) * N_GRAPHSX);
  int* gend     = (int*)alloc(sizeof(int) * N_GRAPHSX);
  float* xf     = (float*)alloc(sizeof(float) * N_GRAPHSX * 2 * HIDX);
  float* fc1o   = (float*)alloc(sizeof(float) * N_GRAPHSX * 1500);
  float* fc2o   = (float*)alloc(sizeof(float) * N_GRAPHSX * 1024);
  float* t1     = (float*)alloc(sizeof(float) * N_CLASSESX * 1024);
  float* adj    = (float*)alloc(sizeof(float) * N_CLASSESX * N_CLASSESX);
  float* dvec   = (float*)alloc(sizeof(float) * N_CLASSESX);
  float* y1     = (float*)alloc(sizeof(float) * N_CLASSESX * 1024);
  float* t2     = (float*)alloc(sizeof(float) * N_CLASSESX * 1024);
  float* ybuf   = (float*)alloc(sizeof(float) * N_CLASSESX * 1024);
  // bf16 split planes
  unsigned short* wgTh = (unsigned short*)alloc(sizeof(short) * (size_t)HIDX * KP_GAT);
  unsigned short* wgTl = (unsigned short*)alloc(sizeof(short) * (size_t)HIDX * KP_GAT);
  unsigned short* wcTh = (unsigned short*)alloc(sizeof(short) * (size_t)HIDX * KP_GCN);
  unsigned short* wcTl = (unsigned short*)alloc(sizeof(short) * (size_t)HIDX * KP_GCN);
  unsigned short* xgl  = (unsigned short*)alloc(sizeof(short) * (size_t)N_NODESX * KP_GCN);
  // aliases (lifetimes disjoint):
  unsigned short* xh  = (unsigned short*)e_edge;                    // 30000x96, dead before e_edge written
  unsigned short* xl  = xh + (size_t)N_NODESX * KP_GAT;
  unsigned short* xgh = (unsigned short*)bufB;                      // 30000x800, dead before xg2 written
  (void)ws_size; (void)in_sizes; (void)n_in; (void)out_size;

  hipMemsetAsync(den, 0, sizeof(float) * N_NODESX * HEADSX, stream);
  hipMemsetAsync(counts, 0, sizeof(int) * N_NODESX, stream);
  hipMemsetAsync(cursor, 0, sizeof(int) * N_NODESX, stream);

  // split conversions
  k_split_pad<<<(N_NODESX * (KP_GAT/8) + 255) / 256, 256, 0, stream>>>(x, N_NODESX, F_XDX, KP_GAT, xh, xl);
  k_splitT<<<(HIDX * (KP_GAT/8) + 255) / 256, 256, 0, stream>>>(W_gat, F_XDX, HIDX, KP_GAT, wgTh, wgTl);
  k_splitT<<<(HIDX * (KP_GCN/8) + 255) / 256, 256, 0, stream>>>(W_gcn, HIDX, HIDX, KP_GCN, wcTh, wcTl);

  // h = x @ W_gat  (MFMA split-bf16)
  gemm_mfma3<<<dim3((HIDX + 127) / 128, (N_NODESX + 127) / 128), 256, 0, stream>>>(
      xh, xl, wgTh, wgTl, bufA, N_NODESX, HIDX, KP_GAT);
  // attention logits
  k_al<<<(N_NODESX * HEADSX + 255) / 256, 256, 0, stream>>>(bufA, a_src, a_dst, al_s, al_d);
  // CSR
  k_count<<<(N_E + 255) / 256, 256, 0, stream>>>(ei, counts);
  k_scan<<<1, 1024, 0, stream>>>(counts, row_ptr);
  k_fill<<<(N_E + 255) / 256, 256, 0, stream>>>(ei, row_ptr, cursor, csr_src, csr_eid);
  // edge softmax
  k_edge_exp<<<(N_E + 255) / 256, 256, 0, stream>>>(ei, al_s, al_d, e_edge, den);
  // GAT aggregate -> xg split planes
  k_gat_agg<<<N_NODESX, 256, 0, stream>>>(bufA, e_edge, den, row_ptr, csr_src, csr_eid,
                                          b_gat, xgh, xgl);
  // GCN
  k_dinv<<<(N_NODESX + 255) / 256, 256, 0, stream>>>(counts, dinv);
  gemm_mfma3<<<dim3((HIDX + 127) / 128, (N_NODESX + 127) / 128), 256, 0, stream>>>(
      xgh, xgl, wcTh, wcTl, bufA, N_NODESX, HIDX, KP_GCN);          // s -> bufA
  k_gcn_agg<<<N_NODESX, 256, 0, stream>>>(bufA, dinv, row_ptr, csr_src, b_gcn, bufB); // xg2
  // pooling
  k_range_init<<<1, 64, 0, stream>>>(gstart, gend);
  k_ranges<<<(N_NODESX + 255) / 256, 256, 0, stream>>>(batch, gstart, gend);
  k_pool<<<N_GRAPHSX, 256, 0, stream>>>(bufB, gstart, gend, xf);
  // dense head
  gemm_nn<1, true><<<dim3((1500 + 63) / 64, (N_GRAPHSX + 63) / 64), 256, 0, stream>>>(
      xf, W_fc1, b_fc1, fc1o, N_GRAPHSX, 1500, 2 * HIDX);
  gemm_nn<0, true><<<dim3((1024 + 63) / 64, (N_GRAPHSX + 63) / 64), 256, 0, stream>>>(
      fc1o, W_fc2, b_fc2, fc2o, N_GRAPHSX, 1024, 1500);
  // label branch
  k_dvec<<<(N_CLASSESX + 63) / 64, 64, 0, stream>>>(A, dvec);
  k_adj<<<(N_CLASSESX * N_CLASSESX + 255) / 256, 256, 0, stream>>>(A, dvec, adj);
  gemm_nn<0, false><<<dim3((1024 + 63) / 64, (N_CLASSESX + 63) / 64), 256, 0, stream>>>(
      inp, W_gc1, nullptr, t1, N_CLASSESX, 1024, IN_CHX);
  gemm_nn<2, false><<<dim3((1024 + 63) / 64, (N_CLASSESX + 63) / 64), 256, 0, stream>>>(
      adj, t1, nullptr, y1, N_CLASSESX, 1024, N_CLASSESX);
  gemm_nn<0, false><<<dim3((1024 + 63) / 64, (N_CLASSESX + 63) / 64), 256, 0, stream>>>(
      y1, W_gc2, nullptr, t2, N_CLASSESX, 1024, 1024);
  gemm_nn<0, false><<<dim3((1024 + 63) / 64, (N_CLASSESX + 63) / 64), 256, 0, stream>>>(
      adj, t2, nullptr, ybuf, N_CLASSESX, 1024, N_CLASSESX);
  // out = fc2o @ ybuf^T
  k_out<<<(N_GRAPHSX * N_CLASSESX + 255) / 256, 256, 0, stream>>>(fc2o, ybuf, out);
}

// Round 4
// 1446.688 us; speedup vs baseline: 1.6375x; 1.4812x over previous
//
#include <hip/hip_runtime.h>

#define N_NODESX 30000
#define N_EDGES0 300000
#define N_E      330000
#define N_GRAPHSX 64
#define N_CLASSESX 100
#define F_XDX 78
#define HEADSX 10
#define HIDX 780
#define IN_CHX 300
#define KP_GAT 96    // ceil(78/32)*32
#define KP_GCN 800   // ceil(780/32)*32

typedef __attribute__((ext_vector_type(8))) short short8v;
typedef __attribute__((ext_vector_type(8))) unsigned short ushort8v;
typedef __attribute__((ext_vector_type(4))) float f32x4;

// ---------- bf16 split helpers ----------
__device__ inline unsigned short f2bf_rne(float f) {
  unsigned u = __float_as_uint(f);
  unsigned r = (u + 0x7FFFu + ((u >> 16) & 1u)) >> 16;
  return (unsigned short)r;
}
__device__ inline float bf2f(unsigned short h) {
  return __uint_as_float(((unsigned)h) << 16);
}
__device__ inline void splitbf(float v, unsigned short& h, unsigned short& l) {
  unsigned short hh = f2bf_rne(v);
  h = hh;
  l = f2bf_rne(v - bf2f(hh));
}

// ---------- split fp32 matrix (M x K, row-major) into hi/lo bf16 planes (M x Kp, zero pad) ----------
__global__ void k_split_pad(const float* __restrict__ X, int M, int K, int Kp,
                            unsigned short* __restrict__ Ph, unsigned short* __restrict__ Pl) {
  int idx = blockIdx.x * 256 + threadIdx.x;
  int packs = Kp >> 3;
  if (idx >= M * packs) return;
  int row = idx / packs, p = idx - row * packs;
  ushort8v h, l;
  #pragma unroll
  for (int j = 0; j < 8; j++) {
    int k = p * 8 + j;
    float v = (k < K) ? X[(size_t)row * K + k] : 0.f;
    unsigned short hh, ll;
    splitbf(v, hh, ll);
    h[j] = hh; l[j] = ll;
  }
  *(ushort8v*)&Ph[(size_t)row * Kp + p * 8] = h;
  *(ushort8v*)&Pl[(size_t)row * Kp + p * 8] = l;
}

// ---------- split + transpose: W (K x N) -> planes (N x Kp) ----------
__global__ void k_splitT(const float* __restrict__ W, int K, int N, int Kp,
                         unsigned short* __restrict__ Th, unsigned short* __restrict__ Tl) {
  int idx = blockIdx.x * 256 + threadIdx.x;
  int packs = Kp >> 3;
  if (idx >= N * packs) return;
  int n = idx / packs, p = idx - n * packs;
  ushort8v h, l;
  #pragma unroll
  for (int j = 0; j < 8; j++) {
    int k = p * 8 + j;
    float v = (k < K) ? W[(size_t)k * N + n] : 0.f;
    unsigned short hh, ll;
    splitbf(v, hh, ll);
    h[j] = hh; l[j] = ll;
  }
  *(ushort8v*)&Th[(size_t)n * Kp + p * 8] = h;
  *(ushort8v*)&Tl[(size_t)n * Kp + p * 8] = l;
}

// ---------- MFMA split-bf16 GEMM: C[M,N] = A[M,K] @ B[K,N] ----------
// A as hi/lo planes (M x Kp), B as TRANSPOSED hi/lo planes (N x Kp).
// 3-product: AhBh + AhBl + AlBh. Tile 128x128xBK32, 256 threads (4 waves, 2x2).
__global__ __launch_bounds__(256)
void gemm_mfma3(const unsigned short* __restrict__ Ah, const unsigned short* __restrict__ Al,
                const unsigned short* __restrict__ Bh, const unsigned short* __restrict__ Bl,
                float* __restrict__ C, int M, int N, int Kp) {
  __shared__ unsigned short lds[4 * 4096];  // planes: Ah, Al, Bh, Bl; fragment-order
  const int tid  = threadIdx.x;
  const int lane = tid & 63;
  const int w    = tid >> 6;
  const int wr   = w >> 1, wc = w & 1;
  const int bm = blockIdx.y * 128;
  const int bn = blockIdx.x * 128;

  f32x4 acc[4][4];
  #pragma unroll
  for (int m = 0; m < 4; m++)
    #pragma unroll
    for (int n = 0; n < 4; n++) acc[m][n] = (f32x4){0.f, 0.f, 0.f, 0.f};

  const unsigned short* srcs[4] = {Ah, Al, Bh, Bl};

  for (int k0 = 0; k0 < Kp; k0 += 32) {
    __syncthreads();
    #pragma unroll
    for (int i = 0; i < 8; i++) {
      const int plane = i >> 1;
      const int q  = ((i & 1) << 8) + tid;      // 0..511
      const int fm = q >> 6;
      const int rr = q & 63;
      const int ks = rr >> 4, r16 = rr & 15;
      const int rowbase = (plane < 2) ? bm : bn;
      const int lim     = (plane < 2) ? M : N;
      const int row = rowbase + fm * 16 + r16;
      ushort8v v = (ushort8v){0,0,0,0,0,0,0,0};
      if (row < lim)
        v = *(const ushort8v*)(srcs[plane] + (size_t)row * Kp + k0 + ks * 8);
      *(ushort8v*)&lds[(size_t)plane * 4096 + (size_t)q * 8] = v;
    }
    __syncthreads();

    short8v afh[4], afl[4], bfh[4], bfl[4];
    #pragma unroll
    for (int m = 0; m < 4; m++) {
      int fmA = wr * 4 + m;
      afh[m] = *(const short8v*)&lds[0 * 4096 + fmA * 512 + lane * 8];
      afl[m] = *(const short8v*)&lds[1 * 4096 + fmA * 512 + lane * 8];
    }
    #pragma unroll
    for (int n = 0; n < 4; n++) {
      int fnB = wc * 4 + n;
      bfh[n] = *(const short8v*)&lds[2 * 4096 + fnB * 512 + lane * 8];
      bfl[n] = *(const short8v*)&lds[3 * 4096 + fnB * 512 + lane * 8];
    }
    #pragma unroll
    for (int m = 0; m < 4; m++) {
      #pragma unroll
      for (int n = 0; n < 4; n++) {
        acc[m][n] = __builtin_amdgcn_mfma_f32_16x16x32_bf16(afh[m], bfh[n], acc[m][n], 0, 0, 0);
        acc[m][n] = __builtin_amdgcn_mfma_f32_16x16x32_bf16(afh[m], bfl[n], acc[m][n], 0, 0, 0);
        acc[m][n] = __builtin_amdgcn_mfma_f32_16x16x32_bf16(afl[m], bfh[n], acc[m][n], 0, 0, 0);
      }
    }
  }

  const int r0 = (lane >> 4) * 4;
  const int cc = lane & 15;
  #pragma unroll
  for (int m = 0; m < 4; m++) {
    #pragma unroll
    for (int n = 0; n < 4; n++) {
      int gcol = bn + (wc * 4 + n) * 16 + cc;
      if (gcol >= N) continue;
      #pragma unroll
      for (int r = 0; r < 4; r++) {
        int grow = bm + (wr * 4 + m) * 16 + r0 + r;
        if (grow < M) C[(size_t)grow * N + gcol] = acc[m][n][r];
      }
    }
  }
}

// ---------- split-K fp32 GEMM for skinny-M: partials P[slice][M][N] ----------
// grid (nN, nM, nSlices); block 256; 64x64 tile, 4x4 micro.
__global__ __launch_bounds__(256)
void gemm_sk(const float* __restrict__ A, const float* __restrict__ B,
             float* __restrict__ P, int M, int N, int K, int SK) {
  __shared__ float As[16][64];
  __shared__ float Bs[16][64];
  int tid = threadIdx.x;
  int bm = blockIdx.y * 64;
  int bn = blockIdx.x * 64;
  int ks = blockIdx.z * SK;
  int ke = min(K, ks + SK);
  int tr = tid >> 4;
  int tc = tid & 15;
  float acc[4][4] = {{0.f}};
  int la_m = tid >> 2;
  int la_k = (tid & 3) << 2;
  int lb_k4 = (tid >> 6) << 2;
  int lb_n = tid & 63;

  for (int k0 = ks; k0 < ke; k0 += 16) {
    {
      int gm = bm + la_m;
      bool mok = gm < M;
      const float* ap = A + (size_t)gm * K + k0 + la_k;
      #pragma unroll
      for (int q = 0; q < 4; q++) {
        int kk = la_k + q;
        As[kk][la_m] = (mok && (k0 + kk) < ke) ? ap[q] : 0.f;
      }
    }
    {
      int gn = bn + lb_n;
      #pragma unroll
      for (int q = 0; q < 4; q++) {
        int kk = lb_k4 + q;
        int gk = k0 + kk;
        Bs[kk][lb_n] = (gk < ke && gn < N) ? B[(size_t)gk * N + gn] : 0.f;
      }
    }
    __syncthreads();
    #pragma unroll
    for (int kk = 0; kk < 16; kk++) {
      float a0 = As[kk][tr*4+0], a1 = As[kk][tr*4+1],
            a2 = As[kk][tr*4+2], a3 = As[kk][tr*4+3];
      float b0 = Bs[kk][tc*4+0], b1 = Bs[kk][tc*4+1],
            b2 = Bs[kk][tc*4+2], b3 = Bs[kk][tc*4+3];
      acc[0][0] += a0*b0; acc[0][1] += a0*b1; acc[0][2] += a0*b2; acc[0][3] += a0*b3;
      acc[1][0] += a1*b0; acc[1][1] += a1*b1; acc[1][2] += a1*b2; acc[1][3] += a1*b3;
      acc[2][0] += a2*b0; acc[2][1] += a2*b1; acc[2][2] += a2*b2; acc[2][3] += a2*b3;
      acc[3][0] += a3*b0; acc[3][1] += a3*b1; acc[3][2] += a3*b2; acc[3][3] += a3*b3;
    }
    __syncthreads();
  }
  float* Pp = P + (size_t)blockIdx.z * M * N;
  #pragma unroll
  for (int i = 0; i < 4; i++) {
    int gm = bm + tr*4 + i;
    if (gm >= M) continue;
    #pragma unroll
    for (int j = 0; j < 4; j++) {
      int gn = bn + tc*4 + j;
      if (gn >= N) continue;
      Pp[(size_t)gm * N + gn] = acc[i][j];
    }
  }
}

// reduce slices + bias + act. ACT: 0 none, 1 relu, 2 leaky(0.2)
template<int ACT, bool HAS_BIAS>
__global__ void k_sk_reduce(const float* __restrict__ P, const float* __restrict__ bias,
                            float* __restrict__ C, int MN, int N, int nS) {
  int idx = blockIdx.x * 256 + threadIdx.x;
  if (idx >= MN) return;
  float s = 0.f;
  for (int sl = 0; sl < nS; sl++) s += P[(size_t)sl * MN + idx];
  if (HAS_BIAS) s += bias[idx % N];
  if (ACT == 1) s = fmaxf(s, 0.f);
  else if (ACT == 2) s = s > 0.f ? s : 0.2f * s;
  C[idx] = s;
}

// ---------- attention logits per (node, head), float2 ----------
__global__ void k_al(const float* __restrict__ h, const float* __restrict__ a_src,
                     const float* __restrict__ a_dst,
                     float* __restrict__ al_s, float* __restrict__ al_d) {
  int idx = blockIdx.x * 256 + threadIdx.x;
  if (idx >= N_NODESX * HEADSX) return;
  int n = idx / HEADSX, hd = idx % HEADSX;
  const float2* hp  = (const float2*)(h + (size_t)n * HIDX + hd * F_XDX);
  const float2* as2 = (const float2*)(a_src + hd * F_XDX);
  const float2* ad2 = (const float2*)(a_dst + hd * F_XDX);
  float s1 = 0.f, s2 = 0.f;
  #pragma unroll 13
  for (int i = 0; i < F_XDX / 2; i++) {
    float2 v = hp[i], a = as2[i], d = ad2[i];
    s1 += v.x * a.x + v.y * a.y;
    s2 += v.x * d.x + v.y * d.y;
  }
  al_s[idx] = s1; al_d[idx] = s2;
}

// ---------- CSR build ----------
__global__ void k_count(const int* __restrict__ ei, int* __restrict__ counts) {
  int e = blockIdx.x * 256 + threadIdx.x;
  if (e >= N_E) return;
  int dst = (e < N_EDGES0) ? ei[N_EDGES0 + e] : (e - N_EDGES0);
  atomicAdd(&counts[dst], 1);
}

__global__ void k_scan(const int* __restrict__ cnt, int* __restrict__ row_ptr) {
  __shared__ int part[1024];
  int tid = threadIdx.x;
  const int CH = 30;
  int b0 = tid * CH;
  int s = 0;
  for (int i = 0; i < CH; i++) { int g = b0 + i; if (g < N_NODESX) s += cnt[g]; }
  part[tid] = s;
  __syncthreads();
  for (int off = 1; off < 1024; off <<= 1) {
    int v = (tid >= off) ? part[tid - off] : 0;
    __syncthreads();
    part[tid] += v;
    __syncthreads();
  }
  int pre = (tid > 0) ? part[tid - 1] : 0;
  for (int i = 0; i < CH; i++) {
    int g = b0 + i;
    if (g < N_NODESX) { row_ptr[g] = pre; pre += cnt[g]; }
  }
  if (tid == 1023) row_ptr[N_NODESX] = part[1023];
}

__global__ void k_fill(const int* __restrict__ ei, const int* __restrict__ row_ptr,
                       int* __restrict__ cursor, int* __restrict__ csr_src,
                       int* __restrict__ csr_eid) {
  int e = blockIdx.x * 256 + threadIdx.x;
  if (e >= N_E) return;
  int src, dst;
  if (e < N_EDGES0) { src = ei[e]; dst = ei[N_EDGES0 + e]; }
  else { src = dst = e - N_EDGES0; }
  int pos = row_ptr[dst] + atomicAdd(&cursor[dst], 1);
  csr_src[pos] = src;
  csr_eid[pos] = e;
}

// ---------- edge softmax (no max shift: logits bounded) ----------
__global__ void k_edge_exp(const int* __restrict__ ei, const float* __restrict__ al_s,
                           const float* __restrict__ al_d,
                           float* __restrict__ e_edge, float* __restrict__ den) {
  int e = blockIdx.x * 256 + threadIdx.x;
  if (e >= N_E) return;
  int src, dst;
  if (e < N_EDGES0) { src = ei[e]; dst = ei[N_EDGES0 + e]; }
  else { src = dst = e - N_EDGES0; }
  const float* ps = al_s + (size_t)src * HEADSX;
  const float* pd = al_d + (size_t)dst * HEADSX;
  float* pe = e_edge + (size_t)e * HEADSX;
  #pragma unroll
  for (int hd = 0; hd < HEADSX; hd++) {
    float v = ps[hd] + pd[hd];
    v = v > 0.f ? v : 0.2f * v;
    float ex = expf(v);
    pe[hd] = ex;
    atomicAdd(&den[dst * HEADSX + hd], ex);
  }
}

// ---------- GAT aggregation (gather per dst); writes bf16 hi/lo planes (M x KP_GCN) ----------
__global__ __launch_bounds__(256)
void k_gat_agg(const float* __restrict__ h, const float* __restrict__ exe,
               const float* __restrict__ den, const int* __restrict__ row_ptr,
               const int* __restrict__ csr_src, const int* __restrict__ csr_eid,
               const float* __restrict__ b_gat,
               unsigned short* __restrict__ xgh, unsigned short* __restrict__ xgl) {
  __shared__ float id[HEADSX];
  int d = blockIdx.x, t = threadIdx.x;
  if (t < HEADSX) id[t] = 1.f / (den[d * HEADSX + t] + 1e-16f);
  __syncthreads();
  if (t >= 200) return;
  if (t >= 195) {  // zero the K padding 780..799
    int c = 780 + (t - 195) * 4;
    ushort4 z = make_ushort4(0, 0, 0, 0);
    *(ushort4*)(xgh + (size_t)d * KP_GCN + c) = z;
    *(ushort4*)(xgl + (size_t)d * KP_GCN + c) = z;
    return;
  }
  int c = t * 4;
  int ha = c / F_XDX;
  int hb = (c + 3) / F_XDX;
  int split = (ha + 1) * F_XDX - c;
  float idA = id[ha], idB = id[hb];
  float4 acc = {0.f, 0.f, 0.f, 0.f};
  int beg = row_ptr[d], end = row_ptr[d + 1];
  for (int j = beg; j < end; j++) {
    int s = csr_src[j];
    int eid = csr_eid[j];
    const float* er = exe + (size_t)eid * HEADSX;
    float aA = er[ha] * idA;
    float aB = (hb != ha) ? er[hb] * idB : aA;
    float w0 = (split > 0) ? aA : aB;
    float w1 = (split > 1) ? aA : aB;
    float w2 = (split > 2) ? aA : aB;
    float w3 = (split > 3) ? aA : aB;
    float4 hv = *(const float4*)(h + (size_t)s * HIDX + c);
    acc.x += w0 * hv.x; acc.y += w1 * hv.y; acc.z += w2 * hv.z; acc.w += w3 * hv.w;
  }
  float4 bb = *(const float4*)(b_gat + c);
  float v0 = fmaxf(acc.x + bb.x, 0.f);
  float v1 = fmaxf(acc.y + bb.y, 0.f);
  float v2 = fmaxf(acc.z + bb.z, 0.f);
  float v3 = fmaxf(acc.w + bb.w, 0.f);
  ushort4 h4, l4;
  splitbf(v0, h4.x, l4.x); splitbf(v1, h4.y, l4.y);
  splitbf(v2, h4.z, l4.z); splitbf(v3, h4.w, l4.w);
  *(ushort4*)(xgh + (size_t)d * KP_GCN + c) = h4;
  *(ushort4*)(xgl + (size_t)d * KP_GCN + c) = l4;
}

// ---------- degree inv sqrt ----------
__global__ void k_dinv(const int* __restrict__ counts, float* __restrict__ dinv) {
  int n = blockIdx.x * 256 + threadIdx.x;
  if (n < N_NODESX) dinv[n] = rsqrtf(fmaxf((float)counts[n], 1.f));
}

// ---------- GCN aggregation (gather per dst, float4) ----------
__global__ __launch_bounds__(256)
void k_gcn_agg(const float* __restrict__ s, const float* __restrict__ dinv,
               const int* __restrict__ row_ptr, const int* __restrict__ csr_src,
               const float* __restrict__ b_gcn, float* __restrict__ out) {
  int d = blockIdx.x, t = threadIdx.x;
  if (t >= HIDX / 4) return;
  int c = t * 4;
  float4 acc = {0.f, 0.f, 0.f, 0.f};
  int beg = row_ptr[d], end = row_ptr[d + 1];
  for (int j = beg; j < end; j++) {
    int si = csr_src[j];
    float w = dinv[si];
    float4 sv = *(const float4*)(s + (size_t)si * HIDX + c);
    acc.x += w * sv.x; acc.y += w * sv.y; acc.z += w * sv.z; acc.w += w * sv.w;
  }
  float dd = dinv[d];
  float4 bb = *(const float4*)(b_gcn + c);
  float4 r;
  r.x = fmaxf(acc.x * dd + bb.x, 0.f);
  r.y = fmaxf(acc.y * dd + bb.y, 0.f);
  r.z = fmaxf(acc.z * dd + bb.z, 0.f);
  r.w = fmaxf(acc.w * dd + bb.w, 0.f);
  *(float4*)(out + (size_t)d * HIDX + c) = r;
}

// ---------- per-graph ranges ----------
__global__ void k_range_init(int* __restrict__ gstart, int* __restrict__ gend) {
  int g = threadIdx.x;
  if (g < N_GRAPHSX) { gstart[g] = 0x7FFFFFFF; gend[g] = 0; }
}
__global__ void k_ranges(const int* __restrict__ batch, int* __restrict__ gstart,
                         int* __restrict__ gend) {
  int n = blockIdx.x * 256 + threadIdx.x;
  if (n >= N_NODESX) return;
  int b = batch[n];
  atomicMin(&gstart[b], n);
  atomicMax(&gend[b], n + 1);
}

// ---------- pooling: max + mean per graph, float4 ----------
__global__ __launch_bounds__(256)
void k_pool(const float* __restrict__ xg2, const int* __restrict__ gstart,
            const int* __restrict__ gend, float* __restrict__ xf) {
  int g = blockIdx.x, t = threadIdx.x;
  if (t >= HIDX / 4) return;
  int c = t * 4;
  int st = gstart[g], en = gend[g];
  float4 mx = {0.f, 0.f, 0.f, 0.f};
  float4 sm = {0.f, 0.f, 0.f, 0.f};
  for (int n = st; n < en; n++) {
    float4 v = *(const float4*)(xg2 + (size_t)n * HIDX + c);
    mx.x = fmaxf(mx.x, v.x); sm.x += v.x;
    mx.y = fmaxf(mx.y, v.y); sm.y += v.y;
    mx.z = fmaxf(mx.z, v.z); sm.z += v.z;
    mx.w = fmaxf(mx.w, v.w); sm.w += v.w;
  }
  float inv = (en > st) ? 1.f / (float)(en - st) : 0.f;
  float* xr = xf + (size_t)g * (2 * HIDX);
  float4 mean; mean.x = sm.x*inv; mean.y = sm.y*inv; mean.z = sm.z*inv; mean.w = sm.w*inv;
  *(float4*)(xr + c) = mx;
  *(float4*)(xr + HIDX + c) = mean;
}

// ---------- label branch ----------
__global__ void k_dvec(const float* __restrict__ A, float* __restrict__ dvec) {
  int i = blockIdx.x * 64 + threadIdx.x;
  if (i >= N_CLASSESX) return;
  float s = 0.f;
  for (int j = 0; j < N_CLASSESX; j++) s += A[i * N_CLASSESX + j];
  dvec[i] = rsqrtf(s);
}
__global__ void k_adj(const float* __restrict__ A, const float* __restrict__ dvec,
                      float* __restrict__ adj) {
  int idx = blockIdx.x * 256 + threadIdx.x;
  if (idx >= N_CLASSESX * N_CLASSESX) return;
  int i = idx / N_CLASSESX, j = idx % N_CLASSESX;
  adj[idx] = dvec[i] * A[j * N_CLASSESX + i] * dvec[j];
}

// ---------- final out = fc2o @ y^T : one wave per output ----------
__global__ __launch_bounds__(256)
void k_out(const float* __restrict__ xf2, const float* __restrict__ y,
           float* __restrict__ out) {
  int gw = (blockIdx.x * 256 + threadIdx.x) >> 6;
  int lane = threadIdx.x & 63;
  if (gw >= N_GRAPHSX * N_CLASSESX) return;
  int b = gw / N_CLASSESX, c = gw - b * N_CLASSESX;
  const float4* xr = (const float4*)(xf2 + (size_t)b * 1024);
  const float4* yr = (const float4*)(y + (size_t)c * 1024);
  float s = 0.f;
  #pragma unroll
  for (int i = 0; i < 4; i++) {
    float4 xv = xr[lane + i * 64], yv = yr[lane + i * 64];
    s += xv.x*yv.x + xv.y*yv.y + xv.z*yv.z + xv.w*yv.w;
  }
  #pragma unroll
  for (int off = 32; off > 0; off >>= 1) s += __shfl_down(s, off, 64);
  if (lane == 0) out[gw] = s;
}

// =======================================================================
extern "C" void kernel_launch(void* const* d_in, const int* in_sizes, int n_in,
                              void* d_out, int out_size, void* d_ws, size_t ws_size,
                              hipStream_t stream) {
  const float* x     = (const float*)d_in[0];
  const int*   ei    = (const int*)d_in[1];
  const int*   batch = (const int*)d_in[2];
  const float* inp   = (const float*)d_in[3];
  const float* W_gat = (const float*)d_in[4];
  const float* a_src = (const float*)d_in[5];
  const float* a_dst = (const float*)d_in[6];
  const float* b_gat = (const float*)d_in[7];
  const float* W_gcn = (const float*)d_in[8];
  const float* b_gcn = (const float*)d_in[9];
  const float* W_fc1 = (const float*)d_in[10];
  const float* b_fc1 = (const float*)d_in[11];
  const float* W_fc2 = (const float*)d_in[12];
  const float* b_fc2 = (const float*)d_in[13];
  const float* W_gc1 = (const float*)d_in[14];
  const float* W_gc2 = (const float*)d_in[15];
  const float* A     = (const float*)d_in[16];
  float* out = (float*)d_out;

  char* ws = (char*)d_ws;
  size_t off = 0;
  auto alloc = [&](size_t bytes) -> void* {
    void* p = ws + off;
    off = (off + bytes + 255) & ~(size_t)255;
    return p;
  };

  float* bufA   = (float*)alloc(sizeof(float) * (size_t)N_NODESX * HIDX); // h, then s
  float* bufB   = (float*)alloc(sizeof(float) * (size_t)N_NODESX * HIDX); // xgh alias, then xg2
  float* e_edge = (float*)alloc(sizeof(float) * (size_t)N_E * HEADSX);    // also aliases xh/xl
  float* al_s   = (float*)alloc(sizeof(float) * N_NODESX * HEADSX);
  float* al_d   = (float*)alloc(sizeof(float) * N_NODESX * HEADSX);
  float* den    = (float*)alloc(sizeof(float) * N_NODESX * HEADSX);
  int* counts   = (int*)alloc(sizeof(int) * N_NODESX);
  int* row_ptr  = (int*)alloc(sizeof(int) * (N_NODESX + 1));
  int* cursor   = (int*)alloc(sizeof(int) * N_NODESX);
  int* csr_src  = (int*)alloc(sizeof(int) * N_E);
  int* csr_eid  = (int*)alloc(sizeof(int) * N_E);
  float* dinv   = (float*)alloc(sizeof(float) * N_NODESX);
  int* gstart   = (int*)alloc(sizeof(int) * N_GRAPHSX);
  int* gend     = (int*)alloc(sizeof(int) * N_GRAPHSX);
  float* xf     = (float*)alloc(sizeof(float) * N_GRAPHSX * 2 * HIDX);
  float* fc1o   = (float*)alloc(sizeof(float) * N_GRAPHSX * 1500);
  float* fc2o   = (float*)alloc(sizeof(float) * N_GRAPHSX * 1024);
  float* t1     = (float*)alloc(sizeof(float) * N_CLASSESX * 1024);
  float* adj    = (float*)alloc(sizeof(float) * N_CLASSESX * N_CLASSESX);
  float* dvec   = (float*)alloc(sizeof(float) * N_CLASSESX);
  float* y1     = (float*)alloc(sizeof(float) * N_CLASSESX * 1024);
  float* t2     = (float*)alloc(sizeof(float) * N_CLASSESX * 1024);
  float* ybuf   = (float*)alloc(sizeof(float) * N_CLASSESX * 1024);
  float* Ppart  = (float*)alloc(sizeof(float) * 13 * 64 * 1500);   // split-K partials (max)
  // bf16 split planes
  unsigned short* wgTh = (unsigned short*)alloc(sizeof(short) * (size_t)HIDX * KP_GAT);
  unsigned short* wgTl = (unsigned short*)alloc(sizeof(short) * (size_t)HIDX * KP_GAT);
  unsigned short* wcTh = (unsigned short*)alloc(sizeof(short) * (size_t)HIDX * KP_GCN);
  unsigned short* wcTl = (unsigned short*)alloc(sizeof(short) * (size_t)HIDX * KP_GCN);
  unsigned short* xgl  = (unsigned short*)alloc(sizeof(short) * (size_t)N_NODESX * KP_GCN);
  // aliases (lifetimes disjoint):
  unsigned short* xh  = (unsigned short*)e_edge;                    // dead before e_edge written
  unsigned short* xl  = xh + (size_t)N_NODESX * KP_GAT;
  unsigned short* xgh = (unsigned short*)bufB;                      // dead before xg2 written
  (void)ws_size; (void)in_sizes; (void)n_in; (void)out_size;

  hipMemsetAsync(den, 0, sizeof(float) * N_NODESX * HEADSX, stream);
  hipMemsetAsync(counts, 0, sizeof(int) * N_NODESX, stream);
  hipMemsetAsync(cursor, 0, sizeof(int) * N_NODESX, stream);

  // split conversions
  k_split_pad<<<(N_NODESX * (KP_GAT/8) + 255) / 256, 256, 0, stream>>>(x, N_NODESX, F_XDX, KP_GAT, xh, xl);
  k_splitT<<<(HIDX * (KP_GAT/8) + 255) / 256, 256, 0, stream>>>(W_gat, F_XDX, HIDX, KP_GAT, wgTh, wgTl);
  k_splitT<<<(HIDX * (KP_GCN/8) + 255) / 256, 256, 0, stream>>>(W_gcn, HIDX, HIDX, KP_GCN, wcTh, wcTl);

  // h = x @ W_gat  (MFMA split-bf16)
  gemm_mfma3<<<dim3((HIDX + 127) / 128, (N_NODESX + 127) / 128), 256, 0, stream>>>(
      xh, xl, wgTh, wgTl, bufA, N_NODESX, HIDX, KP_GAT);
  // attention logits
  k_al<<<(N_NODESX * HEADSX + 255) / 256, 256, 0, stream>>>(bufA, a_src, a_dst, al_s, al_d);
  // CSR
  k_count<<<(N_E + 255) / 256, 256, 0, stream>>>(ei, counts);
  k_scan<<<1, 1024, 0, stream>>>(counts, row_ptr);
  k_fill<<<(N_E + 255) / 256, 256, 0, stream>>>(ei, row_ptr, cursor, csr_src, csr_eid);
  // edge softmax
  k_edge_exp<<<(N_E + 255) / 256, 256, 0, stream>>>(ei, al_s, al_d, e_edge, den);
  // GAT aggregate -> xg split planes
  k_gat_agg<<<N_NODESX, 256, 0, stream>>>(bufA, e_edge, den, row_ptr, csr_src, csr_eid,
                                          b_gat, xgh, xgl);
  // GCN
  k_dinv<<<(N_NODESX + 255) / 256, 256, 0, stream>>>(counts, dinv);
  gemm_mfma3<<<dim3((HIDX + 127) / 128, (N_NODESX + 127) / 128), 256, 0, stream>>>(
      xgh, xgl, wcTh, wcTl, bufA, N_NODESX, HIDX, KP_GCN);          // s -> bufA
  k_gcn_agg<<<N_NODESX, 256, 0, stream>>>(bufA, dinv, row_ptr, csr_src, b_gcn, bufB); // xg2
  // pooling
  k_range_init<<<1, 64, 0, stream>>>(gstart, gend);
  k_ranges<<<(N_NODESX + 255) / 256, 256, 0, stream>>>(batch, gstart, gend);
  k_pool<<<N_GRAPHSX, 256, 0, stream>>>(bufB, gstart, gend, xf);

  // ---- dense head via split-K ----
  // fc1: 64 x 1500, K=1560, SK=128 -> 13 slices
  gemm_sk<<<dim3(24, 1, 13), 256, 0, stream>>>(xf, W_fc1, Ppart, 64, 1500, 1560, 128);
  k_sk_reduce<1, true><<<(64 * 1500 + 255) / 256, 256, 0, stream>>>(
      Ppart, b_fc1, fc1o, 64 * 1500, 1500, 13);
  // fc2: 64 x 1024, K=1500, SK=128 -> 12 slices
  gemm_sk<<<dim3(16, 1, 12), 256, 0, stream>>>(fc1o, W_fc2, Ppart, 64, 1024, 1500, 128);
  k_sk_reduce<0, true><<<(64 * 1024 + 255) / 256, 256, 0, stream>>>(
      Ppart, b_fc2, fc2o, 64 * 1024, 1024, 12);

  // ---- label branch ----
  k_dvec<<<(N_CLASSESX + 63) / 64, 64, 0, stream>>>(A, dvec);
  k_adj<<<(N_CLASSESX * N_CLASSESX + 255) / 256, 256, 0, stream>>>(A, dvec, adj);
  // t1 = inp @ W_gc1: 100 x 1024, K=300, SK=64 -> 5 slices
  gemm_sk<<<dim3(16, 2, 5), 256, 0, stream>>>(inp, W_gc1, Ppart, 100, 1024, 300, 64);
  k_sk_reduce<0, false><<<(100 * 1024 + 255) / 256, 256, 0, stream>>>(
      Ppart, nullptr, t1, 100 * 1024, 1024, 5);
  // y1 = leaky(adj @ t1): 100 x 1024, K=100, SK=32 -> 4 slices
  gemm_sk<<<dim3(16, 2, 4), 256, 0, stream>>>(adj, t1, Ppart, 100, 1024, 100, 32);
  k_sk_reduce<2, false><<<(100 * 1024 + 255) / 256, 256, 0, stream>>>(
      Ppart, nullptr, y1, 100 * 1024, 1024, 4);
  // t2 = y1 @ W_gc2: 100 x 1024, K=1024, SK=128 -> 8 slices
  gemm_sk<<<dim3(16, 2, 8), 256, 0, stream>>>(y1, W_gc2, Ppart, 100, 1024, 1024, 128);
  k_sk_reduce<0, false><<<(100 * 1024 + 255) / 256, 256, 0, stream>>>(
      Ppart, nullptr, t2, 100 * 1024, 1024, 8);
  // ybuf = adj @ t2: 100 x 1024, K=100, SK=32 -> 4 slices
  gemm_sk<<<dim3(16, 2, 4), 256, 0, stream>>>(adj, t2, Ppart, 100, 1024, 100, 32);
  k_sk_reduce<0, false><<<(100 * 1024 + 255) / 256, 256, 0, stream>>>(
      Ppart, nullptr, ybuf, 100 * 1024, 1024, 4);

  // out = fc2o @ ybuf^T (wave per output)
  k_out<<<(N_GRAPHSX * N_CLASSESX * 64 + 255) / 256, 256, 0, stream>>>(fc2o, ybuf, out);
}

// Round 5
// 1398.546 us; speedup vs baseline: 1.6939x; 1.0344x over previous
//
#include <hip/hip_runtime.h>

#define N_NODESX 30000
#define N_EDGES0 300000
#define N_E      330000
#define N_GRAPHSX 64
#define N_CLASSESX 100
#define F_XDX 78
#define HEADSX 10
#define HIDX 780
#define IN_CHX 300
#define KP_GAT 96    // ceil(78/32)*32
#define KP_GCN 800   // ceil(780/32)*32
#define NXCD 8

typedef __attribute__((ext_vector_type(8))) short short8v;
typedef __attribute__((ext_vector_type(8))) unsigned short ushort8v;
typedef __attribute__((ext_vector_type(4))) float f32x4;

// ---------- bf16 split helpers ----------
__device__ inline unsigned short f2bf_rne(float f) {
  unsigned u = __float_as_uint(f);
  unsigned r = (u + 0x7FFFu + ((u >> 16) & 1u)) >> 16;
  return (unsigned short)r;
}
__device__ inline float bf2f(unsigned short h) {
  return __uint_as_float(((unsigned)h) << 16);
}
__device__ inline void splitbf(float v, unsigned short& h, unsigned short& l) {
  unsigned short hh = f2bf_rne(v);
  h = hh;
  l = f2bf_rne(v - bf2f(hh));
}

// ---------- split fp32 matrix (M x K, row-major) into hi/lo bf16 planes (M x Kp, zero pad) ----------
__global__ void k_split_pad(const float* __restrict__ X, int M, int K, int Kp,
                            unsigned short* __restrict__ Ph, unsigned short* __restrict__ Pl) {
  int idx = blockIdx.x * 256 + threadIdx.x;
  int packs = Kp >> 3;
  if (idx >= M * packs) return;
  int row = idx / packs, p = idx - row * packs;
  ushort8v h, l;
  #pragma unroll
  for (int j = 0; j < 8; j++) {
    int k = p * 8 + j;
    float v = (k < K) ? X[(size_t)row * K + k] : 0.f;
    unsigned short hh, ll;
    splitbf(v, hh, ll);
    h[j] = hh; l[j] = ll;
  }
  *(ushort8v*)&Ph[(size_t)row * Kp + p * 8] = h;
  *(ushort8v*)&Pl[(size_t)row * Kp + p * 8] = l;
}

// ---------- split + transpose: W (K x N) -> planes (N x Kp) ----------
__global__ void k_splitT(const float* __restrict__ W, int K, int N, int Kp,
                         unsigned short* __restrict__ Th, unsigned short* __restrict__ Tl) {
  int idx = blockIdx.x * 256 + threadIdx.x;
  int packs = Kp >> 3;
  if (idx >= N * packs) return;
  int n = idx / packs, p = idx - n * packs;
  ushort8v h, l;
  #pragma unroll
  for (int j = 0; j < 8; j++) {
    int k = p * 8 + j;
    float v = (k < K) ? W[(size_t)k * N + n] : 0.f;
    unsigned short hh, ll;
    splitbf(v, hh, ll);
    h[j] = hh; l[j] = ll;
  }
  *(ushort8v*)&Th[(size_t)n * Kp + p * 8] = h;
  *(ushort8v*)&Tl[(size_t)n * Kp + p * 8] = l;
}

// ---------- MFMA split-bf16 GEMM with bijective XCD-chunk swizzle ----------
// A as hi/lo planes (M x Kp), B as TRANSPOSED hi/lo planes (N x Kp).
// 3-product: AhBh + AhBl + AlBh. Tile 128x128xBK32, 256 threads (4 waves, 2x2).
__global__ __launch_bounds__(256)
void gemm_mfma3(const unsigned short* __restrict__ Ah, const unsigned short* __restrict__ Al,
                const unsigned short* __restrict__ Bh, const unsigned short* __restrict__ Bl,
                float* __restrict__ C, int M, int N, int Kp) {
  __shared__ unsigned short lds[4 * 4096];  // planes: Ah, Al, Bh, Bl; fragment-order
  const int tid  = threadIdx.x;
  const int lane = tid & 63;
  const int w    = tid >> 6;
  const int wr   = w >> 1, wc = w & 1;

  // XCD-chunk bijective swizzle (m204): consecutive tiles of a chunk share
  // the same XCD; col-tile fastest -> A row-panel L2 reuse, B resident.
  const int nwg = gridDim.x * gridDim.y;
  const int L   = blockIdx.y * gridDim.x + blockIdx.x;
  const int q = nwg / NXCD, r = nwg % NXCD;
  const int xcd = L % NXCD, pos = L / NXCD;
  const int newL = (xcd < r ? xcd * (q + 1) : r * (q + 1) + (xcd - r) * q) + pos;
  const int bm = (newL / gridDim.x) * 128;
  const int bn = (newL % gridDim.x) * 128;

  f32x4 acc[4][4];
  #pragma unroll
  for (int m = 0; m < 4; m++)
    #pragma unroll
    for (int n = 0; n < 4; n++) acc[m][n] = (f32x4){0.f, 0.f, 0.f, 0.f};

  const unsigned short* srcs[4] = {Ah, Al, Bh, Bl};

  for (int k0 = 0; k0 < Kp; k0 += 32) {
    __syncthreads();
    #pragma unroll
    for (int i = 0; i < 8; i++) {
      const int plane = i >> 1;
      const int q2 = ((i & 1) << 8) + tid;      // 0..511
      const int fm = q2 >> 6;
      const int rr = q2 & 63;
      const int ks = rr >> 4, r16 = rr & 15;
      const int rowbase = (plane < 2) ? bm : bn;
      const int lim     = (plane < 2) ? M : N;
      const int row = rowbase + fm * 16 + r16;
      ushort8v v = (ushort8v){0,0,0,0,0,0,0,0};
      if (row < lim)
        v = *(const ushort8v*)(srcs[plane] + (size_t)row * Kp + k0 + ks * 8);
      *(ushort8v*)&lds[(size_t)plane * 4096 + (size_t)q2 * 8] = v;
    }
    __syncthreads();

    short8v afh[4], afl[4], bfh[4], bfl[4];
    #pragma unroll
    for (int m = 0; m < 4; m++) {
      int fmA = wr * 4 + m;
      afh[m] = *(const short8v*)&lds[0 * 4096 + fmA * 512 + lane * 8];
      afl[m] = *(const short8v*)&lds[1 * 4096 + fmA * 512 + lane * 8];
    }
    #pragma unroll
    for (int n = 0; n < 4; n++) {
      int fnB = wc * 4 + n;
      bfh[n] = *(const short8v*)&lds[2 * 4096 + fnB * 512 + lane * 8];
      bfl[n] = *(const short8v*)&lds[3 * 4096 + fnB * 512 + lane * 8];
    }
    #pragma unroll
    for (int m = 0; m < 4; m++) {
      #pragma unroll
      for (int n = 0; n < 4; n++) {
        acc[m][n] = __builtin_amdgcn_mfma_f32_16x16x32_bf16(afh[m], bfh[n], acc[m][n], 0, 0, 0);
        acc[m][n] = __builtin_amdgcn_mfma_f32_16x16x32_bf16(afh[m], bfl[n], acc[m][n], 0, 0, 0);
        acc[m][n] = __builtin_amdgcn_mfma_f32_16x16x32_bf16(afl[m], bfh[n], acc[m][n], 0, 0, 0);
      }
    }
  }

  const int r0 = (lane >> 4) * 4;
  const int cc = lane & 15;
  #pragma unroll
  for (int m = 0; m < 4; m++) {
    #pragma unroll
    for (int n = 0; n < 4; n++) {
      int gcol = bn + (wc * 4 + n) * 16 + cc;
      if (gcol >= N) continue;
      #pragma unroll
      for (int r2 = 0; r2 < 4; r2++) {
        int grow = bm + (wr * 4 + m) * 16 + r0 + r2;
        if (grow < M) C[(size_t)grow * N + gcol] = acc[m][n][r2];
      }
    }
  }
}

// ---------- split-K fp32 GEMM for skinny-M: partials P[slice][M][N] ----------
__global__ __launch_bounds__(256)
void gemm_sk(const float* __restrict__ A, const float* __restrict__ B,
             float* __restrict__ P, int M, int N, int K, int SK) {
  __shared__ float As[16][64];
  __shared__ float Bs[16][64];
  int tid = threadIdx.x;
  int bm = blockIdx.y * 64;
  int bn = blockIdx.x * 64;
  int ks = blockIdx.z * SK;
  int ke = min(K, ks + SK);
  int tr = tid >> 4;
  int tc = tid & 15;
  float acc[4][4] = {{0.f}};
  int la_m = tid >> 2;
  int la_k = (tid & 3) << 2;
  int lb_k4 = (tid >> 6) << 2;
  int lb_n = tid & 63;

  for (int k0 = ks; k0 < ke; k0 += 16) {
    {
      int gm = bm + la_m;
      bool mok = gm < M;
      const float* ap = A + (size_t)gm * K + k0 + la_k;
      #pragma unroll
      for (int q = 0; q < 4; q++) {
        int kk = la_k + q;
        As[kk][la_m] = (mok && (k0 + kk) < ke) ? ap[q] : 0.f;
      }
    }
    {
      int gn = bn + lb_n;
      #pragma unroll
      for (int q = 0; q < 4; q++) {
        int kk = lb_k4 + q;
        int gk = k0 + kk;
        Bs[kk][lb_n] = (gk < ke && gn < N) ? B[(size_t)gk * N + gn] : 0.f;
      }
    }
    __syncthreads();
    #pragma unroll
    for (int kk = 0; kk < 16; kk++) {
      float a0 = As[kk][tr*4+0], a1 = As[kk][tr*4+1],
            a2 = As[kk][tr*4+2], a3 = As[kk][tr*4+3];
      float b0 = Bs[kk][tc*4+0], b1 = Bs[kk][tc*4+1],
            b2 = Bs[kk][tc*4+2], b3 = Bs[kk][tc*4+3];
      acc[0][0] += a0*b0; acc[0][1] += a0*b1; acc[0][2] += a0*b2; acc[0][3] += a0*b3;
      acc[1][0] += a1*b0; acc[1][1] += a1*b1; acc[1][2] += a1*b2; acc[1][3] += a1*b3;
      acc[2][0] += a2*b0; acc[2][1] += a2*b1; acc[2][2] += a2*b2; acc[2][3] += a2*b3;
      acc[3][0] += a3*b0; acc[3][1] += a3*b1; acc[3][2] += a3*b2; acc[3][3] += a3*b3;
    }
    __syncthreads();
  }
  float* Pp = P + (size_t)blockIdx.z * M * N;
  #pragma unroll
  for (int i = 0; i < 4; i++) {
    int gm = bm + tr*4 + i;
    if (gm >= M) continue;
    #pragma unroll
    for (int j = 0; j < 4; j++) {
      int gn = bn + tc*4 + j;
      if (gn >= N) continue;
      Pp[(size_t)gm * N + gn] = acc[i][j];
    }
  }
}

// reduce slices + bias + act. ACT: 0 none, 1 relu, 2 leaky(0.2)
template<int ACT, bool HAS_BIAS>
__global__ void k_sk_reduce(const float* __restrict__ P, const float* __restrict__ bias,
                            float* __restrict__ C, int MN, int N, int nS) {
  int idx = blockIdx.x * 256 + threadIdx.x;
  if (idx >= MN) return;
  float s = 0.f;
  for (int sl = 0; sl < nS; sl++) s += P[(size_t)sl * MN + idx];
  if (HAS_BIAS) s += bias[idx % N];
  if (ACT == 1) s = fmaxf(s, 0.f);
  else if (ACT == 2) s = s > 0.f ? s : 0.2f * s;
  C[idx] = s;
}

// ---------- attention logits per (node, head), float2 ----------
__global__ void k_al(const float* __restrict__ h, const float* __restrict__ a_src,
                     const float* __restrict__ a_dst,
                     float* __restrict__ al_s, float* __restrict__ al_d) {
  int idx = blockIdx.x * 256 + threadIdx.x;
  if (idx >= N_NODESX * HEADSX) return;
  int n = idx / HEADSX, hd = idx % HEADSX;
  const float2* hp  = (const float2*)(h + (size_t)n * HIDX + hd * F_XDX);
  const float2* as2 = (const float2*)(a_src + hd * F_XDX);
  const float2* ad2 = (const float2*)(a_dst + hd * F_XDX);
  float s1 = 0.f, s2 = 0.f;
  #pragma unroll 13
  for (int i = 0; i < F_XDX / 2; i++) {
    float2 v = hp[i], a = as2[i], d = ad2[i];
    s1 += v.x * a.x + v.y * a.y;
    s2 += v.x * d.x + v.y * d.y;
  }
  al_s[idx] = s1; al_d[idx] = s2;
}

// ---------- CSR build ----------
__global__ void k_count(const int* __restrict__ ei, int* __restrict__ counts) {
  int e = blockIdx.x * 256 + threadIdx.x;
  if (e >= N_E) return;
  int dst = (e < N_EDGES0) ? ei[N_EDGES0 + e] : (e - N_EDGES0);
  atomicAdd(&counts[dst], 1);
}

__global__ void k_scan(const int* __restrict__ cnt, int* __restrict__ row_ptr) {
  __shared__ int part[1024];
  int tid = threadIdx.x;
  const int CH = 30;
  int b0 = tid * CH;
  int s = 0;
  for (int i = 0; i < CH; i++) { int g = b0 + i; if (g < N_NODESX) s += cnt[g]; }
  part[tid] = s;
  __syncthreads();
  for (int off = 1; off < 1024; off <<= 1) {
    int v = (tid >= off) ? part[tid - off] : 0;
    __syncthreads();
    part[tid] += v;
    __syncthreads();
  }
  int pre = (tid > 0) ? part[tid - 1] : 0;
  for (int i = 0; i < CH; i++) {
    int g = b0 + i;
    if (g < N_NODESX) { row_ptr[g] = pre; pre += cnt[g]; }
  }
  if (tid == 1023) row_ptr[N_NODESX] = part[1023];
}

__global__ void k_fill(const int* __restrict__ ei, const int* __restrict__ row_ptr,
                       int* __restrict__ cursor, int* __restrict__ csr_src,
                       int* __restrict__ csr_eid) {
  int e = blockIdx.x * 256 + threadIdx.x;
  if (e >= N_E) return;
  int src, dst;
  if (e < N_EDGES0) { src = ei[e]; dst = ei[N_EDGES0 + e]; }
  else { src = dst = e - N_EDGES0; }
  int pos = row_ptr[dst] + atomicAdd(&cursor[dst], 1);
  csr_src[pos] = src;
  csr_eid[pos] = e;
}

// ---------- edge softmax (no max shift: logits bounded) ----------
__global__ void k_edge_exp(const int* __restrict__ ei, const float* __restrict__ al_s,
                           const float* __restrict__ al_d,
                           float* __restrict__ e_edge, float* __restrict__ den) {
  int e = blockIdx.x * 256 + threadIdx.x;
  if (e >= N_E) return;
  int src, dst;
  if (e < N_EDGES0) { src = ei[e]; dst = ei[N_EDGES0 + e]; }
  else { src = dst = e - N_EDGES0; }
  const float* ps = al_s + (size_t)src * HEADSX;
  const float* pd = al_d + (size_t)dst * HEADSX;
  float* pe = e_edge + (size_t)e * HEADSX;
  #pragma unroll
  for (int hd = 0; hd < HEADSX; hd++) {
    float v = ps[hd] + pd[hd];
    v = v > 0.f ? v : 0.2f * v;
    float ex = expf(v);
    pe[hd] = ex;
    atomicAdd(&den[dst * HEADSX + hd], ex);
  }
}

// ---------- GAT aggregation (gather per dst); writes bf16 hi/lo planes (M x KP_GCN) ----------
__global__ __launch_bounds__(256)
void k_gat_agg(const float* __restrict__ h, const float* __restrict__ exe,
               const float* __restrict__ den, const int* __restrict__ row_ptr,
               const int* __restrict__ csr_src, const int* __restrict__ csr_eid,
               const float* __restrict__ b_gat,
               unsigned short* __restrict__ xgh, unsigned short* __restrict__ xgl) {
  __shared__ float id[HEADSX];
  int d = blockIdx.x, t = threadIdx.x;
  if (t < HEADSX) id[t] = 1.f / (den[d * HEADSX + t] + 1e-16f);
  __syncthreads();
  if (t >= 200) return;
  if (t >= 195) {  // zero the K padding 780..799
    int c = 780 + (t - 195) * 4;
    ushort4 z = make_ushort4(0, 0, 0, 0);
    *(ushort4*)(xgh + (size_t)d * KP_GCN + c) = z;
    *(ushort4*)(xgl + (size_t)d * KP_GCN + c) = z;
    return;
  }
  int c = t * 4;
  int ha = c / F_XDX;
  int hb = (c + 3) / F_XDX;
  int split = (ha + 1) * F_XDX - c;
  float idA = id[ha], idB = id[hb];
  float4 acc = {0.f, 0.f, 0.f, 0.f};
  int beg = row_ptr[d], end = row_ptr[d + 1];
  for (int j = beg; j < end; j++) {
    int s = csr_src[j];
    int eid = csr_eid[j];
    const float* er = exe + (size_t)eid * HEADSX;
    float aA = er[ha] * idA;
    float aB = (hb != ha) ? er[hb] * idB : aA;
    float w0 = (split > 0) ? aA : aB;
    float w1 = (split > 1) ? aA : aB;
    float w2 = (split > 2) ? aA : aB;
    float w3 = (split > 3) ? aA : aB;
    float4 hv = *(const float4*)(h + (size_t)s * HIDX + c);
    acc.x += w0 * hv.x; acc.y += w1 * hv.y; acc.z += w2 * hv.z; acc.w += w3 * hv.w;
  }
  float4 bb = *(const float4*)(b_gat + c);
  float v0 = fmaxf(acc.x + bb.x, 0.f);
  float v1 = fmaxf(acc.y + bb.y, 0.f);
  float v2 = fmaxf(acc.z + bb.z, 0.f);
  float v3 = fmaxf(acc.w + bb.w, 0.f);
  ushort4 h4, l4;
  splitbf(v0, h4.x, l4.x); splitbf(v1, h4.y, l4.y);
  splitbf(v2, h4.z, l4.z); splitbf(v3, h4.w, l4.w);
  *(ushort4*)(xgh + (size_t)d * KP_GCN + c) = h4;
  *(ushort4*)(xgl + (size_t)d * KP_GCN + c) = l4;
}

// ---------- degree inv sqrt ----------
__global__ void k_dinv(const int* __restrict__ counts, float* __restrict__ dinv) {
  int n = blockIdx.x * 256 + threadIdx.x;
  if (n < N_NODESX) dinv[n] = rsqrtf(fmaxf((float)counts[n], 1.f));
}

// ---------- GCN aggregation (gather per dst, float4) ----------
__global__ __launch_bounds__(256)
void k_gcn_agg(const float* __restrict__ s, const float* __restrict__ dinv,
               const int* __restrict__ row_ptr, const int* __restrict__ csr_src,
               const float* __restrict__ b_gcn, float* __restrict__ out) {
  int d = blockIdx.x, t = threadIdx.x;
  if (t >= HIDX / 4) return;
  int c = t * 4;
  float4 acc = {0.f, 0.f, 0.f, 0.f};
  int beg = row_ptr[d], end = row_ptr[d + 1];
  for (int j = beg; j < end; j++) {
    int si = csr_src[j];
    float w = dinv[si];
    float4 sv = *(const float4*)(s + (size_t)si * HIDX + c);
    acc.x += w * sv.x; acc.y += w * sv.y; acc.z += w * sv.z; acc.w += w * sv.w;
  }
  float dd = dinv[d];
  float4 bb = *(const float4*)(b_gcn + c);
  float4 r;
  r.x = fmaxf(acc.x * dd + bb.x, 0.f);
  r.y = fmaxf(acc.y * dd + bb.y, 0.f);
  r.z = fmaxf(acc.z * dd + bb.z, 0.f);
  r.w = fmaxf(acc.w * dd + bb.w, 0.f);
  *(float4*)(out + (size_t)d * HIDX + c) = r;
}

// ---------- per-graph ranges ----------
__global__ void k_range_init(int* __restrict__ gstart, int* __restrict__ gend) {
  int g = threadIdx.x;
  if (g < N_GRAPHSX) { gstart[g] = 0x7FFFFFFF; gend[g] = 0; }
}
__global__ void k_ranges(const int* __restrict__ batch, int* __restrict__ gstart,
                         int* __restrict__ gend) {
  int n = blockIdx.x * 256 + threadIdx.x;
  if (n >= N_NODESX) return;
  int b = batch[n];
  atomicMin(&gstart[b], n);
  atomicMax(&gend[b], n + 1);
}

// ---------- pooling: max + mean per graph, float4 ----------
__global__ __launch_bounds__(256)
void k_pool(const float* __restrict__ xg2, const int* __restrict__ gstart,
            const int* __restrict__ gend, float* __restrict__ xf) {
  int g = blockIdx.x, t = threadIdx.x;
  if (t >= HIDX / 4) return;
  int c = t * 4;
  int st = gstart[g], en = gend[g];
  float4 mx = {0.f, 0.f, 0.f, 0.f};
  float4 sm = {0.f, 0.f, 0.f, 0.f};
  for (int n = st; n < en; n++) {
    float4 v = *(const float4*)(xg2 + (size_t)n * HIDX + c);
    mx.x = fmaxf(mx.x, v.x); sm.x += v.x;
    mx.y = fmaxf(mx.y, v.y); sm.y += v.y;
    mx.z = fmaxf(mx.z, v.z); sm.z += v.z;
    mx.w = fmaxf(mx.w, v.w); sm.w += v.w;
  }
  float inv = (en > st) ? 1.f / (float)(en - st) : 0.f;
  float* xr = xf + (size_t)g * (2 * HIDX);
  float4 mean; mean.x = sm.x*inv; mean.y = sm.y*inv; mean.z = sm.z*inv; mean.w = sm.w*inv;
  *(float4*)(xr + c) = mx;
  *(float4*)(xr + HIDX + c) = mean;
}

// ---------- label branch ----------
__global__ void k_dvec(const float* __restrict__ A, float* __restrict__ dvec) {
  int i = blockIdx.x * 64 + threadIdx.x;
  if (i >= N_CLASSESX) return;
  float s = 0.f;
  for (int j = 0; j < N_CLASSESX; j++) s += A[i * N_CLASSESX + j];
  dvec[i] = rsqrtf(s);
}
__global__ void k_adj(const float* __restrict__ A, const float* __restrict__ dvec,
                      float* __restrict__ adj) {
  int idx = blockIdx.x * 256 + threadIdx.x;
  if (idx >= N_CLASSESX * N_CLASSESX) return;
  int i = idx / N_CLASSESX, j = idx % N_CLASSESX;
  adj[idx] = dvec[i] * A[j * N_CLASSESX + i] * dvec[j];
}

// ---------- final out = fc2o @ y^T : one wave per output ----------
__global__ __launch_bounds__(256)
void k_out(const float* __restrict__ xf2, const float* __restrict__ y,
           float* __restrict__ out) {
  int gw = (blockIdx.x * 256 + threadIdx.x) >> 6;
  int lane = threadIdx.x & 63;
  if (gw >= N_GRAPHSX * N_CLASSESX) return;
  int b = gw / N_CLASSESX, c = gw - b * N_CLASSESX;
  const float4* xr = (const float4*)(xf2 + (size_t)b * 1024);
  const float4* yr = (const float4*)(y + (size_t)c * 1024);
  float s = 0.f;
  #pragma unroll
  for (int i = 0; i < 4; i++) {
    float4 xv = xr[lane + i * 64], yv = yr[lane + i * 64];
    s += xv.x*yv.x + xv.y*yv.y + xv.z*yv.z + xv.w*yv.w;
  }
  #pragma unroll
  for (int off = 32; off > 0; off >>= 1) s += __shfl_down(s, off, 64);
  if (lane == 0) out[gw] = s;
}

// =======================================================================
extern "C" void kernel_launch(void* const* d_in, const int* in_sizes, int n_in,
                              void* d_out, int out_size, void* d_ws, size_t ws_size,
                              hipStream_t stream) {
  const float* x     = (const float*)d_in[0];
  const int*   ei    = (const int*)d_in[1];
  const int*   batch = (const int*)d_in[2];
  const float* inp   = (const float*)d_in[3];
  const float* W_gat = (const float*)d_in[4];
  const float* a_src = (const float*)d_in[5];
  const float* a_dst = (const float*)d_in[6];
  const float* b_gat = (const float*)d_in[7];
  const float* W_gcn = (const float*)d_in[8];
  const float* b_gcn = (const float*)d_in[9];
  const float* W_fc1 = (const float*)d_in[10];
  const float* b_fc1 = (const float*)d_in[11];
  const float* W_fc2 = (const float*)d_in[12];
  const float* b_fc2 = (const float*)d_in[13];
  const float* W_gc1 = (const float*)d_in[14];
  const float* W_gc2 = (const float*)d_in[15];
  const float* A     = (const float*)d_in[16];
  float* out = (float*)d_out;

  char* ws = (char*)d_ws;
  size_t off = 0;
  auto alloc = [&](size_t bytes) -> void* {
    void* p = ws + off;
    off = (off + bytes + 255) & ~(size_t)255;
    return p;
  };

  float* bufA   = (float*)alloc(sizeof(float) * (size_t)N_NODESX * HIDX); // h, then s
  float* bufB   = (float*)alloc(sizeof(float) * (size_t)N_NODESX * HIDX); // xgh alias, then xg2
  float* e_edge = (float*)alloc(sizeof(float) * (size_t)N_E * HEADSX);    // also aliases xh/xl
  float* al_s   = (float*)alloc(sizeof(float) * N_NODESX * HEADSX);
  float* al_d   = (float*)alloc(sizeof(float) * N_NODESX * HEADSX);
  float* den    = (float*)alloc(sizeof(float) * N_NODESX * HEADSX);
  int* counts   = (int*)alloc(sizeof(int) * N_NODESX);
  int* row_ptr  = (int*)alloc(sizeof(int) * (N_NODESX + 1));
  int* cursor   = (int*)alloc(sizeof(int) * N_NODESX);
  int* csr_src  = (int*)alloc(sizeof(int) * N_E);
  int* csr_eid  = (int*)alloc(sizeof(int) * N_E);
  float* dinv   = (float*)alloc(sizeof(float) * N_NODESX);
  int* gstart   = (int*)alloc(sizeof(int) * N_GRAPHSX);
  int* gend     = (int*)alloc(sizeof(int) * N_GRAPHSX);
  float* xf     = (float*)alloc(sizeof(float) * N_GRAPHSX * 2 * HIDX);
  float* fc1o   = (float*)alloc(sizeof(float) * N_GRAPHSX * 1500);
  float* fc2o   = (float*)alloc(sizeof(float) * N_GRAPHSX * 1024);
  float* t1     = (float*)alloc(sizeof(float) * N_CLASSESX * 1024);
  float* adj    = (float*)alloc(sizeof(float) * N_CLASSESX * N_CLASSESX);
  float* dvec   = (float*)alloc(sizeof(float) * N_CLASSESX);
  float* y1     = (float*)alloc(sizeof(float) * N_CLASSESX * 1024);
  float* t2     = (float*)alloc(sizeof(float) * N_CLASSESX * 1024);
  float* ybuf   = (float*)alloc(sizeof(float) * N_CLASSESX * 1024);
  float* Ppart  = (float*)alloc(sizeof(float) * 13 * 64 * 1500);   // split-K partials (max)
  // bf16 split planes
  unsigned short* wgTh = (unsigned short*)alloc(sizeof(short) * (size_t)HIDX * KP_GAT);
  unsigned short* wgTl = (unsigned short*)alloc(sizeof(short) * (size_t)HIDX * KP_GAT);
  unsigned short* wcTh = (unsigned short*)alloc(sizeof(short) * (size_t)HIDX * KP_GCN);
  unsigned short* wcTl = (unsigned short*)alloc(sizeof(short) * (size_t)HIDX * KP_GCN);
  unsigned short* xgl  = (unsigned short*)alloc(sizeof(short) * (size_t)N_NODESX * KP_GCN);
  // aliases (lifetimes disjoint):
  unsigned short* xh  = (unsigned short*)e_edge;                    // dead before e_edge written
  unsigned short* xl  = xh + (size_t)N_NODESX * KP_GAT;
  unsigned short* xgh = (unsigned short*)bufB;                      // dead before xg2 written
  (void)ws_size; (void)in_sizes; (void)n_in; (void)out_size;

  hipMemsetAsync(den, 0, sizeof(float) * N_NODESX * HEADSX, stream);
  hipMemsetAsync(counts, 0, sizeof(int) * N_NODESX, stream);
  hipMemsetAsync(cursor, 0, sizeof(int) * N_NODESX, stream);

  // split conversions
  k_split_pad<<<(N_NODESX * (KP_GAT/8) + 255) / 256, 256, 0, stream>>>(x, N_NODESX, F_XDX, KP_GAT, xh, xl);
  k_splitT<<<(HIDX * (KP_GAT/8) + 255) / 256, 256, 0, stream>>>(W_gat, F_XDX, HIDX, KP_GAT, wgTh, wgTl);
  k_splitT<<<(HIDX * (KP_GCN/8) + 255) / 256, 256, 0, stream>>>(W_gcn, HIDX, HIDX, KP_GCN, wcTh, wcTl);

  // h = x @ W_gat  (MFMA split-bf16, XCD-swizzled)
  gemm_mfma3<<<dim3((HIDX + 127) / 128, (N_NODESX + 127) / 128), 256, 0, stream>>>(
      xh, xl, wgTh, wgTl, bufA, N_NODESX, HIDX, KP_GAT);
  // attention logits
  k_al<<<(N_NODESX * HEADSX + 255) / 256, 256, 0, stream>>>(bufA, a_src, a_dst, al_s, al_d);
  // CSR
  k_count<<<(N_E + 255) / 256, 256, 0, stream>>>(ei, counts);
  k_scan<<<1, 1024, 0, stream>>>(counts, row_ptr);
  k_fill<<<(N_E + 255) / 256, 256, 0, stream>>>(ei, row_ptr, cursor, csr_src, csr_eid);
  // edge softmax
  k_edge_exp<<<(N_E + 255) / 256, 256, 0, stream>>>(ei, al_s, al_d, e_edge, den);
  // GAT aggregate -> xg split planes
  k_gat_agg<<<N_NODESX, 256, 0, stream>>>(bufA, e_edge, den, row_ptr, csr_src, csr_eid,
                                          b_gat, xgh, xgl);
  // GCN
  k_dinv<<<(N_NODESX + 255) / 256, 256, 0, stream>>>(counts, dinv);
  gemm_mfma3<<<dim3((HIDX + 127) / 128, (N_NODESX + 127) / 128), 256, 0, stream>>>(
      xgh, xgl, wcTh, wcTl, bufA, N_NODESX, HIDX, KP_GCN);          // s -> bufA
  k_gcn_agg<<<N_NODESX, 256, 0, stream>>>(bufA, dinv, row_ptr, csr_src, b_gcn, bufB); // xg2
  // pooling
  k_range_init<<<1, 64, 0, stream>>>(gstart, gend);
  k_ranges<<<(N_NODESX + 255) / 256, 256, 0, stream>>>(batch, gstart, gend);
  k_pool<<<N_GRAPHSX, 256, 0, stream>>>(bufB, gstart, gend, xf);

  // ---- dense head via split-K ----
  gemm_sk<<<dim3(24, 1, 13), 256, 0, stream>>>(xf, W_fc1, Ppart, 64, 1500, 1560, 128);
  k_sk_reduce<1, true><<<(64 * 1500 + 255) / 256, 256, 0, stream>>>(
      Ppart, b_fc1, fc1o, 64 * 1500, 1500, 13);
  gemm_sk<<<dim3(16, 1, 12), 256, 0, stream>>>(fc1o, W_fc2, Ppart, 64, 1024, 1500, 128);
  k_sk_reduce<0, true><<<(64 * 1024 + 255) / 256, 256, 0, stream>>>(
      Ppart, b_fc2, fc2o, 64 * 1024, 1024, 12);

  // ---- label branch ----
  k_dvec<<<(N_CLASSESX + 63) / 64, 64, 0, stream>>>(A, dvec);
  k_adj<<<(N_CLASSESX * N_CLASSESX + 255) / 256, 256, 0, stream>>>(A, dvec, adj);
  gemm_sk<<<dim3(16, 2, 5), 256, 0, stream>>>(inp, W_gc1, Ppart, 100, 1024, 300, 64);
  k_sk_reduce<0, false><<<(100 * 1024 + 255) / 256, 256, 0, stream>>>(
      Ppart, nullptr, t1, 100 * 1024, 1024, 5);
  gemm_sk<<<dim3(16, 2, 4), 256, 0, stream>>>(adj, t1, Ppart, 100, 1024, 100, 32);
  k_sk_reduce<2, false><<<(100 * 1024 + 255) / 256, 256, 0, stream>>>(
      Ppart, nullptr, y1, 100 * 1024, 1024, 4);
  gemm_sk<<<dim3(16, 2, 8), 256, 0, stream>>>(y1, W_gc2, Ppart, 100, 1024, 1024, 128);
  k_sk_reduce<0, false><<<(100 * 1024 + 255) / 256, 256, 0, stream>>>(
      Ppart, nullptr, t2, 100 * 1024, 1024, 8);
  gemm_sk<<<dim3(16, 2, 4), 256, 0, stream>>>(adj, t2, Ppart, 100, 1024, 100, 32);
  k_sk_reduce<0, false><<<(100 * 1024 + 255) / 256, 256, 0, stream>>>(
      Ppart, nullptr, ybuf, 100 * 1024, 1024, 4);

  // out = fc2o @ ybuf^T (wave per output)
  k_out<<<(N_GRAPHSX * N_CLASSESX * 64 + 255) / 256, 256, 0, stream>>>(fc2o, ybuf, out);
}

// Round 6
// 1290.332 us; speedup vs baseline: 1.8359x; 1.0839x over previous
//
#include <hip/hip_runtime.h>

#define N_NODESX 30000
#define M_PAD    30080   // ceil(30000/128)*128
#define N_EDGES0 300000
#define N_E      330000
#define N_GRAPHSX 64
#define N_CLASSESX 100
#define F_XDX 78
#define HEADSX 10
#define HIDX 780
#define N_PAD 896        // ceil(780/128)*128
#define IN_CHX 300
#define KP_GAT 96    // ceil(78/32)*32
#define KP_GCN 800   // ceil(780/32)*32
#define NXCD 8

typedef __attribute__((ext_vector_type(8))) short short8v;
typedef __attribute__((ext_vector_type(8))) unsigned short ushort8v;
typedef __attribute__((ext_vector_type(4))) float f32x4;

// ---------- bf16 split helpers ----------
__device__ inline unsigned short f2bf_rne(float f) {
  unsigned u = __float_as_uint(f);
  unsigned r = (u + 0x7FFFu + ((u >> 16) & 1u)) >> 16;
  return (unsigned short)r;
}
__device__ inline float bf2f(unsigned short h) {
  return __uint_as_float(((unsigned)h) << 16);
}
__device__ inline void splitbf(float v, unsigned short& h, unsigned short& l) {
  unsigned short hh = f2bf_rne(v);
  h = hh;
  l = f2bf_rne(v - bf2f(hh));
}

// ---------- split fp32 matrix (M x K) into hi/lo bf16 planes (Mpad x Kp, zero pad) ----------
__global__ void k_split_pad(const float* __restrict__ X, int M, int Mpad, int K, int Kp,
                            unsigned short* __restrict__ Ph, unsigned short* __restrict__ Pl) {
  int idx = blockIdx.x * 256 + threadIdx.x;
  int packs = Kp >> 3;
  if (idx >= Mpad * packs) return;
  int row = idx / packs, p = idx - row * packs;
  ushort8v h, l;
  #pragma unroll
  for (int j = 0; j < 8; j++) {
    int k = p * 8 + j;
    float v = (row < M && k < K) ? X[(size_t)row * K + k] : 0.f;
    unsigned short hh, ll;
    splitbf(v, hh, ll);
    h[j] = hh; l[j] = ll;
  }
  *(ushort8v*)&Ph[(size_t)row * Kp + p * 8] = h;
  *(ushort8v*)&Pl[(size_t)row * Kp + p * 8] = l;
}

// ---------- split + transpose: W (K x N) -> planes (Npad x Kp, zero pad) ----------
__global__ void k_splitT(const float* __restrict__ W, int K, int N, int Npad, int Kp,
                         unsigned short* __restrict__ Th, unsigned short* __restrict__ Tl) {
  int idx = blockIdx.x * 256 + threadIdx.x;
  int packs = Kp >> 3;
  if (idx >= Npad * packs) return;
  int n = idx / packs, p = idx - n * packs;
  ushort8v h, l;
  #pragma unroll
  for (int j = 0; j < 8; j++) {
    int k = p * 8 + j;
    float v = (n < N && k < K) ? W[(size_t)k * N + n] : 0.f;
    unsigned short hh, ll;
    splitbf(v, hh, ll);
    h[j] = hh; l[j] = ll;
  }
  *(ushort8v*)&Th[(size_t)n * Kp + p * 8] = h;
  *(ushort8v*)&Tl[(size_t)n * Kp + p * 8] = l;
}

// ---------- MFMA split-bf16 GEMM, 2-phase dbuf + global_load_lds + XCD swizzle ----------
// A as hi/lo planes (M_pad x Kp), B as TRANSPOSED hi/lo planes (N_pad x Kp), all rows
// zero-padded so staging needs no bounds checks.
// 3-product: AhBh + AhBl + AlBh. Tile 128x128x32, 256 threads (4 waves, 2x2).
__global__ __launch_bounds__(256)
void gemm_mfma3(const unsigned short* __restrict__ Ah, const unsigned short* __restrict__ Al,
                const unsigned short* __restrict__ Bh, const unsigned short* __restrict__ Bl,
                float* __restrict__ C, int M, int N, int Kp) {
  __shared__ unsigned short lds[2 * 16384];  // 2 bufs x 4 planes x 512 packets x 8 ushort
  const int tid  = threadIdx.x;
  const int lane = tid & 63;
  const int w    = tid >> 6;
  const int wr   = w >> 1, wc = w & 1;

  // bijective XCD-chunk swizzle (m204)
  const int nwg = gridDim.x * gridDim.y;
  const int L   = blockIdx.y * gridDim.x + blockIdx.x;
  const int qq = nwg / NXCD, rr8 = nwg % NXCD;
  const int xcd = L % NXCD, pos = L / NXCD;
  const int newL = (xcd < rr8 ? xcd * (qq + 1) : rr8 * (qq + 1) + (xcd - rr8) * qq) + pos;
  const int bm = (newL / gridDim.x) * 128;
  const int bn = (newL % gridDim.x) * 128;

  f32x4 acc[4][4];
  #pragma unroll
  for (int m = 0; m < 4; m++)
    #pragma unroll
    for (int n = 0; n < 4; n++) acc[m][n] = (f32x4){0.f, 0.f, 0.f, 0.f};

  const unsigned short* srcs[4] = {Ah, Al, Bh, Bl};

  // stage one 32-wide K-tile into buffer `buf`: 2048 16B packets, 8 per thread,
  // LDS dest is wave-uniform base (HW adds lane*16) -> packet q = i*256 + w*64 + lane.
#define STAGE(buf, k0)                                                         \
  {                                                                            \
    _Pragma("unroll")                                                          \
    for (int i = 0; i < 8; i++) {                                              \
      const int plane = i >> 1;                                                \
      const int qp = ((i & 1) << 8) + tid;                                     \
      const int fm = qp >> 6;                                                  \
      const int ks = (qp & 63) >> 4, r16 = qp & 15;                            \
      const int rowbase = (plane < 2) ? bm : bn;                               \
      const int row = rowbase + fm * 16 + r16;                                 \
      const unsigned short* gp = srcs[plane] + (size_t)row * Kp + (k0) + ks * 8; \
      unsigned short* lp = (unsigned short*)lds + (buf) * 16384 + plane * 4096 \
                           + (((i & 1) << 8) + (w << 6)) * 8;                  \
      __builtin_amdgcn_global_load_lds(                                        \
          (const __attribute__((address_space(1))) unsigned int*)gp,           \
          (__attribute__((address_space(3))) unsigned int*)lp, 16, 0, 0);      \
    }                                                                          \
  }

  const int nt = Kp >> 5;
  STAGE(0, 0);
  __syncthreads();            // implicit vmcnt(0): buf0 ready
  int cur = 0;
  for (int t = 0; t < nt; ++t) {
    if (t + 1 < nt) STAGE(cur ^ 1, (t + 1) << 5);   // prefetch next tile
    const unsigned short* Lb = (const unsigned short*)lds + cur * 16384;
    short8v afh[4], afl[4], bfh[4], bfl[4];
    #pragma unroll
    for (int m = 0; m < 4; m++) {
      int fmA = wr * 4 + m;
      afh[m] = *(const short8v*)&Lb[0 * 4096 + fmA * 512 + lane * 8];
      afl[m] = *(const short8v*)&Lb[1 * 4096 + fmA * 512 + lane * 8];
    }
    #pragma unroll
    for (int n = 0; n < 4; n++) {
      int fnB = wc * 4 + n;
      bfh[n] = *(const short8v*)&Lb[2 * 4096 + fnB * 512 + lane * 8];
      bfl[n] = *(const short8v*)&Lb[3 * 4096 + fnB * 512 + lane * 8];
    }
    #pragma unroll
    for (int m = 0; m < 4; m++) {
      #pragma unroll
      for (int n = 0; n < 4; n++) {
        acc[m][n] = __builtin_amdgcn_mfma_f32_16x16x32_bf16(afh[m], bfh[n], acc[m][n], 0, 0, 0);
        acc[m][n] = __builtin_amdgcn_mfma_f32_16x16x32_bf16(afh[m], bfl[n], acc[m][n], 0, 0, 0);
        acc[m][n] = __builtin_amdgcn_mfma_f32_16x16x32_bf16(afl[m], bfh[n], acc[m][n], 0, 0, 0);
      }
    }
    __syncthreads();          // drains vmcnt(0) (next tile staged) + all reads of cur done
    cur ^= 1;
  }
#undef STAGE

  // epilogue: C/D layout col = lane&15, row = (lane>>4)*4 + r  [m89-verified]
  const int r0 = (lane >> 4) * 4;
  const int cc = lane & 15;
  #pragma unroll
  for (int m = 0; m < 4; m++) {
    #pragma unroll
    for (int n = 0; n < 4; n++) {
      int gcol = bn + (wc * 4 + n) * 16 + cc;
      if (gcol >= N) continue;
      #pragma unroll
      for (int r2 = 0; r2 < 4; r2++) {
        int grow = bm + (wr * 4 + m) * 16 + r0 + r2;
        if (grow < M) C[(size_t)grow * N + gcol] = acc[m][n][r2];
      }
    }
  }
}

// ---------- split-K fp32 GEMM for skinny-M: partials P[slice][M][N] ----------
__global__ __launch_bounds__(256)
void gemm_sk(const float* __restrict__ A, const float* __restrict__ B,
             float* __restrict__ P, int M, int N, int K, int SK) {
  __shared__ float As[16][64];
  __shared__ float Bs[16][64];
  int tid = threadIdx.x;
  int bm = blockIdx.y * 64;
  int bn = blockIdx.x * 64;
  int ks = blockIdx.z * SK;
  int ke = min(K, ks + SK);
  int tr = tid >> 4;
  int tc = tid & 15;
  float acc[4][4] = {{0.f}};
  int la_m = tid >> 2;
  int la_k = (tid & 3) << 2;
  int lb_k4 = (tid >> 6) << 2;
  int lb_n = tid & 63;

  for (int k0 = ks; k0 < ke; k0 += 16) {
    {
      int gm = bm + la_m;
      bool mok = gm < M;
      const float* ap = A + (size_t)gm * K + k0 + la_k;
      #pragma unroll
      for (int q = 0; q < 4; q++) {
        int kk = la_k + q;
        As[kk][la_m] = (mok && (k0 + kk) < ke) ? ap[q] : 0.f;
      }
    }
    {
      int gn = bn + lb_n;
      #pragma unroll
      for (int q = 0; q < 4; q++) {
        int kk = lb_k4 + q;
        int gk = k0 + kk;
        Bs[kk][lb_n] = (gk < ke && gn < N) ? B[(size_t)gk * N + gn] : 0.f;
      }
    }
    __syncthreads();
    #pragma unroll
    for (int kk = 0; kk < 16; kk++) {
      float a0 = As[kk][tr*4+0], a1 = As[kk][tr*4+1],
            a2 = As[kk][tr*4+2], a3 = As[kk][tr*4+3];
      float b0 = Bs[kk][tc*4+0], b1 = Bs[kk][tc*4+1],
            b2 = Bs[kk][tc*4+2], b3 = Bs[kk][tc*4+3];
      acc[0][0] += a0*b0; acc[0][1] += a0*b1; acc[0][2] += a0*b2; acc[0][3] += a0*b3;
      acc[1][0] += a1*b0; acc[1][1] += a1*b1; acc[1][2] += a1*b2; acc[1][3] += a1*b3;
      acc[2][0] += a2*b0; acc[2][1] += a2*b1; acc[2][2] += a2*b2; acc[2][3] += a2*b3;
      acc[3][0] += a3*b0; acc[3][1] += a3*b1; acc[3][2] += a3*b2; acc[3][3] += a3*b3;
    }
    __syncthreads();
  }
  float* Pp = P + (size_t)blockIdx.z * M * N;
  #pragma unroll
  for (int i = 0; i < 4; i++) {
    int gm = bm + tr*4 + i;
    if (gm >= M) continue;
    #pragma unroll
    for (int j = 0; j < 4; j++) {
      int gn = bn + tc*4 + j;
      if (gn >= N) continue;
      Pp[(size_t)gm * N + gn] = acc[i][j];
    }
  }
}

// reduce slices + bias + act. ACT: 0 none, 1 relu, 2 leaky(0.2)
template<int ACT, bool HAS_BIAS>
__global__ void k_sk_reduce(const float* __restrict__ P, const float* __restrict__ bias,
                            float* __restrict__ C, int MN, int N, int nS) {
  int idx = blockIdx.x * 256 + threadIdx.x;
  if (idx >= MN) return;
  float s = 0.f;
  for (int sl = 0; sl < nS; sl++) s += P[(size_t)sl * MN + idx];
  if (HAS_BIAS) s += bias[idx % N];
  if (ACT == 1) s = fmaxf(s, 0.f);
  else if (ACT == 2) s = s > 0.f ? s : 0.2f * s;
  C[idx] = s;
}

// ---------- attention logits per (node, head), float2 ----------
__global__ void k_al(const float* __restrict__ h, const float* __restrict__ a_src,
                     const float* __restrict__ a_dst,
                     float* __restrict__ al_s, float* __restrict__ al_d) {
  int idx = blockIdx.x * 256 + threadIdx.x;
  if (idx >= N_NODESX * HEADSX) return;
  int n = idx / HEADSX, hd = idx % HEADSX;
  const float2* hp  = (const float2*)(h + (size_t)n * HIDX + hd * F_XDX);
  const float2* as2 = (const float2*)(a_src + hd * F_XDX);
  const float2* ad2 = (const float2*)(a_dst + hd * F_XDX);
  float s1 = 0.f, s2 = 0.f;
  #pragma unroll 13
  for (int i = 0; i < F_XDX / 2; i++) {
    float2 v = hp[i], a = as2[i], d = ad2[i];
    s1 += v.x * a.x + v.y * a.y;
    s2 += v.x * d.x + v.y * d.y;
  }
  al_s[idx] = s1; al_d[idx] = s2;
}

// ---------- CSR build ----------
__global__ void k_count(const int* __restrict__ ei, int* __restrict__ counts) {
  int e = blockIdx.x * 256 + threadIdx.x;
  if (e >= N_E) return;
  int dst = (e < N_EDGES0) ? ei[N_EDGES0 + e] : (e - N_EDGES0);
  atomicAdd(&counts[dst], 1);
}

__global__ void k_scan(const int* __restrict__ cnt, int* __restrict__ row_ptr) {
  __shared__ int part[1024];
  int tid = threadIdx.x;
  const int CH = 30;
  int b0 = tid * CH;
  int s = 0;
  for (int i = 0; i < CH; i++) { int g = b0 + i; if (g < N_NODESX) s += cnt[g]; }
  part[tid] = s;
  __syncthreads();
  for (int off = 1; off < 1024; off <<= 1) {
    int v = (tid >= off) ? part[tid - off] : 0;
    __syncthreads();
    part[tid] += v;
    __syncthreads();
  }
  int pre = (tid > 0) ? part[tid - 1] : 0;
  for (int i = 0; i < CH; i++) {
    int g = b0 + i;
    if (g < N_NODESX) { row_ptr[g] = pre; pre += cnt[g]; }
  }
  if (tid == 1023) row_ptr[N_NODESX] = part[1023];
}

// fill CSR src list; record each edge's CSR position (epos) so alphas can be
// written in CSR order (sequential reads in k_gat_agg).
__global__ void k_fill(const int* __restrict__ ei, const int* __restrict__ row_ptr,
                       int* __restrict__ cursor, int* __restrict__ csr_src,
                       int* __restrict__ epos) {
  int e = blockIdx.x * 256 + threadIdx.x;
  if (e >= N_E) return;
  int src, dst;
  if (e < N_EDGES0) { src = ei[e]; dst = ei[N_EDGES0 + e]; }
  else { src = dst = e - N_EDGES0; }
  int pos = row_ptr[dst] + atomicAdd(&cursor[dst], 1);
  csr_src[pos] = src;
  epos[e] = pos;
}

// ---------- edge softmax (no max shift: logits bounded); writes CSR-ordered ----------
__global__ void k_edge_exp(const int* __restrict__ ei, const int* __restrict__ epos,
                           const float* __restrict__ al_s, const float* __restrict__ al_d,
                           float* __restrict__ e_csr, float* __restrict__ den) {
  int e = blockIdx.x * 256 + threadIdx.x;
  if (e >= N_E) return;
  int src, dst;
  if (e < N_EDGES0) { src = ei[e]; dst = ei[N_EDGES0 + e]; }
  else { src = dst = e - N_EDGES0; }
  const float* ps = al_s + (size_t)src * HEADSX;
  const float* pd = al_d + (size_t)dst * HEADSX;
  float* pe = e_csr + (size_t)epos[e] * HEADSX;
  #pragma unroll
  for (int hd = 0; hd < HEADSX; hd++) {
    float v = ps[hd] + pd[hd];
    v = v > 0.f ? v : 0.2f * v;
    float ex = expf(v);
    pe[hd] = ex;
    atomicAdd(&den[dst * HEADSX + hd], ex);
  }
}

// ---------- GAT aggregation (gather per dst); writes bf16 hi/lo planes (M_PAD x KP_GCN) ----------
__global__ __launch_bounds__(256)
void k_gat_agg(const float* __restrict__ h, const float* __restrict__ exe,
               const float* __restrict__ den, const int* __restrict__ row_ptr,
               const int* __restrict__ csr_src,
               const float* __restrict__ b_gat,
               unsigned short* __restrict__ xgh, unsigned short* __restrict__ xgl) {
  __shared__ float id[HEADSX];
  int d = blockIdx.x, t = threadIdx.x;
  if (d >= N_NODESX) {           // zero the M padding rows 30000..30079
    if (t < 200) {
      int c = t * 4;
      ushort4 z = make_ushort4(0, 0, 0, 0);
      *(ushort4*)(xgh + (size_t)d * KP_GCN + c) = z;
      *(ushort4*)(xgl + (size_t)d * KP_GCN + c) = z;
    }
    return;
  }
  if (t < HEADSX) id[t] = 1.f / (den[d * HEADSX + t] + 1e-16f);
  __syncthreads();
  if (t >= 200) return;
  if (t >= 195) {  // zero the K padding 780..799
    int c = 780 + (t - 195) * 4;
    ushort4 z = make_ushort4(0, 0, 0, 0);
    *(ushort4*)(xgh + (size_t)d * KP_GCN + c) = z;
    *(ushort4*)(xgl + (size_t)d * KP_GCN + c) = z;
    return;
  }
  int c = t * 4;
  int ha = c / F_XDX;
  int hb = (c + 3) / F_XDX;
  int split = (ha + 1) * F_XDX - c;
  float idA = id[ha], idB = id[hb];
  float4 acc = {0.f, 0.f, 0.f, 0.f};
  int beg = row_ptr[d], end = row_ptr[d + 1];
  for (int j = beg; j < end; j++) {
    int s = csr_src[j];
    const float* er = exe + (size_t)j * HEADSX;   // CSR-ordered: sequential
    float aA = er[ha] * idA;
    float aB = (hb != ha) ? er[hb] * idB : aA;
    float w0 = (split > 0) ? aA : aB;
    float w1 = (split > 1) ? aA : aB;
    float w2 = (split > 2) ? aA : aB;
    float w3 = (split > 3) ? aA : aB;
    float4 hv = *(const float4*)(h + (size_t)s * HIDX + c);
    acc.x += w0 * hv.x; acc.y += w1 * hv.y; acc.z += w2 * hv.z; acc.w += w3 * hv.w;
  }
  float4 bb = *(const float4*)(b_gat + c);
  float v0 = fmaxf(acc.x + bb.x, 0.f);
  float v1 = fmaxf(acc.y + bb.y, 0.f);
  float v2 = fmaxf(acc.z + bb.z, 0.f);
  float v3 = fmaxf(acc.w + bb.w, 0.f);
  ushort4 h4, l4;
  splitbf(v0, h4.x, l4.x); splitbf(v1, h4.y, l4.y);
  splitbf(v2, h4.z, l4.z); splitbf(v3, h4.w, l4.w);
  *(ushort4*)(xgh + (size_t)d * KP_GCN + c) = h4;
  *(ushort4*)(xgl + (size_t)d * KP_GCN + c) = l4;
}

// ---------- degree inv sqrt ----------
__global__ void k_dinv(const int* __restrict__ counts, float* __restrict__ dinv) {
  int n = blockIdx.x * 256 + threadIdx.x;
  if (n < N_NODESX) dinv[n] = rsqrtf(fmaxf((float)counts[n], 1.f));
}

// ---------- GCN aggregation (gather per dst, float4) ----------
__global__ __launch_bounds__(256)
void k_gcn_agg(const float* __restrict__ s, const float* __restrict__ dinv,
               const int* __restrict__ row_ptr, const int* __restrict__ csr_src,
               const float* __restrict__ b_gcn, float* __restrict__ out) {
  int d = blockIdx.x, t = threadIdx.x;
  if (t >= HIDX / 4) return;
  int c = t * 4;
  float4 acc = {0.f, 0.f, 0.f, 0.f};
  int beg = row_ptr[d], end = row_ptr[d + 1];
  for (int j = beg; j < end; j++) {
    int si = csr_src[j];
    float w = dinv[si];
    float4 sv = *(const float4*)(s + (size_t)si * HIDX + c);
    acc.x += w * sv.x; acc.y += w * sv.y; acc.z += w * sv.z; acc.w += w * sv.w;
  }
  float dd = dinv[d];
  float4 bb = *(const float4*)(b_gcn + c);
  float4 r;
  r.x = fmaxf(acc.x * dd + bb.x, 0.f);
  r.y = fmaxf(acc.y * dd + bb.y, 0.f);
  r.z = fmaxf(acc.z * dd + bb.z, 0.f);
  r.w = fmaxf(acc.w * dd + bb.w, 0.f);
  *(float4*)(out + (size_t)d * HIDX + c) = r;
}

// ---------- per-graph ranges ----------
__global__ void k_range_init(int* __restrict__ gstart, int* __restrict__ gend) {
  int g = threadIdx.x;
  if (g < N_GRAPHSX) { gstart[g] = 0x7FFFFFFF; gend[g] = 0; }
}
__global__ void k_ranges(const int* __restrict__ batch, int* __restrict__ gstart,
                         int* __restrict__ gend) {
  int n = blockIdx.x * 256 + threadIdx.x;
  if (n >= N_NODESX) return;
  int b = batch[n];
  atomicMin(&gstart[b], n);
  atomicMax(&gend[b], n + 1);
}

// ---------- pooling: max + mean per graph, float4 ----------
__global__ __launch_bounds__(256)
void k_pool(const float* __restrict__ xg2, const int* __restrict__ gstart,
            const int* __restrict__ gend, float* __restrict__ xf) {
  int g = blockIdx.x, t = threadIdx.x;
  if (t >= HIDX / 4) return;
  int c = t * 4;
  int st = gstart[g], en = gend[g];
  float4 mx = {0.f, 0.f, 0.f, 0.f};
  float4 sm = {0.f, 0.f, 0.f, 0.f};
  for (int n = st; n < en; n++) {
    float4 v = *(const float4*)(xg2 + (size_t)n * HIDX + c);
    mx.x = fmaxf(mx.x, v.x); sm.x += v.x;
    mx.y = fmaxf(mx.y, v.y); sm.y += v.y;
    mx.z = fmaxf(mx.z, v.z); sm.z += v.z;
    mx.w = fmaxf(mx.w, v.w); sm.w += v.w;
  }
  float inv = (en > st) ? 1.f / (float)(en - st) : 0.f;
  float* xr = xf + (size_t)g * (2 * HIDX);
  float4 mean; mean.x = sm.x*inv; mean.y = sm.y*inv; mean.z = sm.z*inv; mean.w = sm.w*inv;
  *(float4*)(xr + c) = mx;
  *(float4*)(xr + HIDX + c) = mean;
}

// ---------- label branch ----------
__global__ void k_dvec(const float* __restrict__ A, float* __restrict__ dvec) {
  int i = blockIdx.x * 64 + threadIdx.x;
  if (i >= N_CLASSESX) return;
  float s = 0.f;
  for (int j = 0; j < N_CLASSESX; j++) s += A[i * N_CLASSESX + j];
  dvec[i] = rsqrtf(s);
}
__global__ void k_adj(const float* __restrict__ A, const float* __restrict__ dvec,
                      float* __restrict__ adj) {
  int idx = blockIdx.x * 256 + threadIdx.x;
  if (idx >= N_CLASSESX * N_CLASSESX) return;
  int i = idx / N_CLASSESX, j = idx % N_CLASSESX;
  adj[idx] = dvec[i] * A[j * N_CLASSESX + i] * dvec[j];
}

// ---------- final out = fc2o @ y^T : one wave per output ----------
__global__ __launch_bounds__(256)
void k_out(const float* __restrict__ xf2, const float* __restrict__ y,
           float* __restrict__ out) {
  int gw = (blockIdx.x * 256 + threadIdx.x) >> 6;
  int lane = threadIdx.x & 63;
  if (gw >= N_GRAPHSX * N_CLASSESX) return;
  int b = gw / N_CLASSESX, c = gw - b * N_CLASSESX;
  const float4* xr = (const float4*)(xf2 + (size_t)b * 1024);
  const float4* yr = (const float4*)(y + (size_t)c * 1024);
  float s = 0.f;
  #pragma unroll
  for (int i = 0; i < 4; i++) {
    float4 xv = xr[lane + i * 64], yv = yr[lane + i * 64];
    s += xv.x*yv.x + xv.y*yv.y + xv.z*yv.z + xv.w*yv.w;
  }
  #pragma unroll
  for (int off = 32; off > 0; off >>= 1) s += __shfl_down(s, off, 64);
  if (lane == 0) out[gw] = s;
}

// =======================================================================
extern "C" void kernel_launch(void* const* d_in, const int* in_sizes, int n_in,
                              void* d_out, int out_size, void* d_ws, size_t ws_size,
                              hipStream_t stream) {
  const float* x     = (const float*)d_in[0];
  const int*   ei    = (const int*)d_in[1];
  const int*   batch = (const int*)d_in[2];
  const float* inp   = (const float*)d_in[3];
  const float* W_gat = (const float*)d_in[4];
  const float* a_src = (const float*)d_in[5];
  const float* a_dst = (const float*)d_in[6];
  const float* b_gat = (const float*)d_in[7];
  const float* W_gcn = (const float*)d_in[8];
  const float* b_gcn = (const float*)d_in[9];
  const float* W_fc1 = (const float*)d_in[10];
  const float* b_fc1 = (const float*)d_in[11];
  const float* W_fc2 = (const float*)d_in[12];
  const float* b_fc2 = (const float*)d_in[13];
  const float* W_gc1 = (const float*)d_in[14];
  const float* W_gc2 = (const float*)d_in[15];
  const float* A     = (const float*)d_in[16];
  float* out = (float*)d_out;

  char* ws = (char*)d_ws;
  size_t off = 0;
  auto alloc = [&](size_t bytes) -> void* {
    void* p = ws + off;
    off = (off + bytes + 255) & ~(size_t)255;
    return p;
  };

  float* bufA   = (float*)alloc(sizeof(float) * (size_t)N_NODESX * HIDX); // h, then s
  float* bufB   = (float*)alloc(sizeof(float) * (size_t)M_PAD * HIDX);    // xgh alias, then xg2
  float* e_edge = (float*)alloc(sizeof(float) * (size_t)N_E * HEADSX);    // also aliases xh/xl
  float* al_s   = (float*)alloc(sizeof(float) * N_NODESX * HEADSX);
  float* al_d   = (float*)alloc(sizeof(float) * N_NODESX * HEADSX);
  float* den    = (float*)alloc(sizeof(float) * N_NODESX * HEADSX);
  int* counts   = (int*)alloc(sizeof(int) * N_NODESX);
  int* row_ptr  = (int*)alloc(sizeof(int) * (N_NODESX + 1));
  int* cursor   = (int*)alloc(sizeof(int) * N_NODESX);
  int* csr_src  = (int*)alloc(sizeof(int) * N_E);
  int* epos     = (int*)alloc(sizeof(int) * N_E);
  float* dinv   = (float*)alloc(sizeof(float) * N_NODESX);
  int* gstart   = (int*)alloc(sizeof(int) * N_GRAPHSX);
  int* gend     = (int*)alloc(sizeof(int) * N_GRAPHSX);
  float* xf     = (float*)alloc(sizeof(float) * N_GRAPHSX * 2 * HIDX);
  float* fc1o   = (float*)alloc(sizeof(float) * N_GRAPHSX * 1500);
  float* fc2o   = (float*)alloc(sizeof(float) * N_GRAPHSX * 1024);
  float* t1     = (float*)alloc(sizeof(float) * N_CLASSESX * 1024);
  float* adj    = (float*)alloc(sizeof(float) * N_CLASSESX * N_CLASSESX);
  float* dvec   = (float*)alloc(sizeof(float) * N_CLASSESX);
  float* y1     = (float*)alloc(sizeof(float) * N_CLASSESX * 1024);
  float* t2     = (float*)alloc(sizeof(float) * N_CLASSESX * 1024);
  float* ybuf   = (float*)alloc(sizeof(float) * N_CLASSESX * 1024);
  float* Ppart  = (float*)alloc(sizeof(float) * 13 * 64 * 1500);   // split-K partials (max)
  // bf16 split planes (padded to tile multiples; zero-filled pads)
  unsigned short* wgTh = (unsigned short*)alloc(sizeof(short) * (size_t)N_PAD * KP_GAT);
  unsigned short* wgTl = (unsigned short*)alloc(sizeof(short) * (size_t)N_PAD * KP_GAT);
  unsigned short* wcTh = (unsigned short*)alloc(sizeof(short) * (size_t)N_PAD * KP_GCN);
  unsigned short* wcTl = (unsigned short*)alloc(sizeof(short) * (size_t)N_PAD * KP_GCN);
  unsigned short* xgl  = (unsigned short*)alloc(sizeof(short) * (size_t)M_PAD * KP_GCN);
  // aliases (lifetimes disjoint):
  unsigned short* xh  = (unsigned short*)e_edge;                    // dead before e_edge written
  unsigned short* xl  = xh + (size_t)M_PAD * KP_GAT;
  unsigned short* xgh = (unsigned short*)bufB;                      // dead before xg2 written
  (void)ws_size; (void)in_sizes; (void)n_in; (void)out_size;

  hipMemsetAsync(den, 0, sizeof(float) * N_NODESX * HEADSX, stream);
  hipMemsetAsync(counts, 0, sizeof(int) * N_NODESX, stream);
  hipMemsetAsync(cursor, 0, sizeof(int) * N_NODESX, stream);

  // split conversions (zero-padded)
  k_split_pad<<<(M_PAD * (KP_GAT/8) + 255) / 256, 256, 0, stream>>>(
      x, N_NODESX, M_PAD, F_XDX, KP_GAT, xh, xl);
  k_splitT<<<(N_PAD * (KP_GAT/8) + 255) / 256, 256, 0, stream>>>(
      W_gat, F_XDX, HIDX, N_PAD, KP_GAT, wgTh, wgTl);
  k_splitT<<<(N_PAD * (KP_GCN/8) + 255) / 256, 256, 0, stream>>>(
      W_gcn, HIDX, HIDX, N_PAD, KP_GCN, wcTh, wcTl);

  // h = x @ W_gat  (MFMA split-bf16, dbuf + global_load_lds + XCD swizzle)
  gemm_mfma3<<<dim3(N_PAD / 128, M_PAD / 128), 256, 0, stream>>>(
      xh, xl, wgTh, wgTl, bufA, N_NODESX, HIDX, KP_GAT);
  // attention logits
  k_al<<<(N_NODESX * HEADSX + 255) / 256, 256, 0, stream>>>(bufA, a_src, a_dst, al_s, al_d);
  // CSR
  k_count<<<(N_E + 255) / 256, 256, 0, stream>>>(ei, counts);
  k_scan<<<1, 1024, 0, stream>>>(counts, row_ptr);
  k_fill<<<(N_E + 255) / 256, 256, 0, stream>>>(ei, row_ptr, cursor, csr_src, epos);
  // edge softmax (CSR-ordered alpha store)
  k_edge_exp<<<(N_E + 255) / 256, 256, 0, stream>>>(ei, epos, al_s, al_d, e_edge, den);
  // GAT aggregate -> xg split planes (incl. zeroing M-pad rows)
  k_gat_agg<<<M_PAD, 256, 0, stream>>>(bufA, e_edge, den, row_ptr, csr_src,
                                       b_gat, xgh, xgl);
  // GCN
  k_dinv<<<(N_NODESX + 255) / 256, 256, 0, stream>>>(counts, dinv);
  gemm_mfma3<<<dim3(N_PAD / 128, M_PAD / 128), 256, 0, stream>>>(
      xgh, xgl, wcTh, wcTl, bufA, N_NODESX, HIDX, KP_GCN);          // s -> bufA
  k_gcn_agg<<<N_NODESX, 256, 0, stream>>>(bufA, dinv, row_ptr, csr_src, b_gcn, bufB); // xg2
  // pooling
  k_range_init<<<1, 64, 0, stream>>>(gstart, gend);
  k_ranges<<<(N_NODESX + 255) / 256, 256, 0, stream>>>(batch, gstart, gend);
  k_pool<<<N_GRAPHSX, 256, 0, stream>>>(bufB, gstart, gend, xf);

  // ---- dense head via split-K ----
  gemm_sk<<<dim3(24, 1, 13), 256, 0, stream>>>(xf, W_fc1, Ppart, 64, 1500, 1560, 128);
  k_sk_reduce<1, true><<<(64 * 1500 + 255) / 256, 256, 0, stream>>>(
      Ppart, b_fc1, fc1o, 64 * 1500, 1500, 13);
  gemm_sk<<<dim3(16, 1, 12), 256, 0, stream>>>(fc1o, W_fc2, Ppart, 64, 1024, 1500, 128);
  k_sk_reduce<0, true><<<(64 * 1024 + 255) / 256, 256, 0, stream>>>(
      Ppart, b_fc2, fc2o, 64 * 1024, 1024, 12);

  // ---- label branch ----
  k_dvec<<<(N_CLASSESX + 63) / 64, 64, 0, stream>>>(A, dvec);
  k_adj<<<(N_CLASSESX * N_CLASSESX + 255) / 256, 256, 0, stream>>>(A, dvec, adj);
  gemm_sk<<<dim3(16, 2, 5), 256, 0, stream>>>(inp, W_gc1, Ppart, 100, 1024, 300, 64);
  k_sk_reduce<0, false><<<(100 * 1024 + 255) / 256, 256, 0, stream>>>(
      Ppart, nullptr, t1, 100 * 1024, 1024, 5);
  gemm_sk<<<dim3(16, 2, 4), 256, 0, stream>>>(adj, t1, Ppart, 100, 1024, 100, 32);
  k_sk_reduce<2, false><<<(100 * 1024 + 255) / 256, 256, 0, stream>>>(
      Ppart, nullptr, y1, 100 * 1024, 1024, 4);
  gemm_sk<<<dim3(16, 2, 8), 256, 0, stream>>>(y1, W_gc2, Ppart, 100, 1024, 1024, 128);
  k_sk_reduce<0, false><<<(100 * 1024 + 255) / 256, 256, 0, stream>>>(
      Ppart, nullptr, t2, 100 * 1024, 1024, 8);
  gemm_sk<<<dim3(16, 2, 4), 256, 0, stream>>>(adj, t2, Ppart, 100, 1024, 100, 32);
  k_sk_reduce<0, false><<<(100 * 1024 + 255) / 256, 256, 0, stream>>>(
      Ppart, nullptr, ybuf, 100 * 1024, 1024, 4);

  // out = fc2o @ ybuf^T (wave per output)
  k_out<<<(N_GRAPHSX * N_CLASSESX * 64 + 255) / 256, 256, 0, stream>>>(fc2o, ybuf, out);
}

// Round 8
// 1158.705 us; speedup vs baseline: 2.0445x; 1.1136x over previous
//
#include <hip/hip_runtime.h>

#define N_NODESX 30000
#define M_PAD    30080   // ceil(30000/128)*128
#define N_EDGES0 300000
#define N_E      330000
#define N_GRAPHSX 64
#define N_CLASSESX 100
#define F_XDX 78
#define HEADSX 10
#define HIDX 780
#define N_PAD 896        // ceil(780/128)*128
#define IN_CHX 300
#define KP_GAT 96    // ceil(78/32)*32
#define KP_GCN 800   // ceil(780/32)*32
#define NXCD 8
#define NSL 8        // pooling node-slices per graph

typedef __attribute__((ext_vector_type(8))) short short8v;
typedef __attribute__((ext_vector_type(8))) unsigned short ushort8v;
typedef __attribute__((ext_vector_type(4))) float f32x4;

// ---------- bf16 split helpers ----------
__device__ inline unsigned short f2bf_rne(float f) {
  unsigned u = __float_as_uint(f);
  unsigned r = (u + 0x7FFFu + ((u >> 16) & 1u)) >> 16;
  return (unsigned short)r;
}
__device__ inline float bf2f(unsigned short h) {
  return __uint_as_float(((unsigned)h) << 16);
}
__device__ inline void splitbf(float v, unsigned short& h, unsigned short& l) {
  unsigned short hh = f2bf_rne(v);
  h = hh;
  l = f2bf_rne(v - bf2f(hh));
}
// packed u32: hi bf16 in [31:16], lo bf16 in [15:0]
__device__ inline unsigned packbf(float v) {
  unsigned short hh, ll;
  splitbf(v, hh, ll);
  return ((unsigned)hh << 16) | (unsigned)ll;
}
__device__ inline float unpackbf(unsigned u) {
  return __uint_as_float(u & 0xFFFF0000u) + __uint_as_float(u << 16);
}

// ---------- split fp32 matrix (M x K) into hi/lo bf16 planes (Mpad x Kp, zero pad) ----------
__global__ void k_split_pad(const float* __restrict__ X, int M, int Mpad, int K, int Kp,
                            unsigned short* __restrict__ Ph, unsigned short* __restrict__ Pl) {
  int idx = blockIdx.x * 256 + threadIdx.x;
  int packs = Kp >> 3;
  if (idx >= Mpad * packs) return;
  int row = idx / packs, p = idx - row * packs;
  ushort8v h, l;
  #pragma unroll
  for (int j = 0; j < 8; j++) {
    int k = p * 8 + j;
    float v = (row < M && k < K) ? X[(size_t)row * K + k] : 0.f;
    unsigned short hh, ll;
    splitbf(v, hh, ll);
    h[j] = hh; l[j] = ll;
  }
  *(ushort8v*)&Ph[(size_t)row * Kp + p * 8] = h;
  *(ushort8v*)&Pl[(size_t)row * Kp + p * 8] = l;
}

// ---------- split + transpose: W (K x N) -> planes (Npad x Kp, zero pad) ----------
__global__ void k_splitT(const float* __restrict__ W, int K, int N, int Npad, int Kp,
                         unsigned short* __restrict__ Th, unsigned short* __restrict__ Tl) {
  int idx = blockIdx.x * 256 + threadIdx.x;
  int packs = Kp >> 3;
  if (idx >= Npad * packs) return;
  int n = idx / packs, p = idx - n * packs;
  ushort8v h, l;
  #pragma unroll
  for (int j = 0; j < 8; j++) {
    int k = p * 8 + j;
    float v = (n < N && k < K) ? W[(size_t)k * N + n] : 0.f;
    unsigned short hh, ll;
    splitbf(v, hh, ll);
    h[j] = hh; l[j] = ll;
  }
  *(ushort8v*)&Th[(size_t)n * Kp + p * 8] = h;
  *(ushort8v*)&Tl[(size_t)n * Kp + p * 8] = l;
}

// ---------- MFMA split-bf16 GEMM, 2-phase dbuf + global_load_lds + XCD swizzle ----------
// A as hi/lo planes (M_pad x Kp), B as TRANSPOSED hi/lo planes (N_pad x Kp), all rows
// zero-padded so staging needs no bounds checks.
// 3-product: AhBh + AhBl + AlBh. Tile 128x128x32, 256 threads (4 waves, 2x2).
// PACKED: write C as u32 (hi bf16 | lo bf16) instead of fp32 (halves C traffic
// and downstream gather traffic).
template<bool PACKED>
__global__ __launch_bounds__(256)
void gemm_mfma3(const unsigned short* __restrict__ Ah, const unsigned short* __restrict__ Al,
                const unsigned short* __restrict__ Bh, const unsigned short* __restrict__ Bl,
                void* __restrict__ Cv, int M, int N, int Kp) {
  __shared__ unsigned short lds[2 * 16384];  // 2 bufs x 4 planes x 512 packets x 8 ushort
  const int tid  = threadIdx.x;
  const int lane = tid & 63;
  const int w    = tid >> 6;
  const int wr   = w >> 1, wc = w & 1;

  // bijective XCD-chunk swizzle (m204)
  const int nwg = gridDim.x * gridDim.y;
  const int L   = blockIdx.y * gridDim.x + blockIdx.x;
  const int qq = nwg / NXCD, rr8 = nwg % NXCD;
  const int xcd = L % NXCD, pos = L / NXCD;
  const int newL = (xcd < rr8 ? xcd * (qq + 1) : rr8 * (qq + 1) + (xcd - rr8) * qq) + pos;
  const int bm = (newL / gridDim.x) * 128;
  const int bn = (newL % gridDim.x) * 128;

  f32x4 acc[4][4];
  #pragma unroll
  for (int m = 0; m < 4; m++)
    #pragma unroll
    for (int n = 0; n < 4; n++) acc[m][n] = (f32x4){0.f, 0.f, 0.f, 0.f};

  const unsigned short* srcs[4] = {Ah, Al, Bh, Bl};

#define STAGE(buf, k0)                                                         \
  {                                                                            \
    _Pragma("unroll")                                                          \
    for (int i = 0; i < 8; i++) {                                              \
      const int plane = i >> 1;                                                \
      const int qp = ((i & 1) << 8) + tid;                                     \
      const int fm = qp >> 6;                                                  \
      const int ks = (qp & 63) >> 4, r16 = qp & 15;                            \
      const int rowbase = (plane < 2) ? bm : bn;                               \
      const int row = rowbase + fm * 16 + r16;                                 \
      const unsigned short* gp = srcs[plane] + (size_t)row * Kp + (k0) + ks * 8; \
      unsigned short* lp = (unsigned short*)lds + (buf) * 16384 + plane * 4096 \
                           + (((i & 1) << 8) + (w << 6)) * 8;                  \
      __builtin_amdgcn_global_load_lds(                                        \
          (const __attribute__((address_space(1))) unsigned int*)gp,           \
          (__attribute__((address_space(3))) unsigned int*)lp, 16, 0, 0);      \
    }                                                                          \
  }

  const int nt = Kp >> 5;
  STAGE(0, 0);
  __syncthreads();            // implicit vmcnt(0): buf0 ready
  int cur = 0;
  for (int t = 0; t < nt; ++t) {
    if (t + 1 < nt) STAGE(cur ^ 1, (t + 1) << 5);   // prefetch next tile
    const unsigned short* Lb = (const unsigned short*)lds + cur * 16384;
    short8v afh[4], afl[4], bfh[4], bfl[4];
    #pragma unroll
    for (int m = 0; m < 4; m++) {
      int fmA = wr * 4 + m;
      afh[m] = *(const short8v*)&Lb[0 * 4096 + fmA * 512 + lane * 8];
      afl[m] = *(const short8v*)&Lb[1 * 4096 + fmA * 512 + lane * 8];
    }
    #pragma unroll
    for (int n = 0; n < 4; n++) {
      int fnB = wc * 4 + n;
      bfh[n] = *(const short8v*)&Lb[2 * 4096 + fnB * 512 + lane * 8];
      bfl[n] = *(const short8v*)&Lb[3 * 4096 + fnB * 512 + lane * 8];
    }
    #pragma unroll
    for (int m = 0; m < 4; m++) {
      #pragma unroll
      for (int n = 0; n < 4; n++) {
        acc[m][n] = __builtin_amdgcn_mfma_f32_16x16x32_bf16(afh[m], bfh[n], acc[m][n], 0, 0, 0);
        acc[m][n] = __builtin_amdgcn_mfma_f32_16x16x32_bf16(afh[m], bfl[n], acc[m][n], 0, 0, 0);
        acc[m][n] = __builtin_amdgcn_mfma_f32_16x16x32_bf16(afl[m], bfh[n], acc[m][n], 0, 0, 0);
      }
    }
    __syncthreads();          // drains vmcnt(0) (next tile staged) + reads of cur done
    cur ^= 1;
  }
#undef STAGE

  // epilogue: C/D layout col = lane&15, row = (lane>>4)*4 + r  [m89-verified]
  const int r0 = (lane >> 4) * 4;
  const int cc = lane & 15;
  #pragma unroll
  for (int m = 0; m < 4; m++) {
    #pragma unroll
    for (int n = 0; n < 4; n++) {
      int gcol = bn + (wc * 4 + n) * 16 + cc;
      if (gcol >= N) continue;
      #pragma unroll
      for (int r2 = 0; r2 < 4; r2++) {
        int grow = bm + (wr * 4 + m) * 16 + r0 + r2;
        if (grow < M) {
          if (PACKED)
            ((unsigned*)Cv)[(size_t)grow * N + gcol] = packbf(acc[m][n][r2]);
          else
            ((float*)Cv)[(size_t)grow * N + gcol] = acc[m][n][r2];
        }
      }
    }
  }
}

// ---------- split-K fp32 GEMM for skinny-M: partials P[slice][M][N] ----------
__global__ __launch_bounds__(256)
void gemm_sk(const float* __restrict__ A, const float* __restrict__ B,
             float* __restrict__ P, int M, int N, int K, int SK) {
  __shared__ float As[16][64];
  __shared__ float Bs[16][64];
  int tid = threadIdx.x;
  int bm = blockIdx.y * 64;
  int bn = blockIdx.x * 64;
  int ks = blockIdx.z * SK;
  int ke = min(K, ks + SK);
  int tr = tid >> 4;
  int tc = tid & 15;
  float acc[4][4] = {{0.f}};
  int la_m = tid >> 2;
  int la_k = (tid & 3) << 2;
  int lb_k4 = (tid >> 6) << 2;
  int lb_n = tid & 63;

  for (int k0 = ks; k0 < ke; k0 += 16) {
    {
      int gm = bm + la_m;
      bool mok = gm < M;
      const float* ap = A + (size_t)gm * K + k0 + la_k;
      #pragma unroll
      for (int q = 0; q < 4; q++) {
        int kk = la_k + q;
        As[kk][la_m] = (mok && (k0 + kk) < ke) ? ap[q] : 0.f;
      }
    }
    {
      int gn = bn + lb_n;
      #pragma unroll
      for (int q = 0; q < 4; q++) {
        int kk = lb_k4 + q;
        int gk = k0 + kk;
        Bs[kk][lb_n] = (gk < ke && gn < N) ? B[(size_t)gk * N + gn] : 0.f;
      }
    }
    __syncthreads();
    #pragma unroll
    for (int kk = 0; kk < 16; kk++) {
      float a0 = As[kk][tr*4+0], a1 = As[kk][tr*4+1],
            a2 = As[kk][tr*4+2], a3 = As[kk][tr*4+3];
      float b0 = Bs[kk][tc*4+0], b1 = Bs[kk][tc*4+1],
            b2 = Bs[kk][tc*4+2], b3 = Bs[kk][tc*4+3];
      acc[0][0] += a0*b0; acc[0][1] += a0*b1; acc[0][2] += a0*b2; acc[0][3] += a0*b3;
      acc[1][0] += a1*b0; acc[1][1] += a1*b1; acc[1][2] += a1*b2; acc[1][3] += a1*b3;
      acc[2][0] += a2*b0; acc[2][1] += a2*b1; acc[2][2] += a2*b2; acc[2][3] += a2*b3;
      acc[3][0] += a3*b0; acc[3][1] += a3*b1; acc[3][2] += a3*b2; acc[3][3] += a3*b3;
    }
    __syncthreads();
  }
  float* Pp = P + (size_t)blockIdx.z * M * N;
  #pragma unroll
  for (int i = 0; i < 4; i++) {
    int gm = bm + tr*4 + i;
    if (gm >= M) continue;
    #pragma unroll
    for (int j = 0; j < 4; j++) {
      int gn = bn + tc*4 + j;
      if (gn >= N) continue;
      Pp[(size_t)gm * N + gn] = acc[i][j];
    }
  }
}

// reduce slices + bias + act. ACT: 0 none, 1 relu, 2 leaky(0.2)
template<int ACT, bool HAS_BIAS>
__global__ void k_sk_reduce(const float* __restrict__ P, const float* __restrict__ bias,
                            float* __restrict__ C, int MN, int N, int nS) {
  int idx = blockIdx.x * 256 + threadIdx.x;
  if (idx >= MN) return;
  float s = 0.f;
  for (int sl = 0; sl < nS; sl++) s += P[(size_t)sl * MN + idx];
  if (HAS_BIAS) s += bias[idx % N];
  if (ACT == 1) s = fmaxf(s, 0.f);
  else if (ACT == 2) s = s > 0.f ? s : 0.2f * s;
  C[idx] = s;
}

// ---------- attention logits per (node, head); h packed u32 ----------
__global__ void k_al(const unsigned* __restrict__ h, const float* __restrict__ a_src,
                     const float* __restrict__ a_dst,
                     float* __restrict__ al_s, float* __restrict__ al_d) {
  int idx = blockIdx.x * 256 + threadIdx.x;
  if (idx >= N_NODESX * HEADSX) return;
  int n = idx / HEADSX, hd = idx % HEADSX;
  const uint2* hp   = (const uint2*)(h + (size_t)n * HIDX + hd * F_XDX);
  const float2* as2 = (const float2*)(a_src + hd * F_XDX);
  const float2* ad2 = (const float2*)(a_dst + hd * F_XDX);
  float s1 = 0.f, s2 = 0.f;
  #pragma unroll 13
  for (int i = 0; i < F_XDX / 2; i++) {
    uint2 u = hp[i];
    float2 a = as2[i], d = ad2[i];
    float vx = unpackbf(u.x), vy = unpackbf(u.y);
    s1 += vx * a.x + vy * a.y;
    s2 += vx * d.x + vy * d.y;
  }
  al_s[idx] = s1; al_d[idx] = s2;
}

// ---------- CSR build ----------
__global__ void k_count(const int* __restrict__ ei, int* __restrict__ counts) {
  int e = blockIdx.x * 256 + threadIdx.x;
  if (e >= N_E) return;
  int dst = (e < N_EDGES0) ? ei[N_EDGES0 + e] : (e - N_EDGES0);
  atomicAdd(&counts[dst], 1);
}

__global__ void k_scan(const int* __restrict__ cnt, int* __restrict__ row_ptr) {
  __shared__ int part[1024];
  int tid = threadIdx.x;
  const int CH = 30;
  int b0 = tid * CH;
  int s = 0;
  for (int i = 0; i < CH; i++) { int g = b0 + i; if (g < N_NODESX) s += cnt[g]; }
  part[tid] = s;
  __syncthreads();
  for (int off = 1; off < 1024; off <<= 1) {
    int v = (tid >= off) ? part[tid - off] : 0;
    __syncthreads();
    part[tid] += v;
    __syncthreads();
  }
  int pre = (tid > 0) ? part[tid - 1] : 0;
  for (int i = 0; i < CH; i++) {
    int g = b0 + i;
    if (g < N_NODESX) { row_ptr[g] = pre; pre += cnt[g]; }
  }
  if (tid == 1023) row_ptr[N_NODESX] = part[1023];
}

__global__ void k_fill(const int* __restrict__ ei, const int* __restrict__ row_ptr,
                       int* __restrict__ cursor, int* __restrict__ csr_src,
                       int* __restrict__ epos) {
  int e = blockIdx.x * 256 + threadIdx.x;
  if (e >= N_E) return;
  int src, dst;
  if (e < N_EDGES0) { src = ei[e]; dst = ei[N_EDGES0 + e]; }
  else { src = dst = e - N_EDGES0; }
  int pos = row_ptr[dst] + atomicAdd(&cursor[dst], 1);
  csr_src[pos] = src;
  epos[e] = pos;
}

// ---------- edge softmax (no max shift: logits bounded); writes CSR-ordered ----------
__global__ void k_edge_exp(const int* __restrict__ ei, const int* __restrict__ epos,
                           const float* __restrict__ al_s, const float* __restrict__ al_d,
                           float* __restrict__ e_csr, float* __restrict__ den) {
  int e = blockIdx.x * 256 + threadIdx.x;
  if (e >= N_E) return;
  int src, dst;
  if (e < N_EDGES0) { src = ei[e]; dst = ei[N_EDGES0 + e]; }
  else { src = dst = e - N_EDGES0; }
  const float* ps = al_s + (size_t)src * HEADSX;
  const float* pd = al_d + (size_t)dst * HEADSX;
  float* pe = e_csr + (size_t)epos[e] * HEADSX;
  #pragma unroll
  for (int hd = 0; hd < HEADSX; hd++) {
    float v = ps[hd] + pd[hd];
    v = v > 0.f ? v : 0.2f * v;
    float ex = expf(v);
    pe[hd] = ex;
    atomicAdd(&den[dst * HEADSX + hd], ex);
  }
}

// ---------- GAT aggregation (gather per dst, packed h); writes bf16 planes ----------
__global__ __launch_bounds__(256)
void k_gat_agg(const unsigned* __restrict__ h, const float* __restrict__ exe,
               const float* __restrict__ den, const int* __restrict__ row_ptr,
               const int* __restrict__ csr_src,
               const float* __restrict__ b_gat,
               unsigned short* __restrict__ xgh, unsigned short* __restrict__ xgl) {
  __shared__ float id[HEADSX];
  int d = blockIdx.x, t = threadIdx.x;
  if (d >= N_NODESX) {           // zero the M padding rows 30000..30079
    if (t < 200) {
      int c = t * 4;
      ushort4 z = make_ushort4(0, 0, 0, 0);
      *(ushort4*)(xgh + (size_t)d * KP_GCN + c) = z;
      *(ushort4*)(xgl + (size_t)d * KP_GCN + c) = z;
    }
    return;
  }
  if (t < HEADSX) id[t] = 1.f / (den[d * HEADSX + t] + 1e-16f);
  __syncthreads();
  if (t >= 200) return;
  if (t >= 195) {  // zero the K padding 780..799
    int c = 780 + (t - 195) * 4;
    ushort4 z = make_ushort4(0, 0, 0, 0);
    *(ushort4*)(xgh + (size_t)d * KP_GCN + c) = z;
    *(ushort4*)(xgl + (size_t)d * KP_GCN + c) = z;
    return;
  }
  int c = t * 4;
  int ha = c / F_XDX;
  int hb = (c + 3) / F_XDX;
  int split = (ha + 1) * F_XDX - c;
  float idA = id[ha], idB = id[hb];
  float4 acc = {0.f, 0.f, 0.f, 0.f};
  int beg = row_ptr[d], end = row_ptr[d + 1];
  for (int j = beg; j < end; j++) {
    int s = csr_src[j];
    const float* er = exe + (size_t)j * HEADSX;   // CSR-ordered: sequential
    float aA = er[ha] * idA;
    float aB = (hb != ha) ? er[hb] * idB : aA;
    float w0 = (split > 0) ? aA : aB;
    float w1 = (split > 1) ? aA : aB;
    float w2 = (split > 2) ? aA : aB;
    float w3 = (split > 3) ? aA : aB;
    uint4 hv = *(const uint4*)(h + (size_t)s * HIDX + c);
    acc.x += w0 * unpackbf(hv.x); acc.y += w1 * unpackbf(hv.y);
    acc.z += w2 * unpackbf(hv.z); acc.w += w3 * unpackbf(hv.w);
  }
  float4 bb = *(const float4*)(b_gat + c);
  float v0 = fmaxf(acc.x + bb.x, 0.f);
  float v1 = fmaxf(acc.y + bb.y, 0.f);
  float v2 = fmaxf(acc.z + bb.z, 0.f);
  float v3 = fmaxf(acc.w + bb.w, 0.f);
  ushort4 h4, l4;
  splitbf(v0, h4.x, l4.x); splitbf(v1, h4.y, l4.y);
  splitbf(v2, h4.z, l4.z); splitbf(v3, h4.w, l4.w);
  *(ushort4*)(xgh + (size_t)d * KP_GCN + c) = h4;
  *(ushort4*)(xgl + (size_t)d * KP_GCN + c) = l4;
}

// ---------- degree inv sqrt ----------
__global__ void k_dinv(const int* __restrict__ counts, float* __restrict__ dinv) {
  int n = blockIdx.x * 256 + threadIdx.x;
  if (n < N_NODESX) dinv[n] = rsqrtf(fmaxf((float)counts[n], 1.f));
}

// ---------- GCN aggregation (gather per dst, packed s) ----------
__global__ __launch_bounds__(256)
void k_gcn_agg(const unsigned* __restrict__ s, const float* __restrict__ dinv,
               const int* __restrict__ row_ptr, const int* __restrict__ csr_src,
               const float* __restrict__ b_gcn, float* __restrict__ out) {
  int d = blockIdx.x, t = threadIdx.x;
  if (t >= HIDX / 4) return;
  int c = t * 4;
  float4 acc = {0.f, 0.f, 0.f, 0.f};
  int beg = row_ptr[d], end = row_ptr[d + 1];
  for (int j = beg; j < end; j++) {
    int si = csr_src[j];
    float w = dinv[si];
    uint4 sv = *(const uint4*)(s + (size_t)si * HIDX + c);
    acc.x += w * unpackbf(sv.x); acc.y += w * unpackbf(sv.y);
    acc.z += w * unpackbf(sv.z); acc.w += w * unpackbf(sv.w);
  }
  float dd = dinv[d];
  float4 bb = *(const float4*)(b_gcn + c);
  float4 r;
  r.x = fmaxf(acc.x * dd + bb.x, 0.f);
  r.y = fmaxf(acc.y * dd + bb.y, 0.f);
  r.z = fmaxf(acc.z * dd + bb.z, 0.f);
  r.w = fmaxf(acc.w * dd + bb.w, 0.f);
  *(float4*)(out + (size_t)d * HIDX + c) = r;
}

// ---------- per-graph ranges ----------
__global__ void k_range_init(int* __restrict__ gstart, int* __restrict__ gend) {
  int g = threadIdx.x;
  if (g < N_GRAPHSX) { gstart[g] = 0x7FFFFFFF; gend[g] = 0; }
}
__global__ void k_ranges(const int* __restrict__ batch, int* __restrict__ gstart,
                         int* __restrict__ gend) {
  int n = blockIdx.x * 256 + threadIdx.x;
  if (n >= N_NODESX) return;
  int b = batch[n];
  atomicMin(&gstart[b], n);
  atomicMax(&gend[b], n + 1);
}

// ---------- pooling stage A: per (graph, node-slice) partial max/sum ----------
__global__ __launch_bounds__(256)
void k_pool_a(const float* __restrict__ xg2, const int* __restrict__ gstart,
              const int* __restrict__ gend,
              float* __restrict__ pmax, float* __restrict__ psum) {
  int g = blockIdx.x, sl = blockIdx.y, t = threadIdx.x;
  if (t >= HIDX / 4) return;
  int c = t * 4;
  int st = gstart[g], en = gend[g];
  int len = en - st; if (len < 0) len = 0;
  int chunk = (len + NSL - 1) / NSL;
  int s0 = st + sl * chunk;
  int s1 = min(en, s0 + chunk);
  float4 mx = {0.f, 0.f, 0.f, 0.f};
  float4 sm = {0.f, 0.f, 0.f, 0.f};
  for (int n = s0; n < s1; n++) {
    float4 v = *(const float4*)(xg2 + (size_t)n * HIDX + c);
    mx.x = fmaxf(mx.x, v.x); sm.x += v.x;
    mx.y = fmaxf(mx.y, v.y); sm.y += v.y;
    mx.z = fmaxf(mx.z, v.z); sm.z += v.z;
    mx.w = fmaxf(mx.w, v.w); sm.w += v.w;
  }
  size_t o = ((size_t)g * NSL + sl) * HIDX + c;
  *(float4*)(pmax + o) = mx;
  *(float4*)(psum + o) = sm;
}

// ---------- pooling stage B: reduce slices, write xf[g][0:780]=max, [780:1560]=mean ----------
__global__ __launch_bounds__(256)
void k_pool_b(const float* __restrict__ pmax, const float* __restrict__ psum,
              const int* __restrict__ gstart, const int* __restrict__ gend,
              float* __restrict__ xf) {
  int g = blockIdx.x, t = threadIdx.x;
  if (t >= HIDX / 4) return;
  int c = t * 4;
  float4 mx = {0.f, 0.f, 0.f, 0.f};
  float4 sm = {0.f, 0.f, 0.f, 0.f};
  #pragma unroll
  for (int sl = 0; sl < NSL; sl++) {
    size_t o = ((size_t)g * NSL + sl) * HIDX + c;
    float4 m = *(const float4*)(pmax + o);
    float4 s = *(const float4*)(psum + o);
    mx.x = fmaxf(mx.x, m.x); sm.x += s.x;
    mx.y = fmaxf(mx.y, m.y); sm.y += s.y;
    mx.z = fmaxf(mx.z, m.z); sm.z += s.z;
    mx.w = fmaxf(mx.w, m.w); sm.w += s.w;
  }
  int st = gstart[g], en = gend[g];
  float inv = (en > st) ? 1.f / (float)(en - st) : 0.f;
  float* xr = xf + (size_t)g * (2 * HIDX);
  float4 mean; mean.x = sm.x*inv; mean.y = sm.y*inv; mean.z = sm.z*inv; mean.w = sm.w*inv;
  *(float4*)(xr + c) = mx;
  *(float4*)(xr + HIDX + c) = mean;
}

// ---------- label branch ----------
__global__ void k_dvec(const float* __restrict__ A, float* __restrict__ dvec) {
  int i = blockIdx.x * 64 + threadIdx.x;
  if (i >= N_CLASSESX) return;
  float s = 0.f;
  for (int j = 0; j < N_CLASSESX; j++) s += A[i * N_CLASSESX + j];
  dvec[i] = rsqrtf(s);
}
__global__ void k_adj(const float* __restrict__ A, const float* __restrict__ dvec,
                      float* __restrict__ adj) {
  int idx = blockIdx.x * 256 + threadIdx.x;
  if (idx >= N_CLASSESX * N_CLASSESX) return;
  int i = idx / N_CLASSESX, j = idx % N_CLASSESX;
  adj[idx] = dvec[i] * A[j * N_CLASSESX + i] * dvec[j];
}

// ---------- final out = fc2o @ y^T : one wave per output ----------
__global__ __launch_bounds__(256)
void k_out(const float* __restrict__ xf2, const float* __restrict__ y,
           float* __restrict__ out) {
  int gw = (blockIdx.x * 256 + threadIdx.x) >> 6;
  int lane = threadIdx.x & 63;
  if (gw >= N_GRAPHSX * N_CLASSESX) return;
  int b = gw / N_CLASSESX, c = gw - b * N_CLASSESX;
  const float4* xr = (const float4*)(xf2 + (size_t)b * 1024);
  const float4* yr = (const float4*)(y + (size_t)c * 1024);
  float s = 0.f;
  #pragma unroll
  for (int i = 0; i < 4; i++) {
    float4 xv = xr[lane + i * 64], yv = yr[lane + i * 64];
    s += xv.x*yv.x + xv.y*yv.y + xv.z*yv.z + xv.w*yv.w;
  }
  #pragma unroll
  for (int off = 32; off > 0; off >>= 1) s += __shfl_down(s, off, 64);
  if (lane == 0) out[gw] = s;
}

// =======================================================================
extern "C" void kernel_launch(void* const* d_in, const int* in_sizes, int n_in,
                              void* d_out, int out_size, void* d_ws, size_t ws_size,
                              hipStream_t stream) {
  const float* x     = (const float*)d_in[0];
  const int*   ei    = (const int*)d_in[1];
  const int*   batch = (const int*)d_in[2];
  const float* inp   = (const float*)d_in[3];
  const float* W_gat = (const float*)d_in[4];
  const float* a_src = (const float*)d_in[5];
  const float* a_dst = (const float*)d_in[6];
  const float* b_gat = (const float*)d_in[7];
  const float* W_gcn = (const float*)d_in[8];
  const float* b_gcn = (const float*)d_in[9];
  const float* W_fc1 = (const float*)d_in[10];
  const float* b_fc1 = (const float*)d_in[11];
  const float* W_fc2 = (const float*)d_in[12];
  const float* b_fc2 = (const float*)d_in[13];
  const float* W_gc1 = (const float*)d_in[14];
  const float* W_gc2 = (const float*)d_in[15];
  const float* A     = (const float*)d_in[16];
  float* out = (float*)d_out;

  char* ws = (char*)d_ws;
  size_t off = 0;
  auto alloc = [&](size_t bytes) -> void* {
    void* p = ws + off;
    off = (off + bytes + 255) & ~(size_t)255;
    return p;
  };

  float* bufA   = (float*)alloc(sizeof(float) * (size_t)N_NODESX * HIDX); // h(packed), then s(packed)
  float* bufB   = (float*)alloc(sizeof(float) * (size_t)M_PAD * HIDX);    // xgh alias, then xg2
  float* e_edge = (float*)alloc(sizeof(float) * (size_t)N_E * HEADSX);    // also aliases xh/xl
  float* al_s   = (float*)alloc(sizeof(float) * N_NODESX * HEADSX);
  float* al_d   = (float*)alloc(sizeof(float) * N_NODESX * HEADSX);
  float* den    = (float*)alloc(sizeof(float) * N_NODESX * HEADSX);
  int* counts   = (int*)alloc(sizeof(int) * N_NODESX);
  int* row_ptr  = (int*)alloc(sizeof(int) * (N_NODESX + 1));
  int* cursor   = (int*)alloc(sizeof(int) * N_NODESX);
  int* csr_src  = (int*)alloc(sizeof(int) * N_E);
  int* epos     = (int*)alloc(sizeof(int) * N_E);
  float* dinv   = (float*)alloc(sizeof(float) * N_NODESX);
  int* gstart   = (int*)alloc(sizeof(int) * N_GRAPHSX);
  int* gend     = (int*)alloc(sizeof(int) * N_GRAPHSX);
  float* xf     = (float*)alloc(sizeof(float) * N_GRAPHSX * 2 * HIDX);
  float* fc1o   = (float*)alloc(sizeof(float) * N_GRAPHSX * 1500);
  float* fc2o   = (float*)alloc(sizeof(float) * N_GRAPHSX * 1024);
  float* t1     = (float*)alloc(sizeof(float) * N_CLASSESX * 1024);
  float* adj    = (float*)alloc(sizeof(float) * N_CLASSESX * N_CLASSESX);
  float* dvec   = (float*)alloc(sizeof(float) * N_CLASSESX);
  float* y1     = (float*)alloc(sizeof(float) * N_CLASSESX * 1024);
  float* t2     = (float*)alloc(sizeof(float) * N_CLASSESX * 1024);
  float* ybuf   = (float*)alloc(sizeof(float) * N_CLASSESX * 1024);
  float* Ppart  = (float*)alloc(sizeof(float) * 13 * 64 * 1500);   // split-K partials (max)
  // bf16 split planes (padded to tile multiples; zero-filled pads)
  unsigned short* wgTh = (unsigned short*)alloc(sizeof(short) * (size_t)N_PAD * KP_GAT);
  unsigned short* wgTl = (unsigned short*)alloc(sizeof(short) * (size_t)N_PAD * KP_GAT);
  unsigned short* wcTh = (unsigned short*)alloc(sizeof(short) * (size_t)N_PAD * KP_GCN);
  unsigned short* wcTl = (unsigned short*)alloc(sizeof(short) * (size_t)N_PAD * KP_GCN);
  unsigned short* xgl  = (unsigned short*)alloc(sizeof(short) * (size_t)M_PAD * KP_GCN);
  // aliases (lifetimes disjoint):
  unsigned short* xh  = (unsigned short*)e_edge;                    // dead before e_edge written
  unsigned short* xl  = xh + (size_t)M_PAD * KP_GAT;
  unsigned short* xgh = (unsigned short*)bufB;                      // dead before xg2 written
  unsigned* hpk = (unsigned*)bufA;                                  // packed h / packed s
  // pooling partials alias Ppart (pooling completes before first gemm_sk;
  // 2 * 64*8*780 floats = 3.19 MB <= Ppart's 4.99 MB). Keeps ws under the
  // 256 MiB limit that R7 overflowed.
  float* pmax = Ppart;
  float* psum = Ppart + (size_t)N_GRAPHSX * NSL * HIDX;
  (void)ws_size; (void)in_sizes; (void)n_in; (void)out_size;

  hipMemsetAsync(den, 0, sizeof(float) * N_NODESX * HEADSX, stream);
  hipMemsetAsync(counts, 0, sizeof(int) * N_NODESX, stream);
  hipMemsetAsync(cursor, 0, sizeof(int) * N_NODESX, stream);

  // split conversions (zero-padded)
  k_split_pad<<<(M_PAD * (KP_GAT/8) + 255) / 256, 256, 0, stream>>>(
      x, N_NODESX, M_PAD, F_XDX, KP_GAT, xh, xl);
  k_splitT<<<(N_PAD * (KP_GAT/8) + 255) / 256, 256, 0, stream>>>(
      W_gat, F_XDX, HIDX, N_PAD, KP_GAT, wgTh, wgTl);
  k_splitT<<<(N_PAD * (KP_GCN/8) + 255) / 256, 256, 0, stream>>>(
      W_gcn, HIDX, HIDX, N_PAD, KP_GCN, wcTh, wcTl);

  // h = x @ W_gat  (MFMA split-bf16 -> packed u32 output)
  gemm_mfma3<true><<<dim3(N_PAD / 128, M_PAD / 128), 256, 0, stream>>>(
      xh, xl, wgTh, wgTl, hpk, N_NODESX, HIDX, KP_GAT);
  // attention logits (packed h)
  k_al<<<(N_NODESX * HEADSX + 255) / 256, 256, 0, stream>>>(hpk, a_src, a_dst, al_s, al_d);
  // CSR
  k_count<<<(N_E + 255) / 256, 256, 0, stream>>>(ei, counts);
  k_scan<<<1, 1024, 0, stream>>>(counts, row_ptr);
  k_fill<<<(N_E + 255) / 256, 256, 0, stream>>>(ei, row_ptr, cursor, csr_src, epos);
  // edge softmax (CSR-ordered alpha store)
  k_edge_exp<<<(N_E + 255) / 256, 256, 0, stream>>>(ei, epos, al_s, al_d, e_edge, den);
  // GAT aggregate (packed h gather) -> xg split planes
  k_gat_agg<<<M_PAD, 256, 0, stream>>>(hpk, e_edge, den, row_ptr, csr_src,
                                       b_gat, xgh, xgl);
  // GCN
  k_dinv<<<(N_NODESX + 255) / 256, 256, 0, stream>>>(counts, dinv);
  gemm_mfma3<true><<<dim3(N_PAD / 128, M_PAD / 128), 256, 0, stream>>>(
      xgh, xgl, wcTh, wcTl, hpk, N_NODESX, HIDX, KP_GCN);           // s(packed) -> bufA
  k_gcn_agg<<<N_NODESX, 256, 0, stream>>>(hpk, dinv, row_ptr, csr_src, b_gcn, bufB); // xg2
  // pooling (2-stage)
  k_range_init<<<1, 64, 0, stream>>>(gstart, gend);
  k_ranges<<<(N_NODESX + 255) / 256, 256, 0, stream>>>(batch, gstart, gend);
  k_pool_a<<<dim3(N_GRAPHSX, NSL), 256, 0, stream>>>(bufB, gstart, gend, pmax, psum);
  k_pool_b<<<N_GRAPHSX, 256, 0, stream>>>(pmax, psum, gstart, gend, xf);

  // ---- dense head via split-K ----
  gemm_sk<<<dim3(24, 1, 13), 256, 0, stream>>>(xf, W_fc1, Ppart, 64, 1500, 1560, 128);
  k_sk_reduce<1, true><<<(64 * 1500 + 255) / 256, 256, 0, stream>>>(
      Ppart, b_fc1, fc1o, 64 * 1500, 1500, 13);
  gemm_sk<<<dim3(16, 1, 12), 256, 0, stream>>>(fc1o, W_fc2, Ppart, 64, 1024, 1500, 128);
  k_sk_reduce<0, true><<<(64 * 1024 + 255) / 256, 256, 0, stream>>>(
      Ppart, b_fc2, fc2o, 64 * 1024, 1024, 12);

  // ---- label branch ----
  k_dvec<<<(N_CLASSESX + 63) / 64, 64, 0, stream>>>(A, dvec);
  k_adj<<<(N_CLASSESX * N_CLASSESX + 255) / 256, 256, 0, stream>>>(A, dvec, adj);
  gemm_sk<<<dim3(16, 2, 5), 256, 0, stream>>>(inp, W_gc1, Ppart, 100, 1024, 300, 64);
  k_sk_reduce<0, false><<<(100 * 1024 + 255) / 256, 256, 0, stream>>>(
      Ppart, nullptr, t1, 100 * 1024, 1024, 5);
  gemm_sk<<<dim3(16, 2, 4), 256, 0, stream>>>(adj, t1, Ppart, 100, 1024, 100, 32);
  k_sk_reduce<2, false><<<(100 * 1024 + 255) / 256, 256, 0, stream>>>(
      Ppart, nullptr, y1, 100 * 1024, 1024, 4);
  gemm_sk<<<dim3(16, 2, 8), 256, 0, stream>>>(y1, W_gc2, Ppart, 100, 1024, 1024, 128);
  k_sk_reduce<0, false><<<(100 * 1024 + 255) / 256, 256, 0, stream>>>(
      Ppart, nullptr, t2, 100 * 1024, 1024, 8);
  gemm_sk<<<dim3(16, 2, 4), 256, 0, stream>>>(adj, t2, Ppart, 100, 1024, 100, 32);
  k_sk_reduce<0, false><<<(100 * 1024 + 255) / 256, 256, 0, stream>>>(
      Ppart, nullptr, ybuf, 100 * 1024, 1024, 4);

  // out = fc2o @ ybuf^T (wave per output)
  k_out<<<(N_GRAPHSX * N_CLASSESX * 64 + 255) / 256, 256, 0, stream>>>(fc2o, ybuf, out);
}